// Round 1
// 299.293 us; speedup vs baseline: 1.0467x; 1.0467x over previous
//
#include <hip/hip_runtime.h>
#include <math.h>

#define N 4096
#define D 128
#define H 512
#define INV_T 5.0f
#define KSPLIT 4

typedef short bf16x8 __attribute__((ext_vector_type(8)));
typedef float f32x4 __attribute__((ext_vector_type(4)));
typedef unsigned short u16x8 __attribute__((ext_vector_type(8)));
typedef unsigned short u16;
typedef _Float16 f16;
typedef _Float16 f16x4 __attribute__((ext_vector_type(4)));

#define MFMA(a, b, c) __builtin_amdgcn_mfma_f32_16x16x32_bf16((a), (b), (c), 0, 0, 0)

__device__ __forceinline__ float bf2f(u16 h)
{
    return __uint_as_float(((unsigned)h) << 16);
}

// Round-to-nearest bf16 (unbiased) — for operands whose hi is used ALONE.
__device__ __forceinline__ u16 rtn_bf16(float v)
{
    unsigned u = __float_as_uint(v);
    return (u16)((u + 0x7FFFu + ((u >> 16) & 1u)) >> 16);
}

// RTN split (hi usable alone; lo compensates). Cold paths + last gen layer.
__device__ __forceinline__ void split1(float v, u16& h, u16& l)
{
    u16 hh = rtn_bf16(v);
    float r = v - bf2f(hh);
    h = hh;
    l = rtn_bf16(r);
}

// Cheap truncation split (3 ops); hi+lo pair accuracy identical.
__device__ __forceinline__ void split1_trunc(float v, u16& h, u16& l)
{
    unsigned bv = __float_as_uint(v);
    unsigned hb = bv & 0xFFFF0000u;
    float r = v - __uint_as_float(hb);
    h = (u16)(hb >> 16);
    l = (u16)(__float_as_uint(r) >> 16);
}

// DPP cross-lane move within 16-lane rows (pure VALU — no DS latency).
// 0xB1 = quad_perm [1,0,3,2] (xor1), 0x4E = quad_perm [2,3,0,1] (xor2),
// 0x141 = row_half_mirror (≡xor4 after quad reduce), 0x140 = row_mirror (≡xor8).
template <int CTRL>
__device__ __forceinline__ float dppf(float x)
{
    int r = __builtin_amdgcn_update_dpp(0, __float_as_int(x), CTRL, 0xF, 0xF, true);
    return __int_as_float(r);
}

// ---------------------------------------------------------------------------
// One-shot splitter for 5 flat fp32 arrays -> bf16 hi/lo (RTN, cold) and,
// on the y==5 plane, workspace init (acc/sp/sn/nx/ny).
// ---------------------------------------------------------------------------
struct SplitDesc { const float* src; u16* h; u16* l; int n; };
struct SplitArgs { SplitDesc d[5]; };

__global__ __launch_bounds__(256) void split_multi(SplitArgs args,
    double* acc, float* sp, float* sn, float* nx, float* ny)
{
    if (blockIdx.y == 5) {
        int idx = blockIdx.x * 256 + threadIdx.x;
        if (idx == 0) *acc = 0.0;
        if (idx < N) { sp[idx] = 0.f; sn[idx] = 0.f; nx[idx] = 0.f; ny[idx] = 0.f; }
        return;
    }
    SplitDesc de = args.d[blockIdx.y];
    int idx = (blockIdx.x * 256 + threadIdx.x) * 4;
    if (idx >= de.n) return;
    float4 v = *(const float4*)(de.src + idx);
    ushort4 hv, lv;
    split1(v.x, hv.x, lv.x); split1(v.y, hv.y, lv.y);
    split1(v.z, hv.z, lv.z); split1(v.w, hv.w, lv.w);
    *(ushort4*)(de.h + idx) = hv;
    *(ushort4*)(de.l + idx) = lv;
}

// ---------------------------------------------------------------------------
// Transpose + RTN-bf16 + fused row-norm partials (atomicAdd into nx/ny).
// ---------------------------------------------------------------------------
__global__ __launch_bounds__(256) void transpose_rtn(
    const float* __restrict__ X, const float* __restrict__ Y,
    u16* __restrict__ Xth, u16* __restrict__ Yth,
    float* __restrict__ nx, float* __restrict__ ny)
{
    const float* src = blockIdx.z ? Y : X;
    u16* th = blockIdx.z ? Yth : Xth;
    float* nrm = blockIdx.z ? ny : nx;
    __shared__ float tile[32][33];
    const int t = threadIdx.x;
    const int r0 = blockIdx.x * 32, c0 = blockIdx.y * 32;
    {
        int rit = t >> 3, coff = (t & 7) * 4;
        float4 v = *(const float4*)(src + (size_t)(r0 + rit) * D + c0 + coff);
        tile[rit][coff + 0] = v.x; tile[rit][coff + 1] = v.y;
        tile[rit][coff + 2] = v.z; tile[rit][coff + 3] = v.w;
        float sq = v.x * v.x + v.y * v.y + v.z * v.z + v.w * v.w;
        sq += __shfl_xor(sq, 1);
        sq += __shfl_xor(sq, 2);
        sq += __shfl_xor(sq, 4);
        if ((t & 7) == 0) atomicAdd(&nrm[r0 + rit], sq);
    }
    __syncthreads();
    {
        int cit = t >> 3, roff = (t & 7) * 4;
        ushort4 hv;
        hv.x = rtn_bf16(tile[roff + 0][cit]);
        hv.y = rtn_bf16(tile[roff + 1][cit]);
        hv.z = rtn_bf16(tile[roff + 2][cit]);
        hv.w = rtn_bf16(tile[roff + 3][cit]);
        *(ushort4*)(th + (size_t)(c0 + cit) * N + r0 + roff) = hv;
    }
}

// ---------------------------------------------------------------------------
// Generator GEMM: A = activations hi/lo bf16 pair, B = weights single RTN
// bf16. Tile 64x64, BK=128 (4 barriers for K=512, 0 loop barriers for
// K=128 — chain is barrier-drain-bound at grid-capped 2 blocks/CU),
// 128 threads (2 waves x 32 rows, proven micro-shape per k-quarter).
// rtn_out=1 on the last layer only.
// ---------------------------------------------------------------------------
__global__ __launch_bounds__(128) void gen_gemm(
    const u16* __restrict__ Ah, const u16* __restrict__ Al,
    const u16* __restrict__ Bh,
    const float* __restrict__ bias,
    float* __restrict__ C, u16* __restrict__ Ch, u16* __restrict__ Cl,
    int M, int Nn, int K, int resid, int rtn_out)
{
    __shared__ u16 AhS[64][136], AlS[64][136];
    __shared__ u16 BhS[64][136];
    const int t = threadIdx.x;
    const int w = t >> 6, lane = t & 63;
    const int quad = lane >> 4, l16 = lane & 15;
    const int bm = blockIdx.y * 64, bn = blockIdx.x * 64;
    f32x4 acc[2][4] = {};

    for (int k0 = 0; k0 < K; k0 += 128) {
        __syncthreads();
        #pragma unroll
        for (int p = 0; p < 8; ++p) {
            int slot = t + p * 128;          // 1024 slots = 64 rows x 16 k-octets
            int row = slot >> 4, koff = (slot & 15) << 3;
            size_t ga = (size_t)(bm + row) * K + k0 + koff;
            size_t gb = (size_t)(bn + row) * K + k0 + koff;
            *(u16x8*)&AhS[row][koff] = *(const u16x8*)(Ah + ga);
            *(u16x8*)&AlS[row][koff] = *(const u16x8*)(Al + ga);
            *(u16x8*)&BhS[row][koff] = *(const u16x8*)(Bh + gb);
        }
        __syncthreads();
        #pragma unroll
        for (int kh = 0; kh < 4; ++kh) {
            const int kk = kh * 32 + quad * 8;
            bf16x8 af[2], alf[2], bhf[4];
            #pragma unroll
            for (int mi = 0; mi < 2; ++mi) {
                int r = w * 32 + mi * 16 + l16;
                af[mi]  = *(const bf16x8*)&AhS[r][kk];
                alf[mi] = *(const bf16x8*)&AlS[r][kk];
            }
            #pragma unroll
            for (int ni = 0; ni < 4; ++ni)
                bhf[ni] = *(const bf16x8*)&BhS[ni * 16 + l16][kk];
            #pragma unroll
            for (int mi = 0; mi < 2; ++mi)
                #pragma unroll
                for (int ni = 0; ni < 4; ++ni) {
                    acc[mi][ni] = MFMA(af[mi], bhf[ni], acc[mi][ni]);
                    acc[mi][ni] = MFMA(alf[mi], bhf[ni], acc[mi][ni]);
                }
        }
    }
    #pragma unroll
    for (int mi = 0; mi < 2; ++mi)
        #pragma unroll
        for (int ni = 0; ni < 4; ++ni)
            #pragma unroll
            for (int r = 0; r < 4; ++r) {
                int gm = bm + w * 32 + mi * 16 + quad * 4 + r;
                int gn = bn + ni * 16 + l16;
                float v = acc[mi][ni][r] + bias[gn];
                if (resid) {
                    size_t o2 = (size_t)gm * K + gn;
                    float prev = bf2f(Ah[o2]) + bf2f(Al[o2]);
                    v = prev + fmaxf(v, 0.0f);
                }
                size_t o = (size_t)gm * Nn + gn;
                if (C) C[o] = v;
                u16 hh, ll;
                if (rtn_out) split1(v, hh, ll);
                else         split1_trunc(v, hh, ll);
                Ch[o] = hh; Cl[o] = ll;
            }
}

// ---------------------------------------------------------------------------
// Distance via SINGLE RTN-bf16 MFMA, fused stats, pos+neg merged. A fp16.
// Tile 128(M)x64(N), 4 waves each owning 32 rows x full 64-col width:
// acc[2][4] = 32 regs/wave (was 64) -> 4 waves/SIMD occupancy, grid 4096.
// B-operand column permutation (proven): fragment slot (ni,l16) holds
// j = l16*4+ni -> one f16x4 store per (mi,r), ny as one float4 load.
// Row-stat reductions via DPP (VALU) instead of shfl_xor (DS).
// ---------------------------------------------------------------------------
__global__ __launch_bounds__(256) void dist_fused(
    const u16* __restrict__ Xh, const u16* __restrict__ Yh,
    const float* __restrict__ nx, const float* __restrict__ ny,
    f16* __restrict__ Apos, f16* __restrict__ Aneg,
    float* __restrict__ prm_p, float* __restrict__ prs_p,
    float* __restrict__ pcm_p, float* __restrict__ pcs_p,
    float* __restrict__ prm_n, float* __restrict__ prs_n)
{
    const int mat = blockIdx.z;                // 0: X vs Y ; 1: X vs X
    const u16* Bhp = mat ? Xh : Yh;
    const float* nb = mat ? nx : ny;
    f16* Out = mat ? Aneg : Apos;
    float* prm = mat ? prm_n : prm_p;
    float* prs = mat ? prs_n : prs_p;

    __shared__ u16 XhS[128][40], YhS[64][40];
    const int t = threadIdx.x;
    const int w = t >> 6, lane = t & 63;
    const int quad = lane >> 4, l16 = lane & 15;
    const int bm = blockIdx.y * 128, bn = blockIdx.x * 64;
    f32x4 acc[2][4] = {};

    for (int k0 = 0; k0 < D; k0 += 32) {
        __syncthreads();
        #pragma unroll
        for (int p = 0; p < 3; ++p) {
            int slot = t + p * 256;            // 768 slots = (128 + 64) rows x 4 octets
            if (slot < 512) {
                int row = slot >> 2, koff = (slot & 3) << 3;
                *(u16x8*)&XhS[row][koff] =
                    *(const u16x8*)(Xh + (size_t)(bm + row) * D + k0 + koff);
            } else {
                int s2 = slot - 512;
                int row = s2 >> 2, koff = (s2 & 3) << 3;
                int pr = ((row & 3) << 4) | (row >> 2);
                int kf = koff ^ (((pr >> 4) & 3) << 3);
                *(u16x8*)&YhS[pr][kf] =
                    *(const u16x8*)(Bhp + (size_t)(bn + row) * D + k0 + koff);
            }
        }
        __syncthreads();
        bf16x8 af[2], bhf[4];
        #pragma unroll
        for (int mi = 0; mi < 2; ++mi)
            af[mi] = *(const bf16x8*)&XhS[w * 32 + mi * 16 + l16][quad * 8];
        #pragma unroll
        for (int ni = 0; ni < 4; ++ni)
            bhf[ni] = *(const bf16x8*)
                &YhS[ni * 16 + l16][(quad * 8) ^ ((ni & 3) << 3)];
        #pragma unroll
        for (int mi = 0; mi < 2; ++mi)
            #pragma unroll
            for (int ni = 0; ni < 4; ++ni)
                acc[mi][ni] = MFMA(af[mi], bhf[ni], acc[mi][ni]);
    }
    // lane's 4 j's are contiguous: jb..jb+3
    const int jb = bn + (l16 << 2);
    const float4 nyv = *(const float4*)(nb + jb);
    const float nyl[4] = {nyv.x, nyv.y, nyv.z, nyv.w};
    // --- transform in place + vector store ---
    #pragma unroll
    for (int mi = 0; mi < 2; ++mi)
        #pragma unroll
        for (int r = 0; r < 4; ++r) {
            int gm = bm + w * 32 + mi * 16 + quad * 4 + r;
            float nxm = nx[gm];
            f16x4 ov;
            #pragma unroll
            for (int ni = 0; ni < 4; ++ni) {
                float d2 = nxm + nyl[ni] - 2.0f * acc[mi][ni][r];
                float a = -sqrtf(fmaxf(d2, 0.0f)) * INV_T;
                if (mat && gm == jb + ni) a = -5.0e6f;
                acc[mi][ni][r] = a;
                ov[ni] = (f16)a;
            }
            *(f16x4*)(Out + (size_t)gm * N + jb) = ov;
        }
    // --- row partials: per (mi,r), reduce over ni (in-lane) + l16 (DPP) ---
    const int ct = blockIdx.x;
    #pragma unroll
    for (int mi = 0; mi < 2; ++mi)
        #pragma unroll
        for (int r = 0; r < 4; ++r) {
            float m = fmaxf(fmaxf(acc[mi][0][r], acc[mi][1][r]),
                            fmaxf(acc[mi][2][r], acc[mi][3][r]));
            m = fmaxf(m, dppf<0xB1>(m));
            m = fmaxf(m, dppf<0x4E>(m));
            m = fmaxf(m, dppf<0x141>(m));
            m = fmaxf(m, dppf<0x140>(m));
            float s = __expf(acc[mi][0][r] - m) + __expf(acc[mi][1][r] - m)
                    + __expf(acc[mi][2][r] - m) + __expf(acc[mi][3][r] - m);
            s += dppf<0xB1>(s);
            s += dppf<0x4E>(s);
            s += dppf<0x141>(s);
            s += dppf<0x140>(s);
            if (l16 == 0) {
                int grow = bm + w * 32 + mi * 16 + quad * 4 + r;
                prm[(size_t)ct * N + grow] = m;
                prs[(size_t)ct * N + grow] = s;
            }
        }
    // --- col partials (pos only): per ni, in-lane over (mi,r) + quad shfl ---
    if (mat == 0) {
        const int rt = blockIdx.y * 4 + w;      // 32-row tiles -> 128 planes
        #pragma unroll
        for (int ni = 0; ni < 4; ++ni) {
            float m = -3.0e38f;
            #pragma unroll
            for (int mi = 0; mi < 2; ++mi)
                #pragma unroll
                for (int r = 0; r < 4; ++r)
                    m = fmaxf(m, acc[mi][ni][r]);
            m = fmaxf(m, __shfl_xor(m, 16));
            m = fmaxf(m, __shfl_xor(m, 32));
            float s = 0.f;
            #pragma unroll
            for (int mi = 0; mi < 2; ++mi)
                #pragma unroll
                for (int r = 0; r < 4; ++r)
                    s += __expf(acc[mi][ni][r] - m);
            s += __shfl_xor(s, 16);
            s += __shfl_xor(s, 32);
            if (quad == 0) {
                pcm_p[(size_t)rt * N + jb + ni] = m;
                pcs_p[(size_t)rt * N + jb + ni] = s;
            }
        }
    }
}

// ---------------------------------------------------------------------------
// Combine partials into row/col softmax stats — parallel (192 x 256).
// Row stats: 64 col-tiles each of pos/neg. Col stats: pos = 128 row-tiles
// (pcm_p), neg = 64 (prm_n, symmetry).
// ---------------------------------------------------------------------------
__global__ __launch_bounds__(256) void stats_combine(
    const float* __restrict__ prm_p, const float* __restrict__ prs_p,
    const float* __restrict__ prm_n, const float* __restrict__ prs_n,
    const float* __restrict__ pcm_p, const float* __restrict__ pcs_p,
    float* __restrict__ m_row, float* __restrict__ isr,
    float* __restrict__ m_col, float* __restrict__ isc)
{
    __shared__ float Ms[4][64], Ss[4][64];
    const int t = threadIdx.x;
    const int g = t >> 6, l = t & 63;
    const int idx = blockIdx.x * 64 + l;
    const int c0 = g * 16;

    float m = -3.0e38f, s = 0.f;
    if (idx < N) {
        const int i = idx;
        #pragma unroll 4
        for (int c = c0; c < c0 + 16; ++c) {
            m = fmaxf(m, prm_p[(size_t)c * N + i]);
            m = fmaxf(m, prm_n[(size_t)c * N + i]);
        }
        #pragma unroll 4
        for (int c = c0; c < c0 + 16; ++c) {
            s += prs_p[(size_t)c * N + i] * __expf(prm_p[(size_t)c * N + i] - m);
            s += prs_n[(size_t)c * N + i] * __expf(prm_n[(size_t)c * N + i] - m);
        }
    } else {
        const int mat = (idx - N) >> 12;
        const int j = idx & (N - 1);
        const float* pm = mat ? prm_n : pcm_p;
        const float* ps = mat ? prs_n : pcs_p;
        const int cnt = mat ? 16 : 32;
        const int cb = g * cnt;
        #pragma unroll 4
        for (int c = cb; c < cb + cnt; ++c)
            m = fmaxf(m, pm[(size_t)c * N + j]);
        #pragma unroll 4
        for (int c = cb; c < cb + cnt; ++c)
            s += ps[(size_t)c * N + j] * __expf(pm[(size_t)c * N + j] - m);
    }
    Ms[g][l] = m; Ss[g][l] = s;
    __syncthreads();
    if (g == 0) {
        float m0 = Ms[0][l], m1 = Ms[1][l], m2 = Ms[2][l], m3 = Ms[3][l];
        float mm = fmaxf(fmaxf(m0, m1), fmaxf(m2, m3));
        float ss = Ss[0][l] * __expf(m0 - mm) + Ss[1][l] * __expf(m1 - mm)
                 + Ss[2][l] * __expf(m2 - mm) + Ss[3][l] * __expf(m3 - mm);
        if (idx < N) {
            m_row[idx] = mm;
            isr[idx] = 1.0f / sqrtf(ss);
        } else {
            const int mat = (idx - N) >> 12;
            const int j = idx & (N - 1);
            m_col[mat * N + j] = mm;
            isc[mat * N + j] = 1.0f / sqrtf(ss);
        }
    }
}

// ---------------------------------------------------------------------------
// pv via MFMA (proven form): A fp16 tile -> P (fp32 rowsums -> sp/sn),
// split P (trunc) to bf16 hi/lo in LDS, MFMA P @ B (B = RTN-bf16 transposed
// [d][j], hi only). Unpermuted staging; scalar C-stores (lane-coalesced).
// ---------------------------------------------------------------------------
__global__ __launch_bounds__(256) void pv_mfma(
    const f16* __restrict__ Apos, const f16* __restrict__ Aneg,
    const u16* __restrict__ Yth, const u16* __restrict__ Xth,
    const float* __restrict__ m_row, const float* __restrict__ isr,
    const float* __restrict__ m_col, const float* __restrict__ isc,
    float* __restrict__ u_part, float* __restrict__ w_part,
    float* __restrict__ sp_arr, float* __restrict__ sn_arr)
{
    const int mat = blockIdx.z;
    const f16* Am = mat ? Aneg : Apos;
    const u16* Bh = mat ? Xth : Yth;
    const float* mc = m_col + mat * N;
    const float* ic = isc + mat * N;
    float* Cp = (mat ? w_part : u_part) + (size_t)blockIdx.y * (N * D);
    float* spn = mat ? sn_arr : sp_arr;

    __shared__ u16 BhS[128][72];
    __shared__ u16 PhS[64][72], PlS[64][72];
    __shared__ float mrS[64], isrS[64];

    const int t = threadIdx.x;
    const int w = t >> 6, lane = t & 63;
    const int quad = lane >> 4, l16 = lane & 15;
    const int bm = blockIdx.x * 64;
    const int jbase = blockIdx.y * (N / KSPLIT);
    const int arow = t >> 4;          // 0..15
    const int aj = (t & 15) << 2;     // 0..60

    if (t < 64) { mrS[t] = m_row[bm + t]; isrS[t] = isr[bm + t]; }

    f32x4 acc[8] = {};
    float rs[4] = {0.f, 0.f, 0.f, 0.f};

    for (int jt = 0; jt < (N / KSPLIT) / 64; ++jt) {
        const int j0 = jbase + jt * 64;
        __syncthreads();   // protect previous iteration's LDS reads (+ mrS init)
        #pragma unroll
        for (int p = 0; p < 4; ++p) {
            int slot = t + p * 256;
            int d = slot >> 3, joff = (slot & 7) << 3;
            *(u16x8*)&BhS[d][joff] = *(const u16x8*)(Bh + (size_t)d * N + j0 + joff);
        }
        float4 mcv = *(const float4*)(mc + j0 + aj);
        float4 icv = *(const float4*)(ic + j0 + aj);
        #pragma unroll
        for (int s = 0; s < 4; ++s) {
            int row = arow + s * 16;
            f16x4 av = *(const f16x4*)(Am + (size_t)(bm + row) * N + j0 + aj);
            float mr = mrS[row], sr = isrS[row];
            float p0 = __expf((float)av.x - 0.5f * (mr + mcv.x)) * (sr * icv.x);
            float p1 = __expf((float)av.y - 0.5f * (mr + mcv.y)) * (sr * icv.y);
            float p2 = __expf((float)av.z - 0.5f * (mr + mcv.z)) * (sr * icv.z);
            float p3 = __expf((float)av.w - 0.5f * (mr + mcv.w)) * (sr * icv.w);
            rs[s] += p0 + p1 + p2 + p3;
            ushort4 hv, lv;
            split1_trunc(p0, hv.x, lv.x); split1_trunc(p1, hv.y, lv.y);
            split1_trunc(p2, hv.z, lv.z); split1_trunc(p3, hv.w, lv.w);
            *(ushort4*)&PhS[row][aj] = hv;
            *(ushort4*)&PlS[row][aj] = lv;
        }
        __syncthreads();
        #pragma unroll
        for (int ks = 0; ks < 2; ++ks) {
            const int kk = ks * 32 + quad * 8;
            bf16x8 ph = *(const bf16x8*)&PhS[w * 16 + l16][kk];
            bf16x8 pl = *(const bf16x8*)&PlS[w * 16 + l16][kk];
            #pragma unroll
            for (int ni = 0; ni < 8; ++ni) {
                bf16x8 bh = *(const bf16x8*)&BhS[ni * 16 + l16][kk];
                acc[ni] = MFMA(ph, bh, acc[ni]);
                acc[ni] = MFMA(pl, bh, acc[ni]);
            }
        }
    }
    #pragma unroll
    for (int ni = 0; ni < 8; ++ni)
        #pragma unroll
        for (int r = 0; r < 4; ++r) {
            int row = w * 16 + quad * 4 + r;
            int col = ni * 16 + l16;
            Cp[(size_t)(bm + row) * D + col] = acc[ni][r];
        }
    #pragma unroll
    for (int s = 0; s < 4; ++s) {
        float v = rs[s];
        v += __shfl_xor(v, 1); v += __shfl_xor(v, 2);
        v += __shfl_xor(v, 4); v += __shfl_xor(v, 8);
        if (l16 == 0) atomicAdd(&spn[bm + arow + s * 16], v);
    }
}

// ---------------------------------------------------------------------------
// Sum split-K partials, V = sn*u - sp*sn*w, accumulate sum(V^2).
// ---------------------------------------------------------------------------
__global__ __launch_bounds__(256) void final_reduce(const float* __restrict__ u_part,
    const float* __restrict__ w_part, const float* __restrict__ sp_arr,
    const float* __restrict__ sn_arr, double* __restrict__ acc_out)
{
    __shared__ float red[256];
    const int t = threadIdx.x;
    const int idx = blockIdx.x * 256 + t;
    float u = 0.f, w = 0.f;
    #pragma unroll
    for (int c = 0; c < KSPLIT; ++c) {
        u += u_part[(size_t)c * (N * D) + idx];
        w += w_part[(size_t)c * (N * D) + idx];
    }
    const int i = idx >> 7;
    const float sn = sn_arr[i];
    const float v = sn * u - sp_arr[i] * sn * w;
    red[t] = v * v; __syncthreads();
    for (int s = 128; s > 0; s >>= 1) { if (t < s) red[t] += red[t + s]; __syncthreads(); }
    if (!t) atomicAdd(acc_out, (double)red[0]);
}

__global__ void finalize(const double* __restrict__ acc, float* __restrict__ out)
{
    out[0] = (float)(*acc * (1.0 / ((double)N * (double)D)));
}

// ---------------------------------------------------------------------------
extern "C" void kernel_launch(void* const* d_in, const int* in_sizes, int n_in,
                              void* d_out, int out_size, void* d_ws, size_t ws_size,
                              hipStream_t stream)
{
    const float* y_pos = (const float*)d_in[0];
    const float* eps   = (const float*)d_in[1];
    const float* W_in  = (const float*)d_in[2];
    const float* b_in  = (const float*)d_in[3];
    const float* W_blk = (const float*)d_in[4];
    const float* b_blk = (const float*)d_in[5];
    const float* W_out = (const float*)d_in[6];
    const float* b_out = (const float*)d_in[7];
    float* out = (float*)d_out;
    (void)in_sizes; (void)n_in; (void)out_size; (void)ws_size;

    char* p = (char*)d_ws;
    auto alloc = [&](size_t bytes) {
        char* r = p;
        p += (bytes + 255) & ~(size_t)255;
        return r;
    };
    // --- small arrays ---
    double* acc  = (double*)alloc(8);
    float* sp     = (float*)alloc(N * 4);
    float* sn     = (float*)alloc(N * 4);
    float* m_row  = (float*)alloc(N * 4);
    float* isr    = (float*)alloc(N * 4);
    float* m_col  = (float*)alloc(2 * N * 4);
    float* isc    = (float*)alloc(2 * N * 4);
    float* nx     = (float*)alloc(N * 4);
    float* ny     = (float*)alloc(N * 4);
    // --- eh/el (2 MB; only live through the first gen layer) ---
    u16* eh = (u16*)alloc((size_t)N * D * 2);
    u16* el = (u16*)alloc((size_t)N * D * 2);
    // --- xo fp32 + bf16 x/y arrays ---
    float* xo  = (float*)alloc((size_t)N * D * 4);
    u16* xh    = (u16*)alloc((size_t)N * D * 2);
    u16* xl    = (u16*)alloc((size_t)N * D * 2);
    u16* xth   = (u16*)alloc((size_t)N * D * 2);
    u16* yh    = (u16*)alloc((size_t)N * D * 2);
    u16* yl    = (u16*)alloc((size_t)N * D * 2);
    u16* yth   = (u16*)alloc((size_t)N * D * 2);
    // --- generator region (21 MB): activations + weights; later aliased by
    //     stats partials (8 MB) then u/w_part (16 MB) ---
    char* genreg = alloc((size_t)(4 * (size_t)N * H * 2
                                + 2 * (size_t)H * D * 2
                                + 2 * (size_t)4 * H * H * 2
                                + 2 * (size_t)D * H * 2));
    u16* x0h = (u16*)genreg;
    u16* x0l = x0h + (size_t)N * H;
    u16* x1h = x0l + (size_t)N * H;
    u16* x1l = x1h + (size_t)N * H;
    u16* wih = x1l + (size_t)N * H;
    u16* wil = wih + (size_t)H * D;
    u16* wbh = wil + (size_t)H * D;
    u16* wbl = wbh + (size_t)4 * H * H;
    u16* woh = wbl + (size_t)4 * H * H;
    u16* wol = woh + (size_t)D * H;
    // aliases (disjoint lifetimes, stream-ordered):
    float* prm_p = (float*)genreg;                 // 64*N each = 1 MB
    float* prs_p = prm_p + 64 * N;
    float* prm_n = prs_p + 64 * N;
    float* prs_n = prm_n + 64 * N;
    float* pcm_p = prs_n + 64 * N;                 // 128*N = 2 MB each
    float* pcs_p = pcm_p + 128 * N;                // ends at 8 MB
    float* u_part = (float*)genreg;                // KSPLIT*N*D = 8 MB
    float* w_part = u_part + (size_t)KSPLIT * N * D;
    // --- the big ones (64 MB, fp16) ---
    f16* Apos = (f16*)alloc((size_t)N * N * 2);
    f16* Aneg = (f16*)alloc((size_t)N * N * 2);

    // --- split inputs/weights to bf16 hi/lo (RTN) + workspace init (y==5) ---
    SplitArgs sa;
    sa.d[0] = { eps,   eh,  el,  N * D };
    sa.d[1] = { y_pos, yh,  yl,  N * D };
    sa.d[2] = { W_in,  wih, wil, H * D };
    sa.d[3] = { W_blk, wbh, wbl, 4 * H * H };
    sa.d[4] = { W_out, woh, wol, D * H };
    split_multi<<<dim3(1024, 6), 256, 0, stream>>>(sa, acc, sp, sn, nx, ny);

    // --- generator (MFMA, act hi/lo x W-RTN, 64x64 blocks, BK=128) ---
    dim3 gh(H / 64, N / 64);
    gen_gemm<<<gh, 128, 0, stream>>>(eh, el, wih, b_in,
                                     nullptr, x0h, x0l, N, H, D, 0, 0);
    gen_gemm<<<gh, 128, 0, stream>>>(x0h, x0l, wbh + 0 * H * H,
                                     b_blk + 0 * H, nullptr, x1h, x1l, N, H, H, 1, 0);
    gen_gemm<<<gh, 128, 0, stream>>>(x1h, x1l, wbh + 1 * H * H,
                                     b_blk + 1 * H, nullptr, x0h, x0l, N, H, H, 1, 0);
    gen_gemm<<<gh, 128, 0, stream>>>(x0h, x0l, wbh + 2 * H * H,
                                     b_blk + 2 * H, nullptr, x1h, x1l, N, H, H, 1, 0);
    gen_gemm<<<gh, 128, 0, stream>>>(x1h, x1l, wbh + 3 * H * H,
                                     b_blk + 3 * H, nullptr, x0h, x0l, N, H, H, 1, 0);
    gen_gemm<<<dim3(D / 64, N / 64), 128, 0, stream>>>(x0h, x0l, woh, b_out,
                                     xo, xh, xl, N, D, H, 0, 1);

    // --- RTN transposes + fused row norms ---
    transpose_rtn<<<dim3(N / 32, D / 32, 2), 256, 0, stream>>>(
        xo, y_pos, xth, yth, nx, ny);

    // --- distance matrices (fp16, single-bf16 MFMA) + fused stats ---
    dist_fused<<<dim3(N / 64, N / 128, 2), 256, 0, stream>>>(
        xh, yh, nx, ny, Apos, Aneg,
        prm_p, prs_p, pcm_p, pcs_p, prm_n, prs_n);

    // --- combine partials into m_row/isr, m_col/isc (parallel) ---
    stats_combine<<<192, 256, 0, stream>>>(prm_p, prs_p, prm_n, prs_n,
                                           pcm_p, pcs_p,
                                           m_row, isr, m_col, isc);

    // --- P@V via MFMA (P built on the fly; sp/sn fp32 via atomics) ---
    pv_mfma<<<dim3(N / 64, KSPLIT, 2), 256, 0, stream>>>(Apos, Aneg,
        yth, xth, m_row, isr, m_col, isc, u_part, w_part, sp, sn);

    // --- combine partials, V^2 reduction ---
    final_reduce<<<(N * D) / 256, 256, 0, stream>>>(u_part, w_part, sp, sn, acc);
    finalize<<<1, 1, 0, stream>>>(acc, out);
}

// Round 2
// 295.085 us; speedup vs baseline: 1.0616x; 1.0143x over previous
//
#include <hip/hip_runtime.h>
#include <math.h>

#define N 4096
#define D 128
#define H 512
#define KSPLIT 4
// 5 * log2(e): distances stored in log2 domain so all softmax exps are raw v_exp_f32
#define SC_LOG2 7.2134752044f

typedef short bf16x8 __attribute__((ext_vector_type(8)));
typedef float f32x4 __attribute__((ext_vector_type(4)));
typedef unsigned short u16x8 __attribute__((ext_vector_type(8)));
typedef unsigned short u16;
typedef _Float16 f16;
typedef _Float16 f16x4 __attribute__((ext_vector_type(4)));

#define MFMA(a, b, c) __builtin_amdgcn_mfma_f32_16x16x32_bf16((a), (b), (c), 0, 0, 0)

__device__ __forceinline__ float fexp2(float x)
{
#if __has_builtin(__builtin_amdgcn_exp2f)
    return __builtin_amdgcn_exp2f(x);
#else
    return exp2f(x);
#endif
}

__device__ __forceinline__ float bf2f(u16 h)
{
    return __uint_as_float(((unsigned)h) << 16);
}

// Round-to-nearest bf16 (unbiased) — for operands whose hi is used ALONE.
__device__ __forceinline__ u16 rtn_bf16(float v)
{
    unsigned u = __float_as_uint(v);
    return (u16)((u + 0x7FFFu + ((u >> 16) & 1u)) >> 16);
}

// RTN split (hi usable alone; lo compensates). Cold paths + last gen layer.
__device__ __forceinline__ void split1(float v, u16& h, u16& l)
{
    u16 hh = rtn_bf16(v);
    float r = v - bf2f(hh);
    h = hh;
    l = rtn_bf16(r);
}

// Cheap truncation split (3 ops); hi+lo pair accuracy identical.
__device__ __forceinline__ void split1_trunc(float v, u16& h, u16& l)
{
    unsigned bv = __float_as_uint(v);
    unsigned hb = bv & 0xFFFF0000u;
    float r = v - __uint_as_float(hb);
    h = (u16)(hb >> 16);
    l = (u16)(__float_as_uint(r) >> 16);
}

// DPP cross-lane move within 16-lane rows (pure VALU — no DS latency).
// 0xB1 = quad_perm [1,0,3,2] (xor1), 0x4E = quad_perm [2,3,0,1] (xor2),
// 0x141 = row_half_mirror (≡xor4 after quad reduce), 0x140 = row_mirror (≡xor8).
template <int CTRL>
__device__ __forceinline__ float dppf(float x)
{
    int r = __builtin_amdgcn_update_dpp(0, __float_as_int(x), CTRL, 0xF, 0xF, true);
    return __int_as_float(r);
}

// ---------------------------------------------------------------------------
// One-shot splitter for 5 flat fp32 arrays -> bf16 hi/lo (RTN, cold) and,
// on the y==5 plane, workspace init (acc/sp/sn/nx/ny).
// ---------------------------------------------------------------------------
struct SplitDesc { const float* src; u16* h; u16* l; int n; };
struct SplitArgs { SplitDesc d[5]; };

__global__ __launch_bounds__(256) void split_multi(SplitArgs args,
    double* acc, float* sp, float* sn, float* nx, float* ny)
{
    if (blockIdx.y == 5) {
        int idx = blockIdx.x * 256 + threadIdx.x;
        if (idx == 0) *acc = 0.0;
        if (idx < N) { sp[idx] = 0.f; sn[idx] = 0.f; nx[idx] = 0.f; ny[idx] = 0.f; }
        return;
    }
    SplitDesc de = args.d[blockIdx.y];
    int idx = (blockIdx.x * 256 + threadIdx.x) * 4;
    if (idx >= de.n) return;
    float4 v = *(const float4*)(de.src + idx);
    ushort4 hv, lv;
    split1(v.x, hv.x, lv.x); split1(v.y, hv.y, lv.y);
    split1(v.z, hv.z, lv.z); split1(v.w, hv.w, lv.w);
    *(ushort4*)(de.h + idx) = hv;
    *(ushort4*)(de.l + idx) = lv;
}

// ---------------------------------------------------------------------------
// Transpose + RTN-bf16 + fused row-norm partials (atomicAdd into nx/ny).
// ---------------------------------------------------------------------------
__global__ __launch_bounds__(256) void transpose_rtn(
    const float* __restrict__ X, const float* __restrict__ Y,
    u16* __restrict__ Xth, u16* __restrict__ Yth,
    float* __restrict__ nx, float* __restrict__ ny)
{
    const float* src = blockIdx.z ? Y : X;
    u16* th = blockIdx.z ? Yth : Xth;
    float* nrm = blockIdx.z ? ny : nx;
    __shared__ float tile[32][33];
    const int t = threadIdx.x;
    const int r0 = blockIdx.x * 32, c0 = blockIdx.y * 32;
    {
        int rit = t >> 3, coff = (t & 7) * 4;
        float4 v = *(const float4*)(src + (size_t)(r0 + rit) * D + c0 + coff);
        tile[rit][coff + 0] = v.x; tile[rit][coff + 1] = v.y;
        tile[rit][coff + 2] = v.z; tile[rit][coff + 3] = v.w;
        float sq = v.x * v.x + v.y * v.y + v.z * v.z + v.w * v.w;
        sq += __shfl_xor(sq, 1);
        sq += __shfl_xor(sq, 2);
        sq += __shfl_xor(sq, 4);
        if ((t & 7) == 0) atomicAdd(&nrm[r0 + rit], sq);
    }
    __syncthreads();
    {
        int cit = t >> 3, roff = (t & 7) * 4;
        ushort4 hv;
        hv.x = rtn_bf16(tile[roff + 0][cit]);
        hv.y = rtn_bf16(tile[roff + 1][cit]);
        hv.z = rtn_bf16(tile[roff + 2][cit]);
        hv.w = rtn_bf16(tile[roff + 3][cit]);
        *(ushort4*)(th + (size_t)(c0 + cit) * N + r0 + roff) = hv;
    }
}

// ---------------------------------------------------------------------------
// Generator GEMM: A = activations hi/lo bf16 pair, B = weights single RTN
// bf16. Tile 64x64, BK=128 (4 barriers for K=512, 0 loop barriers for
// K=128 — chain is barrier-drain-bound at grid-capped 2 blocks/CU),
// 128 threads (2 waves x 32 rows, proven micro-shape per k-quarter).
// rtn_out=1 on the last layer only.
// ---------------------------------------------------------------------------
__global__ __launch_bounds__(128) void gen_gemm(
    const u16* __restrict__ Ah, const u16* __restrict__ Al,
    const u16* __restrict__ Bh,
    const float* __restrict__ bias,
    float* __restrict__ C, u16* __restrict__ Ch, u16* __restrict__ Cl,
    int M, int Nn, int K, int resid, int rtn_out)
{
    __shared__ u16 AhS[64][136], AlS[64][136];
    __shared__ u16 BhS[64][136];
    const int t = threadIdx.x;
    const int w = t >> 6, lane = t & 63;
    const int quad = lane >> 4, l16 = lane & 15;
    const int bm = blockIdx.y * 64, bn = blockIdx.x * 64;
    f32x4 acc[2][4] = {};

    for (int k0 = 0; k0 < K; k0 += 128) {
        __syncthreads();
        #pragma unroll
        for (int p = 0; p < 8; ++p) {
            int slot = t + p * 128;          // 1024 slots = 64 rows x 16 k-octets
            int row = slot >> 4, koff = (slot & 15) << 3;
            size_t ga = (size_t)(bm + row) * K + k0 + koff;
            size_t gb = (size_t)(bn + row) * K + k0 + koff;
            *(u16x8*)&AhS[row][koff] = *(const u16x8*)(Ah + ga);
            *(u16x8*)&AlS[row][koff] = *(const u16x8*)(Al + ga);
            *(u16x8*)&BhS[row][koff] = *(const u16x8*)(Bh + gb);
        }
        __syncthreads();
        #pragma unroll
        for (int kh = 0; kh < 4; ++kh) {
            const int kk = kh * 32 + quad * 8;
            bf16x8 af[2], alf[2], bhf[4];
            #pragma unroll
            for (int mi = 0; mi < 2; ++mi) {
                int r = w * 32 + mi * 16 + l16;
                af[mi]  = *(const bf16x8*)&AhS[r][kk];
                alf[mi] = *(const bf16x8*)&AlS[r][kk];
            }
            #pragma unroll
            for (int ni = 0; ni < 4; ++ni)
                bhf[ni] = *(const bf16x8*)&BhS[ni * 16 + l16][kk];
            #pragma unroll
            for (int mi = 0; mi < 2; ++mi)
                #pragma unroll
                for (int ni = 0; ni < 4; ++ni) {
                    acc[mi][ni] = MFMA(af[mi], bhf[ni], acc[mi][ni]);
                    acc[mi][ni] = MFMA(alf[mi], bhf[ni], acc[mi][ni]);
                }
        }
    }
    #pragma unroll
    for (int mi = 0; mi < 2; ++mi)
        #pragma unroll
        for (int ni = 0; ni < 4; ++ni)
            #pragma unroll
            for (int r = 0; r < 4; ++r) {
                int gm = bm + w * 32 + mi * 16 + quad * 4 + r;
                int gn = bn + ni * 16 + l16;
                float v = acc[mi][ni][r] + bias[gn];
                if (resid) {
                    size_t o2 = (size_t)gm * K + gn;
                    float prev = bf2f(Ah[o2]) + bf2f(Al[o2]);
                    v = prev + fmaxf(v, 0.0f);
                }
                size_t o = (size_t)gm * Nn + gn;
                if (C) C[o] = v;
                u16 hh, ll;
                if (rtn_out) split1(v, hh, ll);
                else         split1_trunc(v, hh, ll);
                Ch[o] = hh; Cl[o] = ll;
            }
}

// ---------------------------------------------------------------------------
// Distance via SINGLE RTN-bf16 MFMA, fused stats, pos+neg merged. A fp16,
// stored in LOG2 domain (a = -dist * 5*log2e) so every softmax exp is a
// bare v_exp_f32.
// Tile 128(M)x128(N), 4 waves each owning 32 rows x full 128 cols:
// acc[2][8]. Per-element VALU cut vs 128x64: trees/staging amortized 2x,
// and a single wave-shared shift mq feeds BOTH row partials (rescaled by
// exp2(mq-m_row), 8 exp/lane) and col partials (shift = mq, 0 extra exp).
// B-operand column permutation (proven): fragment slot (nn,l16) in each
// 64-col half holds j = half*64 + l16*4 + nn.
// ---------------------------------------------------------------------------
__global__ __launch_bounds__(256) void dist_fused(
    const u16* __restrict__ Xh, const u16* __restrict__ Yh,
    const float* __restrict__ nx, const float* __restrict__ ny,
    f16* __restrict__ Apos, f16* __restrict__ Aneg,
    float* __restrict__ prm_p, float* __restrict__ prs_p,
    float* __restrict__ pcm_p, float* __restrict__ pcs_p,
    float* __restrict__ prm_n, float* __restrict__ prs_n)
{
    const int mat = blockIdx.z;                // 0: X vs Y ; 1: X vs X
    const u16* Bhp = mat ? Xh : Yh;
    const float* nb = mat ? nx : ny;
    f16* Out = mat ? Aneg : Apos;
    float* prm = mat ? prm_n : prm_p;
    float* prs = mat ? prs_n : prs_p;

    __shared__ u16 XhS[128][40], YhS[128][40];
    const int t = threadIdx.x;
    const int w = t >> 6, lane = t & 63;
    const int quad = lane >> 4, l16 = lane & 15;
    const int bm = blockIdx.y * 128, bn = blockIdx.x * 128;
    f32x4 acc[2][8] = {};

    for (int k0 = 0; k0 < D; k0 += 32) {
        __syncthreads();
        #pragma unroll
        for (int p = 0; p < 2; ++p) {
            int slot = t + p * 256;            // 512 slots = 128 rows x 4 octets
            int row = slot >> 2, koff = (slot & 3) << 3;
            *(u16x8*)&XhS[row][koff] =
                *(const u16x8*)(Xh + (size_t)(bm + row) * D + k0 + koff);
        }
        #pragma unroll
        for (int p = 0; p < 2; ++p) {
            int slot = t + p * 256;
            int row = slot >> 2, koff = (slot & 3) << 3;
            int pr = ((row & 3) << 4) | ((row & 63) >> 2) | (row & 64);
            int kf = koff ^ (((pr >> 4) & 3) << 3);
            *(u16x8*)&YhS[pr][kf] =
                *(const u16x8*)(Bhp + (size_t)(bn + row) * D + k0 + koff);
        }
        __syncthreads();
        bf16x8 af[2], bhf[8];
        #pragma unroll
        for (int mi = 0; mi < 2; ++mi)
            af[mi] = *(const bf16x8*)&XhS[w * 32 + mi * 16 + l16][quad * 8];
        #pragma unroll
        for (int ni = 0; ni < 8; ++ni) {
            int nn = ni & 3, hf = ni >> 2;
            bhf[ni] = *(const bf16x8*)
                &YhS[hf * 64 + nn * 16 + l16][(quad * 8) ^ (nn << 3)];
        }
        #pragma unroll
        for (int mi = 0; mi < 2; ++mi)
            #pragma unroll
            for (int ni = 0; ni < 8; ++ni)
                acc[mi][ni] = MFMA(af[mi], bhf[ni], acc[mi][ni]);
    }
    // lane's 8 j's: jb..jb+3 and jb+64..jb+67
    const int jb = bn + (l16 << 2);
    const float4 n0 = *(const float4*)(nb + jb);
    const float4 n1 = *(const float4*)(nb + jb + 64);
    const float nl[8] = {n0.x, n0.y, n0.z, n0.w, n1.x, n1.y, n1.z, n1.w};
    // --- transform in place (log2 domain) + vector stores ---
    #pragma unroll
    for (int mi = 0; mi < 2; ++mi)
        #pragma unroll
        for (int r = 0; r < 4; ++r) {
            int gm = bm + w * 32 + mi * 16 + quad * 4 + r;
            float nxm = nx[gm];
            f16x4 ov0, ov1;
            #pragma unroll
            for (int nn = 0; nn < 4; ++nn) {
                float d2 = nxm + nl[nn] - 2.0f * acc[mi][nn][r];
                float a = -sqrtf(fmaxf(d2, 0.0f)) * SC_LOG2;
                if (mat && gm == jb + nn) a = -5.0e6f;
                acc[mi][nn][r] = a;
                ov0[nn] = (f16)a;
                float d2b = nxm + nl[4 + nn] - 2.0f * acc[mi][4 + nn][r];
                float ab = -sqrtf(fmaxf(d2b, 0.0f)) * SC_LOG2;
                if (mat && gm == jb + 64 + nn) ab = -5.0e6f;
                acc[mi][4 + nn][r] = ab;
                ov1[nn] = (f16)ab;
            }
            *(f16x4*)(Out + (size_t)gm * N + jb) = ov0;
            *(f16x4*)(Out + (size_t)gm * N + jb + 64) = ov1;
        }
    // --- row maxes: in-lane over 8 ni, then DPP tree over l16 ---
    float m[2][4];
    #pragma unroll
    for (int mi = 0; mi < 2; ++mi)
        #pragma unroll
        for (int r = 0; r < 4; ++r) {
            float v = fmaxf(fmaxf(fmaxf(acc[mi][0][r], acc[mi][1][r]),
                                  fmaxf(acc[mi][2][r], acc[mi][3][r])),
                            fmaxf(fmaxf(acc[mi][4][r], acc[mi][5][r]),
                                  fmaxf(acc[mi][6][r], acc[mi][7][r])));
            v = fmaxf(v, dppf<0xB1>(v));
            v = fmaxf(v, dppf<0x4E>(v));
            v = fmaxf(v, dppf<0x141>(v));
            v = fmaxf(v, dppf<0x140>(v));
            m[mi][r] = v;
        }
    // --- wave-shared shift mq (max over the wave's 32 rows x 128 cols) ---
    float mq = fmaxf(fmaxf(fmaxf(m[0][0], m[0][1]), fmaxf(m[0][2], m[0][3])),
                     fmaxf(fmaxf(m[1][0], m[1][1]), fmaxf(m[1][2], m[1][3])));
    mq = fmaxf(mq, __shfl_xor(mq, 16));
    mq = fmaxf(mq, __shfl_xor(mq, 32));
    // --- single exp pass: e feeds row sums (sig) and col sums (cs) ---
    float sig[2][4] = {};
    float cs[8] = {};
    #pragma unroll
    for (int mi = 0; mi < 2; ++mi)
        #pragma unroll
        for (int ni = 0; ni < 8; ++ni) {
            float e0 = fexp2(acc[mi][ni][0] - mq);
            float e1 = fexp2(acc[mi][ni][1] - mq);
            float e2 = fexp2(acc[mi][ni][2] - mq);
            float e3 = fexp2(acc[mi][ni][3] - mq);
            sig[mi][0] += e0; sig[mi][1] += e1;
            sig[mi][2] += e2; sig[mi][3] += e3;
            cs[ni] += (e0 + e1) + (e2 + e3);
        }
    // --- row partials: DPP tree-sum sig, rescale to row max ---
    const int ct = blockIdx.x;
    #pragma unroll
    for (int mi = 0; mi < 2; ++mi)
        #pragma unroll
        for (int r = 0; r < 4; ++r) {
            float s = sig[mi][r];
            s += dppf<0xB1>(s);
            s += dppf<0x4E>(s);
            s += dppf<0x141>(s);
            s += dppf<0x140>(s);
            s *= fexp2(mq - m[mi][r]);
            if (l16 == 0) {
                int grow = bm + w * 32 + mi * 16 + quad * 4 + r;
                prm[(size_t)ct * N + grow] = m[mi][r];
                prs[(size_t)ct * N + grow] = s;
            }
        }
    // --- col partials (pos only): quad-reduce cs, shift is mq (uniform) ---
    if (mat == 0) {
        const int rt = blockIdx.y * 4 + w;      // 32-row tiles -> 128 planes
        #pragma unroll
        for (int ni = 0; ni < 8; ++ni) {
            cs[ni] += __shfl_xor(cs[ni], 16);
            cs[ni] += __shfl_xor(cs[ni], 32);
        }
        if (quad == 0) {
            float4 c0 = {cs[0], cs[1], cs[2], cs[3]};
            float4 c1 = {cs[4], cs[5], cs[6], cs[7]};
            float4 m4 = {mq, mq, mq, mq};
            *(float4*)(pcs_p + (size_t)rt * N + jb) = c0;
            *(float4*)(pcs_p + (size_t)rt * N + jb + 64) = c1;
            *(float4*)(pcm_p + (size_t)rt * N + jb) = m4;
            *(float4*)(pcm_p + (size_t)rt * N + jb + 64) = m4;
        }
    }
}

// ---------------------------------------------------------------------------
// Combine partials into row/col softmax stats — parallel (192 x 256).
// Row stats: 32 col-tiles each of pos/neg. Col stats: pos = 128 row-tiles
// (pcm_p), neg = 32 (prm_n, symmetry). All in log2 domain.
// ---------------------------------------------------------------------------
__global__ __launch_bounds__(256) void stats_combine(
    const float* __restrict__ prm_p, const float* __restrict__ prs_p,
    const float* __restrict__ prm_n, const float* __restrict__ prs_n,
    const float* __restrict__ pcm_p, const float* __restrict__ pcs_p,
    float* __restrict__ m_row, float* __restrict__ isr,
    float* __restrict__ m_col, float* __restrict__ isc)
{
    __shared__ float Ms[4][64], Ss[4][64];
    const int t = threadIdx.x;
    const int g = t >> 6, l = t & 63;
    const int idx = blockIdx.x * 64 + l;

    float m = -3.0e38f, s = 0.f;
    if (idx < N) {
        const int i = idx;
        const int c0 = g * 8;
        #pragma unroll 4
        for (int c = c0; c < c0 + 8; ++c) {
            m = fmaxf(m, prm_p[(size_t)c * N + i]);
            m = fmaxf(m, prm_n[(size_t)c * N + i]);
        }
        #pragma unroll 4
        for (int c = c0; c < c0 + 8; ++c) {
            s += prs_p[(size_t)c * N + i] * fexp2(prm_p[(size_t)c * N + i] - m);
            s += prs_n[(size_t)c * N + i] * fexp2(prm_n[(size_t)c * N + i] - m);
        }
    } else {
        const int mat = (idx - N) >> 12;
        const int j = idx & (N - 1);
        const float* pm = mat ? prm_n : pcm_p;
        const float* ps = mat ? prs_n : pcs_p;
        const int cnt = mat ? 8 : 32;
        const int cb = g * cnt;
        #pragma unroll 4
        for (int c = cb; c < cb + cnt; ++c)
            m = fmaxf(m, pm[(size_t)c * N + j]);
        #pragma unroll 4
        for (int c = cb; c < cb + cnt; ++c)
            s += ps[(size_t)c * N + j] * fexp2(pm[(size_t)c * N + j] - m);
    }
    Ms[g][l] = m; Ss[g][l] = s;
    __syncthreads();
    if (g == 0) {
        float m0 = Ms[0][l], m1 = Ms[1][l], m2 = Ms[2][l], m3 = Ms[3][l];
        float mm = fmaxf(fmaxf(m0, m1), fmaxf(m2, m3));
        float ss = Ss[0][l] * fexp2(m0 - mm) + Ss[1][l] * fexp2(m1 - mm)
                 + Ss[2][l] * fexp2(m2 - mm) + Ss[3][l] * fexp2(m3 - mm);
        if (idx < N) {
            m_row[idx] = mm;
            isr[idx] = 1.0f / sqrtf(ss);
        } else {
            const int mat = (idx - N) >> 12;
            const int j = idx & (N - 1);
            m_col[mat * N + j] = mm;
            isc[mat * N + j] = 1.0f / sqrtf(ss);
        }
    }
}

// ---------------------------------------------------------------------------
// pv via MFMA (proven form): A fp16 tile (log2 domain) -> P (fp32 rowsums
// -> sp/sn), split P (trunc) to bf16 hi/lo in LDS, MFMA P @ B (B = RTN-bf16
// transposed [d][j], hi only). Unpermuted staging; scalar C-stores.
// ---------------------------------------------------------------------------
__global__ __launch_bounds__(256) void pv_mfma(
    const f16* __restrict__ Apos, const f16* __restrict__ Aneg,
    const u16* __restrict__ Yth, const u16* __restrict__ Xth,
    const float* __restrict__ m_row, const float* __restrict__ isr,
    const float* __restrict__ m_col, const float* __restrict__ isc,
    float* __restrict__ u_part, float* __restrict__ w_part,
    float* __restrict__ sp_arr, float* __restrict__ sn_arr)
{
    const int mat = blockIdx.z;
    const f16* Am = mat ? Aneg : Apos;
    const u16* Bh = mat ? Xth : Yth;
    const float* mc = m_col + mat * N;
    const float* ic = isc + mat * N;
    float* Cp = (mat ? w_part : u_part) + (size_t)blockIdx.y * (N * D);
    float* spn = mat ? sn_arr : sp_arr;

    __shared__ u16 BhS[128][72];
    __shared__ u16 PhS[64][72], PlS[64][72];
    __shared__ float mrS[64], isrS[64];

    const int t = threadIdx.x;
    const int w = t >> 6, lane = t & 63;
    const int quad = lane >> 4, l16 = lane & 15;
    const int bm = blockIdx.x * 64;
    const int jbase = blockIdx.y * (N / KSPLIT);
    const int arow = t >> 4;          // 0..15
    const int aj = (t & 15) << 2;     // 0..60

    if (t < 64) { mrS[t] = m_row[bm + t]; isrS[t] = isr[bm + t]; }

    f32x4 acc[8] = {};
    float rs[4] = {0.f, 0.f, 0.f, 0.f};

    for (int jt = 0; jt < (N / KSPLIT) / 64; ++jt) {
        const int j0 = jbase + jt * 64;
        __syncthreads();   // protect previous iteration's LDS reads (+ mrS init)
        #pragma unroll
        for (int p = 0; p < 4; ++p) {
            int slot = t + p * 256;
            int d = slot >> 3, joff = (slot & 7) << 3;
            *(u16x8*)&BhS[d][joff] = *(const u16x8*)(Bh + (size_t)d * N + j0 + joff);
        }
        float4 mcv = *(const float4*)(mc + j0 + aj);
        float4 icv = *(const float4*)(ic + j0 + aj);
        #pragma unroll
        for (int s = 0; s < 4; ++s) {
            int row = arow + s * 16;
            f16x4 av = *(const f16x4*)(Am + (size_t)(bm + row) * N + j0 + aj);
            float mr = mrS[row], sr = isrS[row];
            float p0 = fexp2((float)av.x - 0.5f * (mr + mcv.x)) * (sr * icv.x);
            float p1 = fexp2((float)av.y - 0.5f * (mr + mcv.y)) * (sr * icv.y);
            float p2 = fexp2((float)av.z - 0.5f * (mr + mcv.z)) * (sr * icv.z);
            float p3 = fexp2((float)av.w - 0.5f * (mr + mcv.w)) * (sr * icv.w);
            rs[s] += p0 + p1 + p2 + p3;
            ushort4 hv, lv;
            split1_trunc(p0, hv.x, lv.x); split1_trunc(p1, hv.y, lv.y);
            split1_trunc(p2, hv.z, lv.z); split1_trunc(p3, hv.w, lv.w);
            *(ushort4*)&PhS[row][aj] = hv;
            *(ushort4*)&PlS[row][aj] = lv;
        }
        __syncthreads();
        #pragma unroll
        for (int ks = 0; ks < 2; ++ks) {
            const int kk = ks * 32 + quad * 8;
            bf16x8 ph = *(const bf16x8*)&PhS[w * 16 + l16][kk];
            bf16x8 pl = *(const bf16x8*)&PlS[w * 16 + l16][kk];
            #pragma unroll
            for (int ni = 0; ni < 8; ++ni) {
                bf16x8 bh = *(const bf16x8*)&BhS[ni * 16 + l16][kk];
                acc[ni] = MFMA(ph, bh, acc[ni]);
                acc[ni] = MFMA(pl, bh, acc[ni]);
            }
        }
    }
    #pragma unroll
    for (int ni = 0; ni < 8; ++ni)
        #pragma unroll
        for (int r = 0; r < 4; ++r) {
            int row = w * 16 + quad * 4 + r;
            int col = ni * 16 + l16;
            Cp[(size_t)(bm + row) * D + col] = acc[ni][r];
        }
    #pragma unroll
    for (int s = 0; s < 4; ++s) {
        float v = rs[s];
        v += __shfl_xor(v, 1); v += __shfl_xor(v, 2);
        v += __shfl_xor(v, 4); v += __shfl_xor(v, 8);
        if (l16 == 0) atomicAdd(&spn[bm + arow + s * 16], v);
    }
}

// ---------------------------------------------------------------------------
// Sum split-K partials, V = sn*u - sp*sn*w, accumulate sum(V^2).
// ---------------------------------------------------------------------------
__global__ __launch_bounds__(256) void final_reduce(const float* __restrict__ u_part,
    const float* __restrict__ w_part, const float* __restrict__ sp_arr,
    const float* __restrict__ sn_arr, double* __restrict__ acc_out)
{
    __shared__ float red[256];
    const int t = threadIdx.x;
    const int idx = blockIdx.x * 256 + t;
    float u = 0.f, w = 0.f;
    #pragma unroll
    for (int c = 0; c < KSPLIT; ++c) {
        u += u_part[(size_t)c * (N * D) + idx];
        w += w_part[(size_t)c * (N * D) + idx];
    }
    const int i = idx >> 7;
    const float sn = sn_arr[i];
    const float v = sn * u - sp_arr[i] * sn * w;
    red[t] = v * v; __syncthreads();
    for (int s = 128; s > 0; s >>= 1) { if (t < s) red[t] += red[t + s]; __syncthreads(); }
    if (!t) atomicAdd(acc_out, (double)red[0]);
}

__global__ void finalize(const double* __restrict__ acc, float* __restrict__ out)
{
    out[0] = (float)(*acc * (1.0 / ((double)N * (double)D)));
}

// ---------------------------------------------------------------------------
extern "C" void kernel_launch(void* const* d_in, const int* in_sizes, int n_in,
                              void* d_out, int out_size, void* d_ws, size_t ws_size,
                              hipStream_t stream)
{
    const float* y_pos = (const float*)d_in[0];
    const float* eps   = (const float*)d_in[1];
    const float* W_in  = (const float*)d_in[2];
    const float* b_in  = (const float*)d_in[3];
    const float* W_blk = (const float*)d_in[4];
    const float* b_blk = (const float*)d_in[5];
    const float* W_out = (const float*)d_in[6];
    const float* b_out = (const float*)d_in[7];
    float* out = (float*)d_out;
    (void)in_sizes; (void)n_in; (void)out_size; (void)ws_size;

    char* p = (char*)d_ws;
    auto alloc = [&](size_t bytes) {
        char* r = p;
        p += (bytes + 255) & ~(size_t)255;
        return r;
    };
    // --- small arrays ---
    double* acc  = (double*)alloc(8);
    float* sp     = (float*)alloc(N * 4);
    float* sn     = (float*)alloc(N * 4);
    float* m_row  = (float*)alloc(N * 4);
    float* isr    = (float*)alloc(N * 4);
    float* m_col  = (float*)alloc(2 * N * 4);
    float* isc    = (float*)alloc(2 * N * 4);
    float* nx     = (float*)alloc(N * 4);
    float* ny     = (float*)alloc(N * 4);
    // --- eh/el (2 MB; only live through the first gen layer) ---
    u16* eh = (u16*)alloc((size_t)N * D * 2);
    u16* el = (u16*)alloc((size_t)N * D * 2);
    // --- xo fp32 + bf16 x/y arrays ---
    float* xo  = (float*)alloc((size_t)N * D * 4);
    u16* xh    = (u16*)alloc((size_t)N * D * 2);
    u16* xl    = (u16*)alloc((size_t)N * D * 2);
    u16* xth   = (u16*)alloc((size_t)N * D * 2);
    u16* yh    = (u16*)alloc((size_t)N * D * 2);
    u16* yl    = (u16*)alloc((size_t)N * D * 2);
    u16* yth   = (u16*)alloc((size_t)N * D * 2);
    // --- generator region (21 MB): activations + weights; later aliased by
    //     stats partials (6 MB) then u/w_part (16 MB) ---
    char* genreg = alloc((size_t)(4 * (size_t)N * H * 2
                                + 2 * (size_t)H * D * 2
                                + 2 * (size_t)4 * H * H * 2
                                + 2 * (size_t)D * H * 2));
    u16* x0h = (u16*)genreg;
    u16* x0l = x0h + (size_t)N * H;
    u16* x1h = x0l + (size_t)N * H;
    u16* x1l = x1h + (size_t)N * H;
    u16* wih = x1l + (size_t)N * H;
    u16* wil = wih + (size_t)H * D;
    u16* wbh = wil + (size_t)H * D;
    u16* wbl = wbh + (size_t)4 * H * H;
    u16* woh = wbl + (size_t)4 * H * H;
    u16* wol = woh + (size_t)D * H;
    // aliases (disjoint lifetimes, stream-ordered):
    float* prm_p = (float*)genreg;                 // 32*N each = 0.5 MB
    float* prs_p = prm_p + 32 * N;
    float* prm_n = prs_p + 32 * N;
    float* prs_n = prm_n + 32 * N;
    float* pcm_p = prs_n + 32 * N;                 // 128*N = 2 MB each
    float* pcs_p = pcm_p + 128 * N;                // ends at 6 MB
    float* u_part = (float*)genreg;                // KSPLIT*N*D = 8 MB
    float* w_part = u_part + (size_t)KSPLIT * N * D;
    // --- the big ones (64 MB, fp16) ---
    f16* Apos = (f16*)alloc((size_t)N * N * 2);
    f16* Aneg = (f16*)alloc((size_t)N * N * 2);

    // --- split inputs/weights to bf16 hi/lo (RTN) + workspace init (y==5) ---
    SplitArgs sa;
    sa.d[0] = { eps,   eh,  el,  N * D };
    sa.d[1] = { y_pos, yh,  yl,  N * D };
    sa.d[2] = { W_in,  wih, wil, H * D };
    sa.d[3] = { W_blk, wbh, wbl, 4 * H * H };
    sa.d[4] = { W_out, woh, wol, D * H };
    split_multi<<<dim3(1024, 6), 256, 0, stream>>>(sa, acc, sp, sn, nx, ny);

    // --- generator (MFMA, act hi/lo x W-RTN, 64x64 blocks, BK=128) ---
    dim3 gh(H / 64, N / 64);
    gen_gemm<<<gh, 128, 0, stream>>>(eh, el, wih, b_in,
                                     nullptr, x0h, x0l, N, H, D, 0, 0);
    gen_gemm<<<gh, 128, 0, stream>>>(x0h, x0l, wbh + 0 * H * H,
                                     b_blk + 0 * H, nullptr, x1h, x1l, N, H, H, 1, 0);
    gen_gemm<<<gh, 128, 0, stream>>>(x1h, x1l, wbh + 1 * H * H,
                                     b_blk + 1 * H, nullptr, x0h, x0l, N, H, H, 1, 0);
    gen_gemm<<<gh, 128, 0, stream>>>(x0h, x0l, wbh + 2 * H * H,
                                     b_blk + 2 * H, nullptr, x1h, x1l, N, H, H, 1, 0);
    gen_gemm<<<gh, 128, 0, stream>>>(x1h, x1l, wbh + 3 * H * H,
                                     b_blk + 3 * H, nullptr, x0h, x0l, N, H, H, 1, 0);
    gen_gemm<<<dim3(D / 64, N / 64), 128, 0, stream>>>(x0h, x0l, woh, b_out,
                                     xo, xh, xl, N, D, H, 0, 1);

    // --- RTN transposes + fused row norms ---
    transpose_rtn<<<dim3(N / 32, D / 32, 2), 256, 0, stream>>>(
        xo, y_pos, xth, yth, nx, ny);

    // --- distance matrices (fp16 log2-domain, single-bf16 MFMA) + stats ---
    dist_fused<<<dim3(N / 128, N / 128, 2), 256, 0, stream>>>(
        xh, yh, nx, ny, Apos, Aneg,
        prm_p, prs_p, pcm_p, pcs_p, prm_n, prs_n);

    // --- combine partials into m_row/isr, m_col/isc (parallel) ---
    stats_combine<<<192, 256, 0, stream>>>(prm_p, prs_p, prm_n, prs_n,
                                           pcm_p, pcs_p,
                                           m_row, isr, m_col, isc);

    // --- P@V via MFMA (P built on the fly; sp/sn fp32 via atomics) ---
    pv_mfma<<<dim3(N / 64, KSPLIT, 2), 256, 0, stream>>>(Apos, Aneg,
        yth, xth, m_row, isr, m_col, isc, u_part, w_part, sp, sn);

    // --- combine partials, V^2 reduction ---
    final_reduce<<<(N * D) / 256, 256, 0, stream>>>(u_part, w_part, sp, sn, acc);
    finalize<<<1, 1, 0, stream>>>(acc, out);
}

// Round 3
// 285.135 us; speedup vs baseline: 1.0987x; 1.0349x over previous
//
#include <hip/hip_runtime.h>
#include <math.h>

#define N 4096
#define D 128
#define H 512
#define KSPLIT 4
// 5 * log2(e): distances stored in log2 domain so all softmax exps are raw v_exp_f32
#define SC_LOG2 7.2134752044f

typedef short bf16x8 __attribute__((ext_vector_type(8)));
typedef float f32x4 __attribute__((ext_vector_type(4)));
typedef unsigned short u16x8 __attribute__((ext_vector_type(8)));
typedef unsigned short u16;
typedef _Float16 f16;
typedef _Float16 f16x4 __attribute__((ext_vector_type(4)));

#define MFMA(a, b, c) __builtin_amdgcn_mfma_f32_16x16x32_bf16((a), (b), (c), 0, 0, 0)

__device__ __forceinline__ float fexp2(float x)
{
#if __has_builtin(__builtin_amdgcn_exp2f)
    return __builtin_amdgcn_exp2f(x);
#else
    return exp2f(x);
#endif
}

// Raw v_sqrt_f32 (~2 ULP) — downstream is f16-quantized anyway.
__device__ __forceinline__ float fsqrt(float x)
{
#if __has_builtin(__builtin_amdgcn_sqrtf)
    return __builtin_amdgcn_sqrtf(x);
#else
    return sqrtf(x);
#endif
}

__device__ __forceinline__ float bf2f(u16 h)
{
    return __uint_as_float(((unsigned)h) << 16);
}

// Round-to-nearest bf16 (unbiased) — for operands whose hi is used ALONE.
__device__ __forceinline__ u16 rtn_bf16(float v)
{
    unsigned u = __float_as_uint(v);
    return (u16)((u + 0x7FFFu + ((u >> 16) & 1u)) >> 16);
}

// RTN split (hi usable alone; lo compensates). Cold paths + last gen layer.
__device__ __forceinline__ void split1(float v, u16& h, u16& l)
{
    u16 hh = rtn_bf16(v);
    float r = v - bf2f(hh);
    h = hh;
    l = rtn_bf16(r);
}

// Cheap truncation split (3 ops); hi+lo pair accuracy identical.
__device__ __forceinline__ void split1_trunc(float v, u16& h, u16& l)
{
    unsigned bv = __float_as_uint(v);
    unsigned hb = bv & 0xFFFF0000u;
    float r = v - __uint_as_float(hb);
    h = (u16)(hb >> 16);
    l = (u16)(__float_as_uint(r) >> 16);
}

// DPP cross-lane move within 16-lane rows (pure VALU — no DS latency).
// 0xB1 = quad_perm [1,0,3,2] (xor1), 0x4E = quad_perm [2,3,0,1] (xor2),
// 0x141 = row_half_mirror (≡xor4 after quad reduce), 0x140 = row_mirror (≡xor8).
template <int CTRL>
__device__ __forceinline__ float dppf(float x)
{
    int r = __builtin_amdgcn_update_dpp(0, __float_as_int(x), CTRL, 0xF, 0xF, true);
    return __int_as_float(r);
}

// ---------------------------------------------------------------------------
// One-shot splitter for 5 flat fp32 arrays -> bf16 hi/lo (RTN, cold) and,
// on the y==5 plane, workspace init (acc/sp/sn/nx/ny).
// ---------------------------------------------------------------------------
struct SplitDesc { const float* src; u16* h; u16* l; int n; };
struct SplitArgs { SplitDesc d[5]; };

__global__ __launch_bounds__(256) void split_multi(SplitArgs args,
    double* acc, float* sp, float* sn, float* nx, float* ny)
{
    if (blockIdx.y == 5) {
        int idx = blockIdx.x * 256 + threadIdx.x;
        if (idx == 0) *acc = 0.0;
        if (idx < N) { sp[idx] = 0.f; sn[idx] = 0.f; nx[idx] = 0.f; ny[idx] = 0.f; }
        return;
    }
    SplitDesc de = args.d[blockIdx.y];
    int idx = (blockIdx.x * 256 + threadIdx.x) * 4;
    if (idx >= de.n) return;
    float4 v = *(const float4*)(de.src + idx);
    ushort4 hv, lv;
    split1(v.x, hv.x, lv.x); split1(v.y, hv.y, lv.y);
    split1(v.z, hv.z, lv.z); split1(v.w, hv.w, lv.w);
    *(ushort4*)(de.h + idx) = hv;
    *(ushort4*)(de.l + idx) = lv;
}

// ---------------------------------------------------------------------------
// Transpose + RTN-bf16 + fused row-norm partials (atomicAdd into nx/ny).
// ---------------------------------------------------------------------------
__global__ __launch_bounds__(256) void transpose_rtn(
    const float* __restrict__ X, const float* __restrict__ Y,
    u16* __restrict__ Xth, u16* __restrict__ Yth,
    float* __restrict__ nx, float* __restrict__ ny)
{
    const float* src = blockIdx.z ? Y : X;
    u16* th = blockIdx.z ? Yth : Xth;
    float* nrm = blockIdx.z ? ny : nx;
    __shared__ float tile[32][33];
    const int t = threadIdx.x;
    const int r0 = blockIdx.x * 32, c0 = blockIdx.y * 32;
    {
        int rit = t >> 3, coff = (t & 7) * 4;
        float4 v = *(const float4*)(src + (size_t)(r0 + rit) * D + c0 + coff);
        tile[rit][coff + 0] = v.x; tile[rit][coff + 1] = v.y;
        tile[rit][coff + 2] = v.z; tile[rit][coff + 3] = v.w;
        float sq = v.x * v.x + v.y * v.y + v.z * v.z + v.w * v.w;
        sq += __shfl_xor(sq, 1);
        sq += __shfl_xor(sq, 2);
        sq += __shfl_xor(sq, 4);
        if ((t & 7) == 0) atomicAdd(&nrm[r0 + rit], sq);
    }
    __syncthreads();
    {
        int cit = t >> 3, roff = (t & 7) * 4;
        ushort4 hv;
        hv.x = rtn_bf16(tile[roff + 0][cit]);
        hv.y = rtn_bf16(tile[roff + 1][cit]);
        hv.z = rtn_bf16(tile[roff + 2][cit]);
        hv.w = rtn_bf16(tile[roff + 3][cit]);
        *(ushort4*)(th + (size_t)(c0 + cit) * N + r0 + roff) = hv;
    }
}

// ---------------------------------------------------------------------------
// Generator GEMM: A = activations hi/lo bf16 pair, B = weights single RTN
// bf16. Tile 64x64, 256 threads (4 waves 2m x 2n, acc[2][2]=16 regs),
// DOUBLE-BUFFERED LDS (2 x 3 x 64x72 u16 = 55 KB -> 2 blocks/CU = 8
// waves/CU), ONE barrier per BK=64 K-step: stage(next) overlaps
// compute(cur). Chain was ~1 wave/SIMD barrier-drain-bound before.
// rtn_out=1 on the last layer only.
// ---------------------------------------------------------------------------
__global__ __launch_bounds__(256) void gen_gemm(
    const u16* __restrict__ Ah, const u16* __restrict__ Al,
    const u16* __restrict__ Bh,
    const float* __restrict__ bias,
    float* __restrict__ C, u16* __restrict__ Ch, u16* __restrict__ Cl,
    int M, int Nn, int K, int resid, int rtn_out)
{
    __shared__ u16 AhS[2][64][72], AlS[2][64][72];
    __shared__ u16 BhS[2][64][72];
    const int t = threadIdx.x;
    const int w = t >> 6, lane = t & 63;
    const int quad = lane >> 4, l16 = lane & 15;
    const int wm = w & 1, wn = w >> 1;
    const int bm = blockIdx.y * 64, bn = blockIdx.x * 64;
    f32x4 acc[2][2] = {};

    auto stage = [&](int buf, int k0) {
        #pragma unroll
        for (int p = 0; p < 2; ++p) {
            int slot = t + p * 256;          // 512 slots = 64 rows x 8 k-octets
            int row = slot >> 3, koff = (slot & 7) << 3;
            size_t ga = (size_t)(bm + row) * K + k0 + koff;
            size_t gb = (size_t)(bn + row) * K + k0 + koff;
            *(u16x8*)&AhS[buf][row][koff] = *(const u16x8*)(Ah + ga);
            *(u16x8*)&AlS[buf][row][koff] = *(const u16x8*)(Al + ga);
            *(u16x8*)&BhS[buf][row][koff] = *(const u16x8*)(Bh + gb);
        }
    };

    stage(0, 0);
    __syncthreads();
    const int NT = K >> 6;
    for (int kt = 0; kt < NT; ++kt) {
        const int cur = kt & 1;
        if (kt + 1 < NT) stage(cur ^ 1, (kt + 1) << 6);
        #pragma unroll
        for (int kh = 0; kh < 2; ++kh) {
            const int kk = kh * 32 + quad * 8;
            bf16x8 af[2], alf[2], bhf[2];
            #pragma unroll
            for (int mi = 0; mi < 2; ++mi) {
                int r = wm * 32 + mi * 16 + l16;
                af[mi]  = *(const bf16x8*)&AhS[cur][r][kk];
                alf[mi] = *(const bf16x8*)&AlS[cur][r][kk];
            }
            #pragma unroll
            for (int ni = 0; ni < 2; ++ni)
                bhf[ni] = *(const bf16x8*)&BhS[cur][wn * 32 + ni * 16 + l16][kk];
            #pragma unroll
            for (int mi = 0; mi < 2; ++mi)
                #pragma unroll
                for (int ni = 0; ni < 2; ++ni) {
                    acc[mi][ni] = MFMA(af[mi], bhf[ni], acc[mi][ni]);
                    acc[mi][ni] = MFMA(alf[mi], bhf[ni], acc[mi][ni]);
                }
        }
        __syncthreads();
    }
    #pragma unroll
    for (int mi = 0; mi < 2; ++mi)
        #pragma unroll
        for (int ni = 0; ni < 2; ++ni)
            #pragma unroll
            for (int r = 0; r < 4; ++r) {
                int gm = bm + wm * 32 + mi * 16 + quad * 4 + r;
                int gn = bn + wn * 32 + ni * 16 + l16;
                float v = acc[mi][ni][r] + bias[gn];
                if (resid) {
                    size_t o2 = (size_t)gm * K + gn;
                    float prev = bf2f(Ah[o2]) + bf2f(Al[o2]);
                    v = prev + fmaxf(v, 0.0f);
                }
                size_t o = (size_t)gm * Nn + gn;
                if (C) C[o] = v;
                u16 hh, ll;
                if (rtn_out) split1(v, hh, ll);
                else         split1_trunc(v, hh, ll);
                Ch[o] = hh; Cl[o] = ll;
            }
}

// ---------------------------------------------------------------------------
// Distance via SINGLE RTN-bf16 MFMA, fused stats, pos+neg merged. A fp16,
// stored in LOG2 domain (a = -dist * 5*log2e) so every softmax exp is a
// bare v_exp_f32. Internally the epilogue works in the POSITIVE s-domain
// (s = -a): raw v_sqrt_f32, SC^2 folded into the norms (1 add + 1 fma +
// 1 sqrt per element), diag fixup hoisted to a uniform block-level branch.
// Tile 128(M)x128(N), 4 waves each owning 32 rows x full 128 cols.
// B-operand column permutation (proven): fragment slot (nn,l16) in each
// 64-col half holds j = half*64 + l16*4 + nn.
// ---------------------------------------------------------------------------
__global__ __launch_bounds__(256) void dist_fused(
    const u16* __restrict__ Xh, const u16* __restrict__ Yh,
    const float* __restrict__ nx, const float* __restrict__ ny,
    f16* __restrict__ Apos, f16* __restrict__ Aneg,
    float* __restrict__ prm_p, float* __restrict__ prs_p,
    float* __restrict__ pcm_p, float* __restrict__ pcs_p,
    float* __restrict__ prm_n, float* __restrict__ prs_n)
{
    const int mat = blockIdx.z;                // 0: X vs Y ; 1: X vs X
    const u16* Bhp = mat ? Xh : Yh;
    const float* nb = mat ? nx : ny;
    f16* Out = mat ? Aneg : Apos;
    float* prm = mat ? prm_n : prm_p;
    float* prs = mat ? prs_n : prs_p;

    __shared__ u16 XhS[128][40], YhS[128][40];
    const int t = threadIdx.x;
    const int w = t >> 6, lane = t & 63;
    const int quad = lane >> 4, l16 = lane & 15;
    const int bm = blockIdx.y * 128, bn = blockIdx.x * 128;
    f32x4 acc[2][8] = {};

    for (int k0 = 0; k0 < D; k0 += 32) {
        __syncthreads();
        #pragma unroll
        for (int p = 0; p < 2; ++p) {
            int slot = t + p * 256;            // 512 slots = 128 rows x 4 octets
            int row = slot >> 2, koff = (slot & 3) << 3;
            *(u16x8*)&XhS[row][koff] =
                *(const u16x8*)(Xh + (size_t)(bm + row) * D + k0 + koff);
        }
        #pragma unroll
        for (int p = 0; p < 2; ++p) {
            int slot = t + p * 256;
            int row = slot >> 2, koff = (slot & 3) << 3;
            int pr = ((row & 3) << 4) | ((row & 63) >> 2) | (row & 64);
            int kf = koff ^ (((pr >> 4) & 3) << 3);
            *(u16x8*)&YhS[pr][kf] =
                *(const u16x8*)(Bhp + (size_t)(bn + row) * D + k0 + koff);
        }
        __syncthreads();
        bf16x8 af[2], bhf[8];
        #pragma unroll
        for (int mi = 0; mi < 2; ++mi)
            af[mi] = *(const bf16x8*)&XhS[w * 32 + mi * 16 + l16][quad * 8];
        #pragma unroll
        for (int ni = 0; ni < 8; ++ni) {
            int nn = ni & 3, hf = ni >> 2;
            bhf[ni] = *(const bf16x8*)
                &YhS[hf * 64 + nn * 16 + l16][(quad * 8) ^ (nn << 3)];
        }
        #pragma unroll
        for (int mi = 0; mi < 2; ++mi)
            #pragma unroll
            for (int ni = 0; ni < 8; ++ni)
                acc[mi][ni] = MFMA(af[mi], bhf[ni], acc[mi][ni]);
    }
    // lane's 8 j's: jb..jb+3 and jb+64..jb+67
    const int jb = bn + (l16 << 2);
    const float SC2 = SC_LOG2 * SC_LOG2;
    const float c2 = -2.0f * SC2;
    const float4 n0 = *(const float4*)(nb + jb);
    const float4 n1 = *(const float4*)(nb + jb + 64);
    const float nl[8] = {n0.x * SC2, n0.y * SC2, n0.z * SC2, n0.w * SC2,
                         n1.x * SC2, n1.y * SC2, n1.z * SC2, n1.w * SC2};
    const bool diagb = (mat != 0) && (bm == bn);
    // --- transform in place to s = dist*SC (positive domain) + f16 stores ---
    auto xform = [&](bool dg) {
        #pragma unroll
        for (int mi = 0; mi < 2; ++mi) {
            const int rb = bm + w * 32 + mi * 16 + quad * 4;
            const float4 nxq = *(const float4*)(nx + rb);
            const float nxa[4] = {nxq.x * SC2, nxq.y * SC2,
                                  nxq.z * SC2, nxq.w * SC2};
            #pragma unroll
            for (int r = 0; r < 4; ++r) {
                f16x4 ov0, ov1;
                #pragma unroll
                for (int nn = 0; nn < 4; ++nn) {
                    float s0 = fsqrt(fmaxf(
                        fmaf(acc[mi][nn][r], c2, nxa[r] + nl[nn]), 0.f));
                    float s1 = fsqrt(fmaxf(
                        fmaf(acc[mi][4 + nn][r], c2, nxa[r] + nl[4 + nn]), 0.f));
                    if (dg) {
                        int gm = rb + r;
                        if (gm == jb + nn) s0 = 5.0e6f;
                        if (gm == jb + 64 + nn) s1 = 5.0e6f;
                    }
                    acc[mi][nn][r] = s0;
                    acc[mi][4 + nn][r] = s1;
                    ov0[nn] = (f16)(-s0);
                    ov1[nn] = (f16)(-s1);
                }
                *(f16x4*)(Out + (size_t)(rb + r) * N + jb) = ov0;
                *(f16x4*)(Out + (size_t)(rb + r) * N + jb + 64) = ov1;
            }
        }
    };
    if (diagb) xform(true); else xform(false);
    // --- row mins of s (== -row max of a): in-lane over 8 ni, DPP over l16 ---
    float m[2][4];
    #pragma unroll
    for (int mi = 0; mi < 2; ++mi)
        #pragma unroll
        for (int r = 0; r < 4; ++r) {
            float v = fminf(fminf(fminf(acc[mi][0][r], acc[mi][1][r]),
                                  fminf(acc[mi][2][r], acc[mi][3][r])),
                            fminf(fminf(acc[mi][4][r], acc[mi][5][r]),
                                  fminf(acc[mi][6][r], acc[mi][7][r])));
            v = fminf(v, dppf<0xB1>(v));
            v = fminf(v, dppf<0x4E>(v));
            v = fminf(v, dppf<0x141>(v));
            v = fminf(v, dppf<0x140>(v));
            m[mi][r] = v;
        }
    // --- wave-shared shift mn (min s over the wave's 32 rows x 128 cols) ---
    float mn = fminf(fminf(fminf(m[0][0], m[0][1]), fminf(m[0][2], m[0][3])),
                     fminf(fminf(m[1][0], m[1][1]), fminf(m[1][2], m[1][3])));
    mn = fminf(mn, __shfl_xor(mn, 16));
    mn = fminf(mn, __shfl_xor(mn, 32));
    // --- single exp pass: e = 2^(mn - s) feeds row sums (sig) + col sums ---
    float sig[2][4] = {};
    float cs[8] = {};
    #pragma unroll
    for (int mi = 0; mi < 2; ++mi)
        #pragma unroll
        for (int ni = 0; ni < 8; ++ni) {
            float e0 = fexp2(mn - acc[mi][ni][0]);
            float e1 = fexp2(mn - acc[mi][ni][1]);
            float e2 = fexp2(mn - acc[mi][ni][2]);
            float e3 = fexp2(mn - acc[mi][ni][3]);
            sig[mi][0] += e0; sig[mi][1] += e1;
            sig[mi][2] += e2; sig[mi][3] += e3;
            cs[ni] += (e0 + e1) + (e2 + e3);
        }
    // --- row partials: DPP tree-sum sig, rescale to row max (a-domain) ---
    const int ct = blockIdx.x;
    #pragma unroll
    for (int mi = 0; mi < 2; ++mi)
        #pragma unroll
        for (int r = 0; r < 4; ++r) {
            float s = sig[mi][r];
            s += dppf<0xB1>(s);
            s += dppf<0x4E>(s);
            s += dppf<0x141>(s);
            s += dppf<0x140>(s);
            s *= fexp2(m[mi][r] - mn);
            if (l16 == 0) {
                int grow = bm + w * 32 + mi * 16 + quad * 4 + r;
                prm[(size_t)ct * N + grow] = -m[mi][r];
                prs[(size_t)ct * N + grow] = s;
            }
        }
    // --- col partials (pos only): quad-reduce cs, shift is -mn (uniform) ---
    if (mat == 0) {
        const int rt = blockIdx.y * 4 + w;      // 32-row tiles -> 128 planes
        #pragma unroll
        for (int ni = 0; ni < 8; ++ni) {
            cs[ni] += __shfl_xor(cs[ni], 16);
            cs[ni] += __shfl_xor(cs[ni], 32);
        }
        if (quad == 0) {
            float4 c0 = {cs[0], cs[1], cs[2], cs[3]};
            float4 c1 = {cs[4], cs[5], cs[6], cs[7]};
            float4 m4 = {-mn, -mn, -mn, -mn};
            *(float4*)(pcs_p + (size_t)rt * N + jb) = c0;
            *(float4*)(pcs_p + (size_t)rt * N + jb + 64) = c1;
            *(float4*)(pcm_p + (size_t)rt * N + jb) = m4;
            *(float4*)(pcm_p + (size_t)rt * N + jb + 64) = m4;
        }
    }
}

// ---------------------------------------------------------------------------
// Combine partials into row/col softmax stats — parallel (192 x 256).
// Row stats: 32 col-tiles each of pos/neg. Col stats: pos = 128 row-tiles
// (pcm_p), neg = 32 (prm_n, symmetry). All in log2 domain.
// ---------------------------------------------------------------------------
__global__ __launch_bounds__(256) void stats_combine(
    const float* __restrict__ prm_p, const float* __restrict__ prs_p,
    const float* __restrict__ prm_n, const float* __restrict__ prs_n,
    const float* __restrict__ pcm_p, const float* __restrict__ pcs_p,
    float* __restrict__ m_row, float* __restrict__ isr,
    float* __restrict__ m_col, float* __restrict__ isc)
{
    __shared__ float Ms[4][64], Ss[4][64];
    const int t = threadIdx.x;
    const int g = t >> 6, l = t & 63;
    const int idx = blockIdx.x * 64 + l;

    float m = -3.0e38f, s = 0.f;
    if (idx < N) {
        const int i = idx;
        const int c0 = g * 8;
        #pragma unroll 4
        for (int c = c0; c < c0 + 8; ++c) {
            m = fmaxf(m, prm_p[(size_t)c * N + i]);
            m = fmaxf(m, prm_n[(size_t)c * N + i]);
        }
        #pragma unroll 4
        for (int c = c0; c < c0 + 8; ++c) {
            s += prs_p[(size_t)c * N + i] * fexp2(prm_p[(size_t)c * N + i] - m);
            s += prs_n[(size_t)c * N + i] * fexp2(prm_n[(size_t)c * N + i] - m);
        }
    } else {
        const int mat = (idx - N) >> 12;
        const int j = idx & (N - 1);
        const float* pm = mat ? prm_n : pcm_p;
        const float* ps = mat ? prs_n : pcs_p;
        const int cnt = mat ? 8 : 32;
        const int cb = g * cnt;
        #pragma unroll 4
        for (int c = cb; c < cb + cnt; ++c)
            m = fmaxf(m, pm[(size_t)c * N + j]);
        #pragma unroll 4
        for (int c = cb; c < cb + cnt; ++c)
            s += ps[(size_t)c * N + j] * fexp2(pm[(size_t)c * N + j] - m);
    }
    Ms[g][l] = m; Ss[g][l] = s;
    __syncthreads();
    if (g == 0) {
        float m0 = Ms[0][l], m1 = Ms[1][l], m2 = Ms[2][l], m3 = Ms[3][l];
        float mm = fmaxf(fmaxf(m0, m1), fmaxf(m2, m3));
        float ss = Ss[0][l] * fexp2(m0 - mm) + Ss[1][l] * fexp2(m1 - mm)
                 + Ss[2][l] * fexp2(m2 - mm) + Ss[3][l] * fexp2(m3 - mm);
        if (idx < N) {
            m_row[idx] = mm;
            isr[idx] = 1.0f / sqrtf(ss);
        } else {
            const int mat = (idx - N) >> 12;
            const int j = idx & (N - 1);
            m_col[mat * N + j] = mm;
            isc[mat * N + j] = 1.0f / sqrtf(ss);
        }
    }
}

// ---------------------------------------------------------------------------
// pv via MFMA (proven form): A fp16 tile (log2 domain) -> P (fp32 rowsums
// -> sp/sn), split P (trunc) to bf16 hi/lo in LDS, MFMA P @ B (B = RTN-bf16
// transposed [d][j], hi only). Unpermuted staging; scalar C-stores.
// ---------------------------------------------------------------------------
__global__ __launch_bounds__(256) void pv_mfma(
    const f16* __restrict__ Apos, const f16* __restrict__ Aneg,
    const u16* __restrict__ Yth, const u16* __restrict__ Xth,
    const float* __restrict__ m_row, const float* __restrict__ isr,
    const float* __restrict__ m_col, const float* __restrict__ isc,
    float* __restrict__ u_part, float* __restrict__ w_part,
    float* __restrict__ sp_arr, float* __restrict__ sn_arr)
{
    const int mat = blockIdx.z;
    const f16* Am = mat ? Aneg : Apos;
    const u16* Bh = mat ? Xth : Yth;
    const float* mc = m_col + mat * N;
    const float* ic = isc + mat * N;
    float* Cp = (mat ? w_part : u_part) + (size_t)blockIdx.y * (N * D);
    float* spn = mat ? sn_arr : sp_arr;

    __shared__ u16 BhS[128][72];
    __shared__ u16 PhS[64][72], PlS[64][72];
    __shared__ float mrS[64], isrS[64];

    const int t = threadIdx.x;
    const int w = t >> 6, lane = t & 63;
    const int quad = lane >> 4, l16 = lane & 15;
    const int bm = blockIdx.x * 64;
    const int jbase = blockIdx.y * (N / KSPLIT);
    const int arow = t >> 4;          // 0..15
    const int aj = (t & 15) << 2;     // 0..60

    if (t < 64) { mrS[t] = m_row[bm + t]; isrS[t] = isr[bm + t]; }

    f32x4 acc[8] = {};
    float rs[4] = {0.f, 0.f, 0.f, 0.f};

    for (int jt = 0; jt < (N / KSPLIT) / 64; ++jt) {
        const int j0 = jbase + jt * 64;
        __syncthreads();   // protect previous iteration's LDS reads (+ mrS init)
        #pragma unroll
        for (int p = 0; p < 4; ++p) {
            int slot = t + p * 256;
            int d = slot >> 3, joff = (slot & 7) << 3;
            *(u16x8*)&BhS[d][joff] = *(const u16x8*)(Bh + (size_t)d * N + j0 + joff);
        }
        float4 mcv = *(const float4*)(mc + j0 + aj);
        float4 icv = *(const float4*)(ic + j0 + aj);
        #pragma unroll
        for (int s = 0; s < 4; ++s) {
            int row = arow + s * 16;
            f16x4 av = *(const f16x4*)(Am + (size_t)(bm + row) * N + j0 + aj);
            float mr = mrS[row], sr = isrS[row];
            float p0 = fexp2((float)av.x - 0.5f * (mr + mcv.x)) * (sr * icv.x);
            float p1 = fexp2((float)av.y - 0.5f * (mr + mcv.y)) * (sr * icv.y);
            float p2 = fexp2((float)av.z - 0.5f * (mr + mcv.z)) * (sr * icv.z);
            float p3 = fexp2((float)av.w - 0.5f * (mr + mcv.w)) * (sr * icv.w);
            rs[s] += p0 + p1 + p2 + p3;
            ushort4 hv, lv;
            split1_trunc(p0, hv.x, lv.x); split1_trunc(p1, hv.y, lv.y);
            split1_trunc(p2, hv.z, lv.z); split1_trunc(p3, hv.w, lv.w);
            *(ushort4*)&PhS[row][aj] = hv;
            *(ushort4*)&PlS[row][aj] = lv;
        }
        __syncthreads();
        #pragma unroll
        for (int ks = 0; ks < 2; ++ks) {
            const int kk = ks * 32 + quad * 8;
            bf16x8 ph = *(const bf16x8*)&PhS[w * 16 + l16][kk];
            bf16x8 pl = *(const bf16x8*)&PlS[w * 16 + l16][kk];
            #pragma unroll
            for (int ni = 0; ni < 8; ++ni) {
                bf16x8 bh = *(const bf16x8*)&BhS[ni * 16 + l16][kk];
                acc[ni] = MFMA(ph, bh, acc[ni]);
                acc[ni] = MFMA(pl, bh, acc[ni]);
            }
        }
    }
    #pragma unroll
    for (int ni = 0; ni < 8; ++ni)
        #pragma unroll
        for (int r = 0; r < 4; ++r) {
            int row = w * 16 + quad * 4 + r;
            int col = ni * 16 + l16;
            Cp[(size_t)(bm + row) * D + col] = acc[ni][r];
        }
    #pragma unroll
    for (int s = 0; s < 4; ++s) {
        float v = rs[s];
        v += __shfl_xor(v, 1); v += __shfl_xor(v, 2);
        v += __shfl_xor(v, 4); v += __shfl_xor(v, 8);
        if (l16 == 0) atomicAdd(&spn[bm + arow + s * 16], v);
    }
}

// ---------------------------------------------------------------------------
// Sum split-K partials, V = sn*u - sp*sn*w, accumulate sum(V^2).
// ---------------------------------------------------------------------------
__global__ __launch_bounds__(256) void final_reduce(const float* __restrict__ u_part,
    const float* __restrict__ w_part, const float* __restrict__ sp_arr,
    const float* __restrict__ sn_arr, double* __restrict__ acc_out)
{
    __shared__ float red[256];
    const int t = threadIdx.x;
    const int idx = blockIdx.x * 256 + t;
    float u = 0.f, w = 0.f;
    #pragma unroll
    for (int c = 0; c < KSPLIT; ++c) {
        u += u_part[(size_t)c * (N * D) + idx];
        w += w_part[(size_t)c * (N * D) + idx];
    }
    const int i = idx >> 7;
    const float sn = sn_arr[i];
    const float v = sn * u - sp_arr[i] * sn * w;
    red[t] = v * v; __syncthreads();
    for (int s = 128; s > 0; s >>= 1) { if (t < s) red[t] += red[t + s]; __syncthreads(); }
    if (!t) atomicAdd(acc_out, (double)red[0]);
}

__global__ void finalize(const double* __restrict__ acc, float* __restrict__ out)
{
    out[0] = (float)(*acc * (1.0 / ((double)N * (double)D)));
}

// ---------------------------------------------------------------------------
extern "C" void kernel_launch(void* const* d_in, const int* in_sizes, int n_in,
                              void* d_out, int out_size, void* d_ws, size_t ws_size,
                              hipStream_t stream)
{
    const float* y_pos = (const float*)d_in[0];
    const float* eps   = (const float*)d_in[1];
    const float* W_in  = (const float*)d_in[2];
    const float* b_in  = (const float*)d_in[3];
    const float* W_blk = (const float*)d_in[4];
    const float* b_blk = (const float*)d_in[5];
    const float* W_out = (const float*)d_in[6];
    const float* b_out = (const float*)d_in[7];
    float* out = (float*)d_out;
    (void)in_sizes; (void)n_in; (void)out_size; (void)ws_size;

    char* p = (char*)d_ws;
    auto alloc = [&](size_t bytes) {
        char* r = p;
        p += (bytes + 255) & ~(size_t)255;
        return r;
    };
    // --- small arrays ---
    double* acc  = (double*)alloc(8);
    float* sp     = (float*)alloc(N * 4);
    float* sn     = (float*)alloc(N * 4);
    float* m_row  = (float*)alloc(N * 4);
    float* isr    = (float*)alloc(N * 4);
    float* m_col  = (float*)alloc(2 * N * 4);
    float* isc    = (float*)alloc(2 * N * 4);
    float* nx     = (float*)alloc(N * 4);
    float* ny     = (float*)alloc(N * 4);
    // --- eh/el (2 MB; only live through the first gen layer) ---
    u16* eh = (u16*)alloc((size_t)N * D * 2);
    u16* el = (u16*)alloc((size_t)N * D * 2);
    // --- xo fp32 + bf16 x/y arrays ---
    float* xo  = (float*)alloc((size_t)N * D * 4);
    u16* xh    = (u16*)alloc((size_t)N * D * 2);
    u16* xl    = (u16*)alloc((size_t)N * D * 2);
    u16* xth   = (u16*)alloc((size_t)N * D * 2);
    u16* yh    = (u16*)alloc((size_t)N * D * 2);
    u16* yl    = (u16*)alloc((size_t)N * D * 2);
    u16* yth   = (u16*)alloc((size_t)N * D * 2);
    // --- generator region (21 MB): activations + weights; later aliased by
    //     stats partials (6 MB) then u/w_part (16 MB) ---
    char* genreg = alloc((size_t)(4 * (size_t)N * H * 2
                                + 2 * (size_t)H * D * 2
                                + 2 * (size_t)4 * H * H * 2
                                + 2 * (size_t)D * H * 2));
    u16* x0h = (u16*)genreg;
    u16* x0l = x0h + (size_t)N * H;
    u16* x1h = x0l + (size_t)N * H;
    u16* x1l = x1h + (size_t)N * H;
    u16* wih = x1l + (size_t)N * H;
    u16* wil = wih + (size_t)H * D;
    u16* wbh = wil + (size_t)H * D;
    u16* wbl = wbh + (size_t)4 * H * H;
    u16* woh = wbl + (size_t)4 * H * H;
    u16* wol = woh + (size_t)D * H;
    // aliases (disjoint lifetimes, stream-ordered):
    float* prm_p = (float*)genreg;                 // 32*N each = 0.5 MB
    float* prs_p = prm_p + 32 * N;
    float* prm_n = prs_p + 32 * N;
    float* prs_n = prm_n + 32 * N;
    float* pcm_p = prs_n + 32 * N;                 // 128*N = 2 MB each
    float* pcs_p = pcm_p + 128 * N;                // ends at 6 MB
    float* u_part = (float*)genreg;                // KSPLIT*N*D = 8 MB
    float* w_part = u_part + (size_t)KSPLIT * N * D;
    // --- the big ones (64 MB, fp16) ---
    f16* Apos = (f16*)alloc((size_t)N * N * 2);
    f16* Aneg = (f16*)alloc((size_t)N * N * 2);

    // --- split inputs/weights to bf16 hi/lo (RTN) + workspace init (y==5) ---
    SplitArgs sa;
    sa.d[0] = { eps,   eh,  el,  N * D };
    sa.d[1] = { y_pos, yh,  yl,  N * D };
    sa.d[2] = { W_in,  wih, wil, H * D };
    sa.d[3] = { W_blk, wbh, wbl, 4 * H * H };
    sa.d[4] = { W_out, woh, wol, D * H };
    split_multi<<<dim3(1024, 6), 256, 0, stream>>>(sa, acc, sp, sn, nx, ny);

    // --- generator (MFMA, act hi/lo x W-RTN, 64x64 blocks, 4 waves, dbuf) ---
    dim3 gh(H / 64, N / 64);
    gen_gemm<<<gh, 256, 0, stream>>>(eh, el, wih, b_in,
                                     nullptr, x0h, x0l, N, H, D, 0, 0);
    gen_gemm<<<gh, 256, 0, stream>>>(x0h, x0l, wbh + 0 * H * H,
                                     b_blk + 0 * H, nullptr, x1h, x1l, N, H, H, 1, 0);
    gen_gemm<<<gh, 256, 0, stream>>>(x1h, x1l, wbh + 1 * H * H,
                                     b_blk + 1 * H, nullptr, x0h, x0l, N, H, H, 1, 0);
    gen_gemm<<<gh, 256, 0, stream>>>(x0h, x0l, wbh + 2 * H * H,
                                     b_blk + 2 * H, nullptr, x1h, x1l, N, H, H, 1, 0);
    gen_gemm<<<gh, 256, 0, stream>>>(x1h, x1l, wbh + 3 * H * H,
                                     b_blk + 3 * H, nullptr, x0h, x0l, N, H, H, 1, 0);
    gen_gemm<<<dim3(D / 64, N / 64), 256, 0, stream>>>(x0h, x0l, woh, b_out,
                                     xo, xh, xl, N, D, H, 0, 1);

    // --- RTN transposes + fused row norms ---
    transpose_rtn<<<dim3(N / 32, D / 32, 2), 256, 0, stream>>>(
        xo, y_pos, xth, yth, nx, ny);

    // --- distance matrices (fp16 log2-domain, single-bf16 MFMA) + stats ---
    dist_fused<<<dim3(N / 128, N / 128, 2), 256, 0, stream>>>(
        xh, yh, nx, ny, Apos, Aneg,
        prm_p, prs_p, pcm_p, pcs_p, prm_n, prs_n);

    // --- combine partials into m_row/isr, m_col/isc (parallel) ---
    stats_combine<<<192, 256, 0, stream>>>(prm_p, prs_p, prm_n, prs_n,
                                           pcm_p, pcs_p,
                                           m_row, isr, m_col, isc);

    // --- P@V via MFMA (P built on the fly; sp/sn fp32 via atomics) ---
    pv_mfma<<<dim3(N / 64, KSPLIT, 2), 256, 0, stream>>>(Apos, Aneg,
        yth, xth, m_row, isr, m_col, isc, u_part, w_part, sp, sn);

    // --- combine partials, V^2 reduction ---
    final_reduce<<<(N * D) / 256, 256, 0, stream>>>(u_part, w_part, sp, sn, acc);
    finalize<<<1, 1, 0, stream>>>(acc, out);
}

// Round 5
// 228.901 us; speedup vs baseline: 1.3686x; 1.2457x over previous
//
#include <hip/hip_runtime.h>
#include <math.h>

#define N 4096
#define D 128
#define H 512
#define KSPLIT 4
// 5 * log2(e): distances stored in log2 domain so all softmax exps are raw v_exp_f32
#define SC_LOG2 7.2134752044f

typedef short bf16x8 __attribute__((ext_vector_type(8)));
typedef float f32x4 __attribute__((ext_vector_type(4)));
typedef unsigned short u16x8 __attribute__((ext_vector_type(8)));
typedef unsigned short u16;
typedef _Float16 f16;
typedef _Float16 f16x4 __attribute__((ext_vector_type(4)));

#define MFMA(a, b, c) __builtin_amdgcn_mfma_f32_16x16x32_bf16((a), (b), (c), 0, 0, 0)

__device__ __forceinline__ float fexp2(float x)
{
#if __has_builtin(__builtin_amdgcn_exp2f)
    return __builtin_amdgcn_exp2f(x);
#else
    return exp2f(x);
#endif
}

// Raw v_sqrt_f32 (~2 ULP) — downstream is f16-quantized anyway.
__device__ __forceinline__ float fsqrt(float x)
{
#if __has_builtin(__builtin_amdgcn_sqrtf)
    return __builtin_amdgcn_sqrtf(x);
#else
    return sqrtf(x);
#endif
}

__device__ __forceinline__ float bf2f(u16 h)
{
    return __uint_as_float(((unsigned)h) << 16);
}

// Round-to-nearest bf16 (unbiased) — for operands whose hi is used ALONE.
__device__ __forceinline__ u16 rtn_bf16(float v)
{
    unsigned u = __float_as_uint(v);
    return (u16)((u + 0x7FFFu + ((u >> 16) & 1u)) >> 16);
}

// RTN split (hi usable alone; lo compensates).
__device__ __forceinline__ void split1(float v, u16& h, u16& l)
{
    u16 hh = rtn_bf16(v);
    float r = v - bf2f(hh);
    h = hh;
    l = rtn_bf16(r);
}

// Cheap truncation split (3 ops); hi+lo pair accuracy identical.
__device__ __forceinline__ void split1_trunc(float v, u16& h, u16& l)
{
    unsigned bv = __float_as_uint(v);
    unsigned hb = bv & 0xFFFF0000u;
    float r = v - __uint_as_float(hb);
    h = (u16)(hb >> 16);
    l = (u16)(__float_as_uint(r) >> 16);
}

// DPP cross-lane move within 16-lane rows (pure VALU — no DS latency).
template <int CTRL>
__device__ __forceinline__ float dppf(float x)
{
    int r = __builtin_amdgcn_update_dpp(0, __float_as_int(x), CTRL, 0xF, 0xF, true);
    return __int_as_float(r);
}

// ---------------------------------------------------------------------------
// RTN-bf16 converter for 4 flat fp32 arrays (hi only — lo parts were never
// consumed). No atomics, no init plane (nothing needs zero-init: every
// downstream reduction is deterministic partial-store + fixed-order sum).
// ---------------------------------------------------------------------------
struct SplitDesc { const float* src; u16* h; int n; };
struct SplitArgs { SplitDesc d[4]; };

__global__ __launch_bounds__(256) void split_multi(SplitArgs args)
{
    SplitDesc de = args.d[blockIdx.y];
    int idx = (blockIdx.x * 256 + threadIdx.x) * 4;
    if (idx >= de.n) return;
    float4 v = *(const float4*)(de.src + idx);
    ushort4 hv;
    hv.x = rtn_bf16(v.x); hv.y = rtn_bf16(v.y);
    hv.z = rtn_bf16(v.z); hv.w = rtn_bf16(v.w);
    *(ushort4*)(de.h + idx) = hv;
}

// ---------------------------------------------------------------------------
// FUSED generator: the residual MLP chain is row-independent, so each block
// owns 16 rows of x and runs ALL 6 layers with x resident in LDS (hi/lo
// bf16, 33 KB) — intermediates never touch HBM. W fragments are loaded
// DIRECTLY global->VGPR (each W element used once per block; all 256 blocks
// stream the same layer -> L2-cached). 8 waves x 64-col output chunks,
// acc[4]. Zero barriers in the K-loop; 2 barriers/layer at the x update.
// ---------------------------------------------------------------------------
__global__ __launch_bounds__(512) void gen_fused(
    const float* __restrict__ eps,
    const u16* __restrict__ Win, const u16* __restrict__ Wblk,
    const u16* __restrict__ Wout,
    const float* __restrict__ b_in, const float* __restrict__ b_blk,
    const float* __restrict__ b_out,
    float* __restrict__ xo, u16* __restrict__ xh)
{
    __shared__ u16 XhS[16][520], XlS[16][520];
    const int t = threadIdx.x;
    const int w = t >> 6, lane = t & 63;
    const int quad = lane >> 4, l16 = lane & 15;
    const int bm = blockIdx.x * 16;

    // --- stage eps rows -> x LDS (split1 RTN, identical to old path) ---
    {
        int idx = t * 4;                       // 0..2047 over 16x128
        int row = idx >> 7, col = idx & 127;
        float4 v = *(const float4*)(eps + (size_t)(bm + row) * D + col);
        ushort4 hv, lv;
        split1(v.x, hv.x, lv.x); split1(v.y, hv.y, lv.y);
        split1(v.z, hv.z, lv.z); split1(v.w, hv.w, lv.w);
        *(ushort4*)&XhS[row][col] = hv;
        *(ushort4*)&XlS[row][col] = lv;
    }
    __syncthreads();

    // --- layers 0..4 (output width 512, written back to x LDS) ---
    auto layer = [&](const u16* __restrict__ W, const float* __restrict__ bias,
                     int K, bool rr) {
        const int nb = w * 64;                 // wave's 64-col chunk
        f32x4 acc[4] = {};
        const int NT = K >> 5;
        bf16x8 bh[4], bn[4];
        #pragma unroll
        for (int ni = 0; ni < 4; ++ni)
            bh[ni] = *(const bf16x8*)(W + (size_t)(nb + ni * 16 + l16) * K + quad * 8);
        for (int kt = 0; kt < NT; ++kt) {
            const int kk = kt * 32 + quad * 8;
            bf16x8 af  = *(const bf16x8*)&XhS[l16][kk];
            bf16x8 alf = *(const bf16x8*)&XlS[l16][kk];
            if (kt + 1 < NT) {
                #pragma unroll
                for (int ni = 0; ni < 4; ++ni)
                    bn[ni] = *(const bf16x8*)
                        (W + (size_t)(nb + ni * 16 + l16) * K + kk + 32);
            }
            #pragma unroll
            for (int ni = 0; ni < 4; ++ni) {
                acc[ni] = MFMA(af,  bh[ni], acc[ni]);
                acc[ni] = MFMA(alf, bh[ni], acc[ni]);
            }
            if (kt + 1 < NT) {
                #pragma unroll
                for (int ni = 0; ni < 4; ++ni) bh[ni] = bn[ni];
            }
        }
        float bl4[4];
        #pragma unroll
        for (int ni = 0; ni < 4; ++ni) bl4[ni] = bias[nb + ni * 16 + l16];
        __syncthreads();                       // all waves done reading x
        #pragma unroll
        for (int ni = 0; ni < 4; ++ni) {
            const int col = nb + ni * 16 + l16;
            #pragma unroll
            for (int r = 0; r < 4; ++r) {
                const int row = quad * 4 + r;
                float v = acc[ni][r] + bl4[ni];
                if (rr) {
                    float prev = bf2f(XhS[row][col]) + bf2f(XlS[row][col]);
                    v = prev + fmaxf(v, 0.0f);
                }
                u16 hh, ll;
                split1_trunc(v, hh, ll);
                XhS[row][col] = hh;
                XlS[row][col] = ll;
            }
        }
        __syncthreads();                       // x updated for next layer
    };

    layer(Win, b_in, D, false);
    for (int i = 0; i < 4; ++i)
        layer(Wblk + (size_t)i * H * H, b_blk + i * H, H, true);

    // --- last layer: out width 128, fp32 xo + RTN xh to global ---
    {
        const int n0 = w * 16;                 // 8 waves x 16 cols
        f32x4 acc5 = {};
        const int NT = H >> 5;
        bf16x8 bh5 = *(const bf16x8*)(Wout + (size_t)(n0 + l16) * H + quad * 8);
        for (int kt = 0; kt < NT; ++kt) {
            const int kk = kt * 32 + quad * 8;
            bf16x8 af  = *(const bf16x8*)&XhS[l16][kk];
            bf16x8 alf = *(const bf16x8*)&XlS[l16][kk];
            bf16x8 bn5;
            if (kt + 1 < NT)
                bn5 = *(const bf16x8*)(Wout + (size_t)(n0 + l16) * H + kk + 32);
            acc5 = MFMA(af,  bh5, acc5);
            acc5 = MFMA(alf, bh5, acc5);
            if (kt + 1 < NT) bh5 = bn5;
        }
        const int col = n0 + l16;
        const float bl = b_out[col];
        #pragma unroll
        for (int r = 0; r < 4; ++r) {
            const int gm = bm + quad * 4 + r;
            float v = acc5[r] + bl;
            xo[(size_t)gm * D + col] = v;
            xh[(size_t)gm * D + col] = rtn_bf16(v);
        }
    }
}

// ---------------------------------------------------------------------------
// Deterministic row-norms: nx from xo, ny from y_pos. 4 threads/row, each
// sums 32 consecutive floats in fixed order, then a fixed 2-step shfl tree.
// Replaces the atomicAdd path (fp-atomic order nondeterminism tripped the
// harness's bit-identical-replay check).
// ---------------------------------------------------------------------------
__global__ __launch_bounds__(256) void rownorm(
    const float* __restrict__ X, const float* __restrict__ Y,
    float* __restrict__ nx, float* __restrict__ ny)
{
    const float* src = blockIdx.y ? Y : X;
    float* dst = blockIdx.y ? ny : nx;
    const int t = threadIdx.x;
    const int row = blockIdx.x * 64 + (t >> 2);
    const int q = t & 3;
    const float* rp = src + (size_t)row * D + q * 32;
    float s = 0.f;
    #pragma unroll
    for (int i = 0; i < 8; ++i) {
        float4 v = *(const float4*)(rp + i * 4);
        s += v.x * v.x + v.y * v.y + v.z * v.z + v.w * v.w;
    }
    s += __shfl_xor(s, 1);
    s += __shfl_xor(s, 2);
    if (q == 0) dst[row] = s;
}

// ---------------------------------------------------------------------------
// Transpose + RTN-bf16 (pure — norms moved to rownorm).
// ---------------------------------------------------------------------------
__global__ __launch_bounds__(256) void transpose_rtn(
    const float* __restrict__ X, const float* __restrict__ Y,
    u16* __restrict__ Xth, u16* __restrict__ Yth)
{
    const float* src = blockIdx.z ? Y : X;
    u16* th = blockIdx.z ? Yth : Xth;
    __shared__ float tile[32][33];
    const int t = threadIdx.x;
    const int r0 = blockIdx.x * 32, c0 = blockIdx.y * 32;
    {
        int rit = t >> 3, coff = (t & 7) * 4;
        float4 v = *(const float4*)(src + (size_t)(r0 + rit) * D + c0 + coff);
        tile[rit][coff + 0] = v.x; tile[rit][coff + 1] = v.y;
        tile[rit][coff + 2] = v.z; tile[rit][coff + 3] = v.w;
    }
    __syncthreads();
    {
        int cit = t >> 3, roff = (t & 7) * 4;
        ushort4 hv;
        hv.x = rtn_bf16(tile[roff + 0][cit]);
        hv.y = rtn_bf16(tile[roff + 1][cit]);
        hv.z = rtn_bf16(tile[roff + 2][cit]);
        hv.w = rtn_bf16(tile[roff + 3][cit]);
        *(ushort4*)(th + (size_t)(c0 + cit) * N + r0 + roff) = hv;
    }
}

// ---------------------------------------------------------------------------
// Distance via SINGLE RTN-bf16 MFMA, fused stats, pos+neg merged. A fp16,
// stored in LOG2 domain (a = -dist * 5*log2e) so every softmax exp is a
// bare v_exp_f32. Epilogue in POSITIVE s-domain: raw v_sqrt_f32, SC^2
// folded into norms, per-element diag cndmask (R2-proven reg profile).
// Tile 128(M)x128(N), 4 waves each owning 32 rows x full 128 cols.
// ---------------------------------------------------------------------------
__global__ __launch_bounds__(256) void dist_fused(
    const u16* __restrict__ Xh, const u16* __restrict__ Yh,
    const float* __restrict__ nx, const float* __restrict__ ny,
    f16* __restrict__ Apos, f16* __restrict__ Aneg,
    float* __restrict__ prm_p, float* __restrict__ prs_p,
    float* __restrict__ pcm_p, float* __restrict__ pcs_p,
    float* __restrict__ prm_n, float* __restrict__ prs_n)
{
    const int mat = blockIdx.z;                // 0: X vs Y ; 1: X vs X
    const u16* Bhp = mat ? Xh : Yh;
    const float* nb = mat ? nx : ny;
    f16* Out = mat ? Aneg : Apos;
    float* prm = mat ? prm_n : prm_p;
    float* prs = mat ? prs_n : prs_p;

    __shared__ u16 XhS[128][40], YhS[128][40];
    const int t = threadIdx.x;
    const int w = t >> 6, lane = t & 63;
    const int quad = lane >> 4, l16 = lane & 15;
    const int bm = blockIdx.y * 128, bn = blockIdx.x * 128;
    f32x4 acc[2][8] = {};

    for (int k0 = 0; k0 < D; k0 += 32) {
        __syncthreads();
        #pragma unroll
        for (int p = 0; p < 2; ++p) {
            int slot = t + p * 256;            // 512 slots = 128 rows x 4 octets
            int row = slot >> 2, koff = (slot & 3) << 3;
            *(u16x8*)&XhS[row][koff] =
                *(const u16x8*)(Xh + (size_t)(bm + row) * D + k0 + koff);
        }
        #pragma unroll
        for (int p = 0; p < 2; ++p) {
            int slot = t + p * 256;
            int row = slot >> 2, koff = (slot & 3) << 3;
            int pr = ((row & 3) << 4) | ((row & 63) >> 2) | (row & 64);
            int kf = koff ^ (((pr >> 4) & 3) << 3);
            *(u16x8*)&YhS[pr][kf] =
                *(const u16x8*)(Bhp + (size_t)(bn + row) * D + k0 + koff);
        }
        __syncthreads();
        bf16x8 af[2], bhf[8];
        #pragma unroll
        for (int mi = 0; mi < 2; ++mi)
            af[mi] = *(const bf16x8*)&XhS[w * 32 + mi * 16 + l16][quad * 8];
        #pragma unroll
        for (int ni = 0; ni < 8; ++ni) {
            int nn = ni & 3, hf = ni >> 2;
            bhf[ni] = *(const bf16x8*)
                &YhS[hf * 64 + nn * 16 + l16][(quad * 8) ^ (nn << 3)];
        }
        #pragma unroll
        for (int mi = 0; mi < 2; ++mi)
            #pragma unroll
            for (int ni = 0; ni < 8; ++ni)
                acc[mi][ni] = MFMA(af[mi], bhf[ni], acc[mi][ni]);
    }
    // lane's 8 j's: jb..jb+3 and jb+64..jb+67
    const int jb = bn + (l16 << 2);
    const float SC2 = SC_LOG2 * SC_LOG2;
    const float c2 = -2.0f * SC2;
    const float4 n0v = *(const float4*)(nb + jb);
    const float4 n1v = *(const float4*)(nb + jb + 64);
    const float nl[8] = {n0v.x * SC2, n0v.y * SC2, n0v.z * SC2, n0v.w * SC2,
                         n1v.x * SC2, n1v.y * SC2, n1v.z * SC2, n1v.w * SC2};
    // --- transform in place to s = dist*SC (positive domain) + f16 stores ---
    #pragma unroll
    for (int mi = 0; mi < 2; ++mi)
        #pragma unroll
        for (int r = 0; r < 4; ++r) {
            const int gm = bm + w * 32 + mi * 16 + quad * 4 + r;
            const float nxm = nx[gm] * SC2;
            f16x4 ov0, ov1;
            #pragma unroll
            for (int nn = 0; nn < 4; ++nn) {
                float s0 = fsqrt(fmaxf(
                    fmaf(acc[mi][nn][r], c2, nxm + nl[nn]), 0.f));
                float s1 = fsqrt(fmaxf(
                    fmaf(acc[mi][4 + nn][r], c2, nxm + nl[4 + nn]), 0.f));
                if (mat) {
                    if (gm == jb + nn) s0 = 5.0e6f;
                    if (gm == jb + 64 + nn) s1 = 5.0e6f;
                }
                acc[mi][nn][r] = s0;
                acc[mi][4 + nn][r] = s1;
                ov0[nn] = (f16)(-s0);
                ov1[nn] = (f16)(-s1);
            }
            *(f16x4*)(Out + (size_t)gm * N + jb) = ov0;
            *(f16x4*)(Out + (size_t)gm * N + jb + 64) = ov1;
        }
    // --- row mins of s (== -row max of a): in-lane over 8 ni, DPP over l16 ---
    float m[2][4];
    #pragma unroll
    for (int mi = 0; mi < 2; ++mi)
        #pragma unroll
        for (int r = 0; r < 4; ++r) {
            float v = fminf(fminf(fminf(acc[mi][0][r], acc[mi][1][r]),
                                  fminf(acc[mi][2][r], acc[mi][3][r])),
                            fminf(fminf(acc[mi][4][r], acc[mi][5][r]),
                                  fminf(acc[mi][6][r], acc[mi][7][r])));
            v = fminf(v, dppf<0xB1>(v));
            v = fminf(v, dppf<0x4E>(v));
            v = fminf(v, dppf<0x141>(v));
            v = fminf(v, dppf<0x140>(v));
            m[mi][r] = v;
        }
    // --- wave-shared shift mn (min s over the wave's 32 rows x 128 cols) ---
    float mn = fminf(fminf(fminf(m[0][0], m[0][1]), fminf(m[0][2], m[0][3])),
                     fminf(fminf(m[1][0], m[1][1]), fminf(m[1][2], m[1][3])));
    mn = fminf(mn, __shfl_xor(mn, 16));
    mn = fminf(mn, __shfl_xor(mn, 32));
    // --- single exp pass: e = 2^(mn - s) feeds row sums (sig) + col sums ---
    float sig[2][4] = {};
    float cs[8] = {};
    #pragma unroll
    for (int mi = 0; mi < 2; ++mi)
        #pragma unroll
        for (int ni = 0; ni < 8; ++ni) {
            float e0 = fexp2(mn - acc[mi][ni][0]);
            float e1 = fexp2(mn - acc[mi][ni][1]);
            float e2 = fexp2(mn - acc[mi][ni][2]);
            float e3 = fexp2(mn - acc[mi][ni][3]);
            sig[mi][0] += e0; sig[mi][1] += e1;
            sig[mi][2] += e2; sig[mi][3] += e3;
            cs[ni] += (e0 + e1) + (e2 + e3);
        }
    // --- row partials: DPP tree-sum sig, rescale to row max (a-domain) ---
    const int ct = blockIdx.x;
    #pragma unroll
    for (int mi = 0; mi < 2; ++mi)
        #pragma unroll
        for (int r = 0; r < 4; ++r) {
            float s = sig[mi][r];
            s += dppf<0xB1>(s);
            s += dppf<0x4E>(s);
            s += dppf<0x141>(s);
            s += dppf<0x140>(s);
            s *= fexp2(m[mi][r] - mn);
            if (l16 == 0) {
                int grow = bm + w * 32 + mi * 16 + quad * 4 + r;
                prm[(size_t)ct * N + grow] = -m[mi][r];
                prs[(size_t)ct * N + grow] = s;
            }
        }
    // --- col partials (pos only): quad-reduce cs, shift is -mn (uniform) ---
    if (mat == 0) {
        const int rt = blockIdx.y * 4 + w;      // 32-row tiles -> 128 planes
        #pragma unroll
        for (int ni = 0; ni < 8; ++ni) {
            cs[ni] += __shfl_xor(cs[ni], 16);
            cs[ni] += __shfl_xor(cs[ni], 32);
        }
        if (quad == 0) {
            float4 c0 = {cs[0], cs[1], cs[2], cs[3]};
            float4 c1 = {cs[4], cs[5], cs[6], cs[7]};
            float4 m4 = {-mn, -mn, -mn, -mn};
            *(float4*)(pcs_p + (size_t)rt * N + jb) = c0;
            *(float4*)(pcs_p + (size_t)rt * N + jb + 64) = c1;
            *(float4*)(pcm_p + (size_t)rt * N + jb) = m4;
            *(float4*)(pcm_p + (size_t)rt * N + jb + 64) = m4;
        }
    }
}

// ---------------------------------------------------------------------------
// Combine partials into row/col softmax stats — parallel (192 x 256).
// ---------------------------------------------------------------------------
__global__ __launch_bounds__(256) void stats_combine(
    const float* __restrict__ prm_p, const float* __restrict__ prs_p,
    const float* __restrict__ prm_n, const float* __restrict__ prs_n,
    const float* __restrict__ pcm_p, const float* __restrict__ pcs_p,
    float* __restrict__ m_row, float* __restrict__ isr,
    float* __restrict__ m_col, float* __restrict__ isc)
{
    __shared__ float Ms[4][64], Ss[4][64];
    const int t = threadIdx.x;
    const int g = t >> 6, l = t & 63;
    const int idx = blockIdx.x * 64 + l;

    float m = -3.0e38f, s = 0.f;
    if (idx < N) {
        const int i = idx;
        const int c0 = g * 8;
        #pragma unroll 4
        for (int c = c0; c < c0 + 8; ++c) {
            m = fmaxf(m, prm_p[(size_t)c * N + i]);
            m = fmaxf(m, prm_n[(size_t)c * N + i]);
        }
        #pragma unroll 4
        for (int c = c0; c < c0 + 8; ++c) {
            s += prs_p[(size_t)c * N + i] * fexp2(prm_p[(size_t)c * N + i] - m);
            s += prs_n[(size_t)c * N + i] * fexp2(prm_n[(size_t)c * N + i] - m);
        }
    } else {
        const int mat = (idx - N) >> 12;
        const int j = idx & (N - 1);
        const float* pm = mat ? prm_n : pcm_p;
        const float* ps = mat ? prs_n : pcs_p;
        const int cnt = mat ? 8 : 32;
        const int cb = g * cnt;
        #pragma unroll 4
        for (int c = cb; c < cb + cnt; ++c)
            m = fmaxf(m, pm[(size_t)c * N + j]);
        #pragma unroll 4
        for (int c = cb; c < cb + cnt; ++c)
            s += ps[(size_t)c * N + j] * fexp2(pm[(size_t)c * N + j] - m);
    }
    Ms[g][l] = m; Ss[g][l] = s;
    __syncthreads();
    if (g == 0) {
        float m0 = Ms[0][l], m1 = Ms[1][l], m2 = Ms[2][l], m3 = Ms[3][l];
        float mm = fmaxf(fmaxf(m0, m1), fmaxf(m2, m3));
        float ss = Ss[0][l] * fexp2(m0 - mm) + Ss[1][l] * fexp2(m1 - mm)
                 + Ss[2][l] * fexp2(m2 - mm) + Ss[3][l] * fexp2(m3 - mm);
        if (idx < N) {
            m_row[idx] = mm;
            isr[idx] = 1.0f / sqrtf(ss);
        } else {
            const int mat = (idx - N) >> 12;
            const int j = idx & (N - 1);
            m_col[mat * N + j] = mm;
            isc[mat * N + j] = 1.0f / sqrtf(ss);
        }
    }
}

// ---------------------------------------------------------------------------
// pv via MFMA: A fp16 tile (log2 domain) -> P (fp32 rowsums -> per-KSPLIT
// partial stores, deterministic), split P (trunc) to bf16 hi/lo in LDS,
// MFMA P @ B (B = RTN-bf16 transposed [d][j], hi only).
// ---------------------------------------------------------------------------
__global__ __launch_bounds__(256) void pv_mfma(
    const f16* __restrict__ Apos, const f16* __restrict__ Aneg,
    const u16* __restrict__ Yth, const u16* __restrict__ Xth,
    const float* __restrict__ m_row, const float* __restrict__ isr,
    const float* __restrict__ m_col, const float* __restrict__ isc,
    float* __restrict__ u_part, float* __restrict__ w_part,
    float* __restrict__ sp_part, float* __restrict__ sn_part)
{
    const int mat = blockIdx.z;
    const f16* Am = mat ? Aneg : Apos;
    const u16* Bh = mat ? Xth : Yth;
    const float* mc = m_col + mat * N;
    const float* ic = isc + mat * N;
    float* Cp = (mat ? w_part : u_part) + (size_t)blockIdx.y * (N * D);
    float* spn = (mat ? sn_part : sp_part) + (size_t)blockIdx.y * N;

    __shared__ u16 BhS[128][72];
    __shared__ u16 PhS[64][72], PlS[64][72];
    __shared__ float mrS[64], isrS[64];

    const int t = threadIdx.x;
    const int w = t >> 6, lane = t & 63;
    const int quad = lane >> 4, l16 = lane & 15;
    const int bm = blockIdx.x * 64;
    const int jbase = blockIdx.y * (N / KSPLIT);
    const int arow = t >> 4;          // 0..15
    const int aj = (t & 15) << 2;     // 0..60

    if (t < 64) { mrS[t] = m_row[bm + t]; isrS[t] = isr[bm + t]; }

    f32x4 acc[8] = {};
    float rs[4] = {0.f, 0.f, 0.f, 0.f};

    for (int jt = 0; jt < (N / KSPLIT) / 64; ++jt) {
        const int j0 = jbase + jt * 64;
        __syncthreads();   // protect previous iteration's LDS reads (+ mrS init)
        #pragma unroll
        for (int p = 0; p < 4; ++p) {
            int slot = t + p * 256;
            int d = slot >> 3, joff = (slot & 7) << 3;
            *(u16x8*)&BhS[d][joff] = *(const u16x8*)(Bh + (size_t)d * N + j0 + joff);
        }
        float4 mcv = *(const float4*)(mc + j0 + aj);
        float4 icv = *(const float4*)(ic + j0 + aj);
        #pragma unroll
        for (int s = 0; s < 4; ++s) {
            int row = arow + s * 16;
            f16x4 av = *(const f16x4*)(Am + (size_t)(bm + row) * N + j0 + aj);
            float mr = mrS[row], sr = isrS[row];
            float p0 = fexp2((float)av.x - 0.5f * (mr + mcv.x)) * (sr * icv.x);
            float p1 = fexp2((float)av.y - 0.5f * (mr + mcv.y)) * (sr * icv.y);
            float p2 = fexp2((float)av.z - 0.5f * (mr + mcv.z)) * (sr * icv.z);
            float p3 = fexp2((float)av.w - 0.5f * (mr + mcv.w)) * (sr * icv.w);
            rs[s] += p0 + p1 + p2 + p3;
            ushort4 hv, lv;
            split1_trunc(p0, hv.x, lv.x); split1_trunc(p1, hv.y, lv.y);
            split1_trunc(p2, hv.z, lv.z); split1_trunc(p3, hv.w, lv.w);
            *(ushort4*)&PhS[row][aj] = hv;
            *(ushort4*)&PlS[row][aj] = lv;
        }
        __syncthreads();
        #pragma unroll
        for (int ks = 0; ks < 2; ++ks) {
            const int kk = ks * 32 + quad * 8;
            bf16x8 ph = *(const bf16x8*)&PhS[w * 16 + l16][kk];
            bf16x8 pl = *(const bf16x8*)&PlS[w * 16 + l16][kk];
            #pragma unroll
            for (int ni = 0; ni < 8; ++ni) {
                bf16x8 bh = *(const bf16x8*)&BhS[ni * 16 + l16][kk];
                acc[ni] = MFMA(ph, bh, acc[ni]);
                acc[ni] = MFMA(pl, bh, acc[ni]);
            }
        }
    }
    #pragma unroll
    for (int ni = 0; ni < 8; ++ni)
        #pragma unroll
        for (int r = 0; r < 4; ++r) {
            int row = w * 16 + quad * 4 + r;
            int col = ni * 16 + l16;
            Cp[(size_t)(bm + row) * D + col] = acc[ni][r];
        }
    #pragma unroll
    for (int s = 0; s < 4; ++s) {
        float v = rs[s];
        v += __shfl_xor(v, 1); v += __shfl_xor(v, 2);
        v += __shfl_xor(v, 4); v += __shfl_xor(v, 8);
        if (l16 == 0) spn[bm + arow + s * 16] = v;   // unique writer per (y,row)
    }
}

// ---------------------------------------------------------------------------
// Sum split-K partials (fixed order), V = sn*u - sp*sn*w, per-block V^2
// partial into acc_part (no atomics — finalize does the deterministic sum).
// ---------------------------------------------------------------------------
__global__ __launch_bounds__(256) void final_reduce(const float* __restrict__ u_part,
    const float* __restrict__ w_part, const float* __restrict__ sp_part,
    const float* __restrict__ sn_part, double* __restrict__ acc_part)
{
    __shared__ float red[256];
    const int t = threadIdx.x;
    const int idx = blockIdx.x * 256 + t;
    float u = 0.f, w = 0.f;
    #pragma unroll
    for (int c = 0; c < KSPLIT; ++c) {
        u += u_part[(size_t)c * (N * D) + idx];
        w += w_part[(size_t)c * (N * D) + idx];
    }
    const int i = idx >> 7;
    float sp = 0.f, sn = 0.f;
    #pragma unroll
    for (int c = 0; c < KSPLIT; ++c) {
        sp += sp_part[(size_t)c * N + i];
        sn += sn_part[(size_t)c * N + i];
    }
    const float v = sn * u - sp * sn * w;
    red[t] = v * v; __syncthreads();
    for (int s = 128; s > 0; s >>= 1) { if (t < s) red[t] += red[t + s]; __syncthreads(); }
    if (!t) acc_part[blockIdx.x] = (double)red[0];
}

// ---------------------------------------------------------------------------
// Deterministic final sum: 2048 double partials, fixed-order + fixed tree.
// ---------------------------------------------------------------------------
__global__ __launch_bounds__(256) void finalize(const double* __restrict__ acc_part,
                                                float* __restrict__ out)
{
    __shared__ double red[256];
    const int t = threadIdx.x;
    double s = 0.0;
    #pragma unroll
    for (int i = 0; i < 8; ++i) s += acc_part[t + i * 256];
    red[t] = s; __syncthreads();
    for (int st = 128; st > 0; st >>= 1) {
        if (t < st) red[t] += red[t + st];
        __syncthreads();
    }
    if (!t) out[0] = (float)(red[0] * (1.0 / ((double)N * (double)D)));
}

// ---------------------------------------------------------------------------
extern "C" void kernel_launch(void* const* d_in, const int* in_sizes, int n_in,
                              void* d_out, int out_size, void* d_ws, size_t ws_size,
                              hipStream_t stream)
{
    const float* y_pos = (const float*)d_in[0];
    const float* eps   = (const float*)d_in[1];
    const float* W_in  = (const float*)d_in[2];
    const float* b_in  = (const float*)d_in[3];
    const float* W_blk = (const float*)d_in[4];
    const float* b_blk = (const float*)d_in[5];
    const float* W_out = (const float*)d_in[6];
    const float* b_out = (const float*)d_in[7];
    float* out = (float*)d_out;
    (void)in_sizes; (void)n_in; (void)out_size; (void)ws_size;

    char* p = (char*)d_ws;
    auto alloc = [&](size_t bytes) {
        char* r = p;
        p += (bytes + 255) & ~(size_t)255;
        return r;
    };
    // --- small arrays ---
    double* acc_part = (double*)alloc(2048 * 8);
    float* sp_part = (float*)alloc((size_t)KSPLIT * N * 4);
    float* sn_part = (float*)alloc((size_t)KSPLIT * N * 4);
    float* m_row  = (float*)alloc(N * 4);
    float* isr    = (float*)alloc(N * 4);
    float* m_col  = (float*)alloc(2 * N * 4);
    float* isc    = (float*)alloc(2 * N * 4);
    float* nx     = (float*)alloc(N * 4);
    float* ny     = (float*)alloc(N * 4);
    // --- xo fp32 + bf16 x/y arrays (hi only) ---
    float* xo  = (float*)alloc((size_t)N * D * 4);
    u16* xh    = (u16*)alloc((size_t)N * D * 2);
    u16* xth   = (u16*)alloc((size_t)N * D * 2);
    u16* yh    = (u16*)alloc((size_t)N * D * 2);
    u16* yth   = (u16*)alloc((size_t)N * D * 2);
    // --- shared region (16 MB): weights hi (2.3 MB, dead after gen_fused),
    //     then stats partials (6 MB), then u/w_part (16 MB) ---
    char* genreg = alloc((size_t)KSPLIT * N * D * 4 * 2);
    u16* wih = (u16*)genreg;
    u16* wbh = wih + (size_t)H * D;
    u16* woh = wbh + (size_t)4 * H * H;
    // aliases (disjoint lifetimes, stream-ordered):
    float* prm_p = (float*)genreg;                 // 32*N each = 0.5 MB
    float* prs_p = prm_p + 32 * N;
    float* prm_n = prs_p + 32 * N;
    float* prs_n = prm_n + 32 * N;
    float* pcm_p = prs_n + 32 * N;                 // 128*N = 2 MB each
    float* pcs_p = pcm_p + 128 * N;                // ends at 6 MB
    float* u_part = (float*)genreg;                // KSPLIT*N*D = 8 MB
    float* w_part = u_part + (size_t)KSPLIT * N * D;
    // --- the big ones (64 MB, fp16) ---
    f16* Apos = (f16*)alloc((size_t)N * N * 2);
    f16* Aneg = (f16*)alloc((size_t)N * N * 2);

    // --- RTN-convert y_pos + weights to bf16 hi ---
    SplitArgs sa;
    sa.d[0] = { y_pos, yh,  N * D };
    sa.d[1] = { W_in,  wih, H * D };
    sa.d[2] = { W_blk, wbh, 4 * H * H };
    sa.d[3] = { W_out, woh, D * H };
    split_multi<<<dim3(1024, 4), 256, 0, stream>>>(sa);

    // --- FUSED generator: whole 6-layer chain, x LDS-resident ---
    gen_fused<<<N / 16, 512, 0, stream>>>(eps, wih, wbh, woh,
                                          b_in, b_blk, b_out, xo, xh);

    // --- deterministic row norms (nx from xo, ny from y_pos) ---
    rownorm<<<dim3(N / 64, 2), 256, 0, stream>>>(xo, y_pos, nx, ny);

    // --- RTN transposes ---
    transpose_rtn<<<dim3(N / 32, D / 32, 2), 256, 0, stream>>>(
        xo, y_pos, xth, yth);

    // --- distance matrices (fp16 log2-domain, single-bf16 MFMA) + stats ---
    dist_fused<<<dim3(N / 128, N / 128, 2), 256, 0, stream>>>(
        xh, yh, nx, ny, Apos, Aneg,
        prm_p, prs_p, pcm_p, pcs_p, prm_n, prs_n);

    // --- combine partials into m_row/isr, m_col/isc (parallel) ---
    stats_combine<<<192, 256, 0, stream>>>(prm_p, prs_p, prm_n, prs_n,
                                           pcm_p, pcs_p,
                                           m_row, isr, m_col, isc);

    // --- P@V via MFMA (P built on the fly; sp/sn deterministic partials) ---
    pv_mfma<<<dim3(N / 64, KSPLIT, 2), 256, 0, stream>>>(Apos, Aneg,
        yth, xth, m_row, isr, m_col, isc, u_part, w_part, sp_part, sn_part);

    // --- combine partials, V^2 reduction (no atomics) ---
    final_reduce<<<(N * D) / 256, 256, 0, stream>>>(u_part, w_part,
                                                    sp_part, sn_part, acc_part);
    finalize<<<1, 256, 0, stream>>>(acc_part, out);
}

// Round 6
// 227.458 us; speedup vs baseline: 1.3772x; 1.0063x over previous
//
#include <hip/hip_runtime.h>
#include <math.h>

#define N 4096
#define D 128
#define H 512
#define KSPLIT 4
// 5 * log2(e): distances stored in log2 domain so all softmax exps are raw v_exp_f32
#define SC_LOG2 7.2134752044f

typedef short bf16x8 __attribute__((ext_vector_type(8)));
typedef float f32x4 __attribute__((ext_vector_type(4)));
typedef unsigned short u16x8 __attribute__((ext_vector_type(8)));
typedef unsigned short u16;
typedef _Float16 f16;
typedef _Float16 f16x4 __attribute__((ext_vector_type(4)));

#define MFMA(a, b, c) __builtin_amdgcn_mfma_f32_16x16x32_bf16((a), (b), (c), 0, 0, 0)

__device__ __forceinline__ float fexp2(float x)
{
#if __has_builtin(__builtin_amdgcn_exp2f)
    return __builtin_amdgcn_exp2f(x);
#else
    return exp2f(x);
#endif
}

// Raw v_sqrt_f32 (~2 ULP) — downstream is f16-quantized anyway.
__device__ __forceinline__ float fsqrt(float x)
{
#if __has_builtin(__builtin_amdgcn_sqrtf)
    return __builtin_amdgcn_sqrtf(x);
#else
    return sqrtf(x);
#endif
}

__device__ __forceinline__ float bf2f(u16 h)
{
    return __uint_as_float(((unsigned)h) << 16);
}

// Round-to-nearest bf16 (unbiased) — for operands whose hi is used ALONE.
__device__ __forceinline__ u16 rtn_bf16(float v)
{
    unsigned u = __float_as_uint(v);
    return (u16)((u + 0x7FFFu + ((u >> 16) & 1u)) >> 16);
}

// RTN split (hi usable alone; lo compensates).
__device__ __forceinline__ void split1(float v, u16& h, u16& l)
{
    u16 hh = rtn_bf16(v);
    float r = v - bf2f(hh);
    h = hh;
    l = rtn_bf16(r);
}

// Cheap truncation split (3 ops); hi+lo pair accuracy identical.
__device__ __forceinline__ void split1_trunc(float v, u16& h, u16& l)
{
    unsigned bv = __float_as_uint(v);
    unsigned hb = bv & 0xFFFF0000u;
    float r = v - __uint_as_float(hb);
    h = (u16)(hb >> 16);
    l = (u16)(__float_as_uint(r) >> 16);
}

// DPP cross-lane move within 16-lane rows (pure VALU — no DS latency).
template <int CTRL>
__device__ __forceinline__ float dppf(float x)
{
    int r = __builtin_amdgcn_update_dpp(0, __float_as_int(x), CTRL, 0xF, 0xF, true);
    return __int_as_float(r);
}

// ---------------------------------------------------------------------------
// RTN-bf16 converter for 4 flat fp32 arrays (hi only).
// ---------------------------------------------------------------------------
struct SplitDesc { const float* src; u16* h; int n; };
struct SplitArgs { SplitDesc d[4]; };

__global__ __launch_bounds__(256) void split_multi(SplitArgs args)
{
    SplitDesc de = args.d[blockIdx.y];
    int idx = (blockIdx.x * 256 + threadIdx.x) * 4;
    if (idx >= de.n) return;
    float4 v = *(const float4*)(de.src + idx);
    ushort4 hv;
    hv.x = rtn_bf16(v.x); hv.y = rtn_bf16(v.y);
    hv.z = rtn_bf16(v.z); hv.w = rtn_bf16(v.w);
    *(ushort4*)(de.h + idx) = hv;
}

// ---------------------------------------------------------------------------
// One generator layer (output width 512 -> x LDS update). K compile-time so
// the NT loop fully unrolls; PF=4-deep explicit prefetch ring (issue-before-
// MFMA) keeps ~16 W-loads in flight. R5's version compiled to VGPR=44 (the
// compiler targeted 4-blocks/CU occupancy the 256-block grid never reaches)
// and serialized every W load behind vmcnt(0) -> 78 us. With
// __launch_bounds__(512,2) the budget is 256 VGPR and the ring fits.
// ---------------------------------------------------------------------------
template <int K, bool RR>
__device__ __forceinline__ void gen_layer(
    u16 (&XhS)[16][520], u16 (&XlS)[16][520],
    const u16* __restrict__ W, const float* __restrict__ bias,
    int w, int quad, int l16)
{
    const int nb = w * 64;
    constexpr int NT = K >> 5;
    constexpr int PF = NT < 4 ? NT : 4;
    f32x4 acc[4] = {};
    const u16* wp[4];
    #pragma unroll
    for (int ni = 0; ni < 4; ++ni)
        wp[ni] = W + (size_t)(nb + ni * 16 + l16) * K + quad * 8;
    // bias loads issued up front (overlap with K-loop)
    float bl4[4];
    #pragma unroll
    for (int ni = 0; ni < 4; ++ni) bl4[ni] = bias[nb + ni * 16 + l16];
    // prefetch ring
    bf16x8 B[PF][4];
    #pragma unroll
    for (int s = 0; s < PF; ++s)
        #pragma unroll
        for (int ni = 0; ni < 4; ++ni)
            B[s][ni] = *(const bf16x8*)(wp[ni] + s * 32);
    #pragma unroll
    for (int kt = 0; kt < NT; ++kt) {
        const int kk = kt * 32 + quad * 8;
        // issue next-stage loads BEFORE the MFMAs consuming this stage
        bf16x8 bn[4];
        if (kt + PF < NT) {
            #pragma unroll
            for (int ni = 0; ni < 4; ++ni)
                bn[ni] = *(const bf16x8*)(wp[ni] + (kt + PF) * 32);
        }
        bf16x8 af  = *(const bf16x8*)&XhS[l16][kk];
        bf16x8 alf = *(const bf16x8*)&XlS[l16][kk];
        #pragma unroll
        for (int ni = 0; ni < 4; ++ni) {
            acc[ni] = MFMA(af,  B[kt % PF][ni], acc[ni]);
            acc[ni] = MFMA(alf, B[kt % PF][ni], acc[ni]);
        }
        if (kt + PF < NT) {
            #pragma unroll
            for (int ni = 0; ni < 4; ++ni)
                B[kt % PF][ni] = bn[ni];        // rename, free when unrolled
        }
    }
    __syncthreads();                            // all waves done reading x
    #pragma unroll
    for (int ni = 0; ni < 4; ++ni) {
        const int col = nb + ni * 16 + l16;
        #pragma unroll
        for (int r = 0; r < 4; ++r) {
            const int row = quad * 4 + r;
            float v = acc[ni][r] + bl4[ni];
            if (RR) {
                float prev = bf2f(XhS[row][col]) + bf2f(XlS[row][col]);
                v = prev + fmaxf(v, 0.0f);
            }
            u16 hh, ll;
            split1_trunc(v, hh, ll);
            XhS[row][col] = hh;
            XlS[row][col] = ll;
        }
    }
    __syncthreads();                            // x updated for next layer
}

// ---------------------------------------------------------------------------
// FUSED generator: each block owns 16 rows of x, runs ALL 6 layers with x
// resident in LDS (hi/lo bf16, 33 KB). W direct global->VGPR (L2-broadcast
// across the 256 blocks). 8 waves x 64-col chunks. Zero K-loop barriers.
// ---------------------------------------------------------------------------
__global__ __launch_bounds__(512, 2) void gen_fused(
    const float* __restrict__ eps,
    const u16* __restrict__ Win, const u16* __restrict__ Wblk,
    const u16* __restrict__ Wout,
    const float* __restrict__ b_in, const float* __restrict__ b_blk,
    const float* __restrict__ b_out,
    float* __restrict__ xo, u16* __restrict__ xh)
{
    __shared__ u16 XhS[16][520], XlS[16][520];
    const int t = threadIdx.x;
    const int w = t >> 6, lane = t & 63;
    const int quad = lane >> 4, l16 = lane & 15;
    const int bm = blockIdx.x * 16;

    // --- stage eps rows -> x LDS (split1 RTN) ---
    {
        int idx = t * 4;                       // 0..2047 over 16x128
        int row = idx >> 7, col = idx & 127;
        float4 v = *(const float4*)(eps + (size_t)(bm + row) * D + col);
        ushort4 hv, lv;
        split1(v.x, hv.x, lv.x); split1(v.y, hv.y, lv.y);
        split1(v.z, hv.z, lv.z); split1(v.w, hv.w, lv.w);
        *(ushort4*)&XhS[row][col] = hv;
        *(ushort4*)&XlS[row][col] = lv;
    }
    __syncthreads();

    gen_layer<D, false>(XhS, XlS, Win, b_in, w, quad, l16);
    for (int i = 0; i < 4; ++i)
        gen_layer<H, true>(XhS, XlS, Wblk + (size_t)i * H * H, b_blk + i * H,
                           w, quad, l16);

    // --- last layer: out width 128, fp32 xo + RTN xh to global ---
    {
        const int n0 = w * 16;                 // 8 waves x 16 cols
        constexpr int NT = H >> 5;
        constexpr int PF = 4;
        f32x4 acc5 = {};
        const u16* wp = Wout + (size_t)(n0 + l16) * H + quad * 8;
        const float bl = b_out[n0 + l16];
        bf16x8 B5[PF];
        #pragma unroll
        for (int s = 0; s < PF; ++s)
            B5[s] = *(const bf16x8*)(wp + s * 32);
        #pragma unroll
        for (int kt = 0; kt < NT; ++kt) {
            const int kk = kt * 32 + quad * 8;
            bf16x8 bn5;
            if (kt + PF < NT)
                bn5 = *(const bf16x8*)(wp + (kt + PF) * 32);
            bf16x8 af  = *(const bf16x8*)&XhS[l16][kk];
            bf16x8 alf = *(const bf16x8*)&XlS[l16][kk];
            acc5 = MFMA(af,  B5[kt % PF], acc5);
            acc5 = MFMA(alf, B5[kt % PF], acc5);
            if (kt + PF < NT) B5[kt % PF] = bn5;
        }
        const int col = n0 + l16;
        #pragma unroll
        for (int r = 0; r < 4; ++r) {
            const int gm = bm + quad * 4 + r;
            float v = acc5[r] + bl;
            xo[(size_t)gm * D + col] = v;
            xh[(size_t)gm * D + col] = rtn_bf16(v);
        }
    }
}

// ---------------------------------------------------------------------------
// Deterministic row-norms: nx from xo, ny from y_pos. 4 threads/row, fixed
// order + fixed 2-step shfl tree (replaces the fp-atomic path that tripped
// the bit-identical-replay check).
// ---------------------------------------------------------------------------
__global__ __launch_bounds__(256) void rownorm(
    const float* __restrict__ X, const float* __restrict__ Y,
    float* __restrict__ nx, float* __restrict__ ny)
{
    const float* src = blockIdx.y ? Y : X;
    float* dst = blockIdx.y ? ny : nx;
    const int t = threadIdx.x;
    const int row = blockIdx.x * 64 + (t >> 2);
    const int q = t & 3;
    const float* rp = src + (size_t)row * D + q * 32;
    float s = 0.f;
    #pragma unroll
    for (int i = 0; i < 8; ++i) {
        float4 v = *(const float4*)(rp + i * 4);
        s += v.x * v.x + v.y * v.y + v.z * v.z + v.w * v.w;
    }
    s += __shfl_xor(s, 1);
    s += __shfl_xor(s, 2);
    if (q == 0) dst[row] = s;
}

// ---------------------------------------------------------------------------
// Transpose + RTN-bf16 (pure — norms moved to rownorm).
// ---------------------------------------------------------------------------
__global__ __launch_bounds__(256) void transpose_rtn(
    const float* __restrict__ X, const float* __restrict__ Y,
    u16* __restrict__ Xth, u16* __restrict__ Yth)
{
    const float* src = blockIdx.z ? Y : X;
    u16* th = blockIdx.z ? Yth : Xth;
    __shared__ float tile[32][33];
    const int t = threadIdx.x;
    const int r0 = blockIdx.x * 32, c0 = blockIdx.y * 32;
    {
        int rit = t >> 3, coff = (t & 7) * 4;
        float4 v = *(const float4*)(src + (size_t)(r0 + rit) * D + c0 + coff);
        tile[rit][coff + 0] = v.x; tile[rit][coff + 1] = v.y;
        tile[rit][coff + 2] = v.z; tile[rit][coff + 3] = v.w;
    }
    __syncthreads();
    {
        int cit = t >> 3, roff = (t & 7) * 4;
        ushort4 hv;
        hv.x = rtn_bf16(tile[roff + 0][cit]);
        hv.y = rtn_bf16(tile[roff + 1][cit]);
        hv.z = rtn_bf16(tile[roff + 2][cit]);
        hv.w = rtn_bf16(tile[roff + 3][cit]);
        *(ushort4*)(th + (size_t)(c0 + cit) * N + r0 + roff) = hv;
    }
}

// ---------------------------------------------------------------------------
// Distance via SINGLE RTN-bf16 MFMA, fused stats, pos+neg merged. A fp16,
// stored in LOG2 domain. Epilogue in POSITIVE s-domain: raw v_sqrt_f32,
// SC^2 folded into norms, per-element diag cndmask.
// Tile 128(M)x128(N), 4 waves each owning 32 rows x full 128 cols.
// ---------------------------------------------------------------------------
__global__ __launch_bounds__(256) void dist_fused(
    const u16* __restrict__ Xh, const u16* __restrict__ Yh,
    const float* __restrict__ nx, const float* __restrict__ ny,
    f16* __restrict__ Apos, f16* __restrict__ Aneg,
    float* __restrict__ prm_p, float* __restrict__ prs_p,
    float* __restrict__ pcm_p, float* __restrict__ pcs_p,
    float* __restrict__ prm_n, float* __restrict__ prs_n)
{
    const int mat = blockIdx.z;                // 0: X vs Y ; 1: X vs X
    const u16* Bhp = mat ? Xh : Yh;
    const float* nb = mat ? nx : ny;
    f16* Out = mat ? Aneg : Apos;
    float* prm = mat ? prm_n : prm_p;
    float* prs = mat ? prs_n : prs_p;

    __shared__ u16 XhS[128][40], YhS[128][40];
    const int t = threadIdx.x;
    const int w = t >> 6, lane = t & 63;
    const int quad = lane >> 4, l16 = lane & 15;
    const int bm = blockIdx.y * 128, bn = blockIdx.x * 128;
    f32x4 acc[2][8] = {};

    for (int k0 = 0; k0 < D; k0 += 32) {
        __syncthreads();
        #pragma unroll
        for (int p = 0; p < 2; ++p) {
            int slot = t + p * 256;            // 512 slots = 128 rows x 4 octets
            int row = slot >> 2, koff = (slot & 3) << 3;
            *(u16x8*)&XhS[row][koff] =
                *(const u16x8*)(Xh + (size_t)(bm + row) * D + k0 + koff);
        }
        #pragma unroll
        for (int p = 0; p < 2; ++p) {
            int slot = t + p * 256;
            int row = slot >> 2, koff = (slot & 3) << 3;
            int pr = ((row & 3) << 4) | ((row & 63) >> 2) | (row & 64);
            int kf = koff ^ (((pr >> 4) & 3) << 3);
            *(u16x8*)&YhS[pr][kf] =
                *(const u16x8*)(Bhp + (size_t)(bn + row) * D + k0 + koff);
        }
        __syncthreads();
        bf16x8 af[2], bhf[8];
        #pragma unroll
        for (int mi = 0; mi < 2; ++mi)
            af[mi] = *(const bf16x8*)&XhS[w * 32 + mi * 16 + l16][quad * 8];
        #pragma unroll
        for (int ni = 0; ni < 8; ++ni) {
            int nn = ni & 3, hf = ni >> 2;
            bhf[ni] = *(const bf16x8*)
                &YhS[hf * 64 + nn * 16 + l16][(quad * 8) ^ (nn << 3)];
        }
        #pragma unroll
        for (int mi = 0; mi < 2; ++mi)
            #pragma unroll
            for (int ni = 0; ni < 8; ++ni)
                acc[mi][ni] = MFMA(af[mi], bhf[ni], acc[mi][ni]);
    }
    // lane's 8 j's: jb..jb+3 and jb+64..jb+67
    const int jb = bn + (l16 << 2);
    const float SC2 = SC_LOG2 * SC_LOG2;
    const float c2 = -2.0f * SC2;
    const float4 n0v = *(const float4*)(nb + jb);
    const float4 n1v = *(const float4*)(nb + jb + 64);
    const float nl[8] = {n0v.x * SC2, n0v.y * SC2, n0v.z * SC2, n0v.w * SC2,
                         n1v.x * SC2, n1v.y * SC2, n1v.z * SC2, n1v.w * SC2};
    // --- transform in place to s = dist*SC (positive domain) + f16 stores ---
    #pragma unroll
    for (int mi = 0; mi < 2; ++mi)
        #pragma unroll
        for (int r = 0; r < 4; ++r) {
            const int gm = bm + w * 32 + mi * 16 + quad * 4 + r;
            const float nxm = nx[gm] * SC2;
            f16x4 ov0, ov1;
            #pragma unroll
            for (int nn = 0; nn < 4; ++nn) {
                float s0 = fsqrt(fmaxf(
                    fmaf(acc[mi][nn][r], c2, nxm + nl[nn]), 0.f));
                float s1 = fsqrt(fmaxf(
                    fmaf(acc[mi][4 + nn][r], c2, nxm + nl[4 + nn]), 0.f));
                if (mat) {
                    if (gm == jb + nn) s0 = 5.0e6f;
                    if (gm == jb + 64 + nn) s1 = 5.0e6f;
                }
                acc[mi][nn][r] = s0;
                acc[mi][4 + nn][r] = s1;
                ov0[nn] = (f16)(-s0);
                ov1[nn] = (f16)(-s1);
            }
            *(f16x4*)(Out + (size_t)gm * N + jb) = ov0;
            *(f16x4*)(Out + (size_t)gm * N + jb + 64) = ov1;
        }
    // --- row mins of s (== -row max of a): in-lane over 8 ni, DPP over l16 ---
    float m[2][4];
    #pragma unroll
    for (int mi = 0; mi < 2; ++mi)
        #pragma unroll
        for (int r = 0; r < 4; ++r) {
            float v = fminf(fminf(fminf(acc[mi][0][r], acc[mi][1][r]),
                                  fminf(acc[mi][2][r], acc[mi][3][r])),
                            fminf(fminf(acc[mi][4][r], acc[mi][5][r]),
                                  fminf(acc[mi][6][r], acc[mi][7][r])));
            v = fminf(v, dppf<0xB1>(v));
            v = fminf(v, dppf<0x4E>(v));
            v = fminf(v, dppf<0x141>(v));
            v = fminf(v, dppf<0x140>(v));
            m[mi][r] = v;
        }
    // --- wave-shared shift mn (min s over the wave's 32 rows x 128 cols) ---
    float mn = fminf(fminf(fminf(m[0][0], m[0][1]), fminf(m[0][2], m[0][3])),
                     fminf(fminf(m[1][0], m[1][1]), fminf(m[1][2], m[1][3])));
    mn = fminf(mn, __shfl_xor(mn, 16));
    mn = fminf(mn, __shfl_xor(mn, 32));
    // --- single exp pass: e = 2^(mn - s) feeds row sums (sig) + col sums ---
    float sig[2][4] = {};
    float cs[8] = {};
    #pragma unroll
    for (int mi = 0; mi < 2; ++mi)
        #pragma unroll
        for (int ni = 0; ni < 8; ++ni) {
            float e0 = fexp2(mn - acc[mi][ni][0]);
            float e1 = fexp2(mn - acc[mi][ni][1]);
            float e2 = fexp2(mn - acc[mi][ni][2]);
            float e3 = fexp2(mn - acc[mi][ni][3]);
            sig[mi][0] += e0; sig[mi][1] += e1;
            sig[mi][2] += e2; sig[mi][3] += e3;
            cs[ni] += (e0 + e1) + (e2 + e3);
        }
    // --- row partials: DPP tree-sum sig, rescale to row max (a-domain) ---
    const int ct = blockIdx.x;
    #pragma unroll
    for (int mi = 0; mi < 2; ++mi)
        #pragma unroll
        for (int r = 0; r < 4; ++r) {
            float s = sig[mi][r];
            s += dppf<0xB1>(s);
            s += dppf<0x4E>(s);
            s += dppf<0x141>(s);
            s += dppf<0x140>(s);
            s *= fexp2(m[mi][r] - mn);
            if (l16 == 0) {
                int grow = bm + w * 32 + mi * 16 + quad * 4 + r;
                prm[(size_t)ct * N + grow] = -m[mi][r];
                prs[(size_t)ct * N + grow] = s;
            }
        }
    // --- col partials (pos only): quad-reduce cs, shift is -mn (uniform) ---
    if (mat == 0) {
        const int rt = blockIdx.y * 4 + w;      // 32-row tiles -> 128 planes
        #pragma unroll
        for (int ni = 0; ni < 8; ++ni) {
            cs[ni] += __shfl_xor(cs[ni], 16);
            cs[ni] += __shfl_xor(cs[ni], 32);
        }
        if (quad == 0) {
            float4 c0 = {cs[0], cs[1], cs[2], cs[3]};
            float4 c1 = {cs[4], cs[5], cs[6], cs[7]};
            float4 m4 = {-mn, -mn, -mn, -mn};
            *(float4*)(pcs_p + (size_t)rt * N + jb) = c0;
            *(float4*)(pcs_p + (size_t)rt * N + jb + 64) = c1;
            *(float4*)(pcm_p + (size_t)rt * N + jb) = m4;
            *(float4*)(pcm_p + (size_t)rt * N + jb + 64) = m4;
        }
    }
}

// ---------------------------------------------------------------------------
// Combine partials into row/col softmax stats — parallel (192 x 256).
// ---------------------------------------------------------------------------
__global__ __launch_bounds__(256) void stats_combine(
    const float* __restrict__ prm_p, const float* __restrict__ prs_p,
    const float* __restrict__ prm_n, const float* __restrict__ prs_n,
    const float* __restrict__ pcm_p, const float* __restrict__ pcs_p,
    float* __restrict__ m_row, float* __restrict__ isr,
    float* __restrict__ m_col, float* __restrict__ isc)
{
    __shared__ float Ms[4][64], Ss[4][64];
    const int t = threadIdx.x;
    const int g = t >> 6, l = t & 63;
    const int idx = blockIdx.x * 64 + l;

    float m = -3.0e38f, s = 0.f;
    if (idx < N) {
        const int i = idx;
        const int c0 = g * 8;
        #pragma unroll 4
        for (int c = c0; c < c0 + 8; ++c) {
            m = fmaxf(m, prm_p[(size_t)c * N + i]);
            m = fmaxf(m, prm_n[(size_t)c * N + i]);
        }
        #pragma unroll 4
        for (int c = c0; c < c0 + 8; ++c) {
            s += prs_p[(size_t)c * N + i] * fexp2(prm_p[(size_t)c * N + i] - m);
            s += prs_n[(size_t)c * N + i] * fexp2(prm_n[(size_t)c * N + i] - m);
        }
    } else {
        const int mat = (idx - N) >> 12;
        const int j = idx & (N - 1);
        const float* pm = mat ? prm_n : pcm_p;
        const float* ps = mat ? prs_n : pcs_p;
        const int cnt = mat ? 8 : 32;
        const int cb = g * cnt;
        #pragma unroll 4
        for (int c = cb; c < cb + cnt; ++c)
            m = fmaxf(m, pm[(size_t)c * N + j]);
        #pragma unroll 4
        for (int c = cb; c < cb + cnt; ++c)
            s += ps[(size_t)c * N + j] * fexp2(pm[(size_t)c * N + j] - m);
    }
    Ms[g][l] = m; Ss[g][l] = s;
    __syncthreads();
    if (g == 0) {
        float m0 = Ms[0][l], m1 = Ms[1][l], m2 = Ms[2][l], m3 = Ms[3][l];
        float mm = fmaxf(fmaxf(m0, m1), fmaxf(m2, m3));
        float ss = Ss[0][l] * fexp2(m0 - mm) + Ss[1][l] * fexp2(m1 - mm)
                 + Ss[2][l] * fexp2(m2 - mm) + Ss[3][l] * fexp2(m3 - mm);
        if (idx < N) {
            m_row[idx] = mm;
            isr[idx] = 1.0f / sqrtf(ss);
        } else {
            const int mat = (idx - N) >> 12;
            const int j = idx & (N - 1);
            m_col[mat * N + j] = mm;
            isc[mat * N + j] = 1.0f / sqrtf(ss);
        }
    }
}

// ---------------------------------------------------------------------------
// pv via MFMA: A fp16 tile (log2 domain) -> P (fp32 rowsums -> per-KSPLIT
// partial stores, deterministic), split P (trunc) to bf16 hi/lo in LDS,
// MFMA P @ B (B = RTN-bf16 transposed [d][j], hi only).
// ---------------------------------------------------------------------------
__global__ __launch_bounds__(256) void pv_mfma(
    const f16* __restrict__ Apos, const f16* __restrict__ Aneg,
    const u16* __restrict__ Yth, const u16* __restrict__ Xth,
    const float* __restrict__ m_row, const float* __restrict__ isr,
    const float* __restrict__ m_col, const float* __restrict__ isc,
    float* __restrict__ u_part, float* __restrict__ w_part,
    float* __restrict__ sp_part, float* __restrict__ sn_part)
{
    const int mat = blockIdx.z;
    const f16* Am = mat ? Aneg : Apos;
    const u16* Bh = mat ? Xth : Yth;
    const float* mc = m_col + mat * N;
    const float* ic = isc + mat * N;
    float* Cp = (mat ? w_part : u_part) + (size_t)blockIdx.y * (N * D);
    float* spn = (mat ? sn_part : sp_part) + (size_t)blockIdx.y * N;

    __shared__ u16 BhS[128][72];
    __shared__ u16 PhS[64][72], PlS[64][72];
    __shared__ float mrS[64], isrS[64];

    const int t = threadIdx.x;
    const int w = t >> 6, lane = t & 63;
    const int quad = lane >> 4, l16 = lane & 15;
    const int bm = blockIdx.x * 64;
    const int jbase = blockIdx.y * (N / KSPLIT);
    const int arow = t >> 4;          // 0..15
    const int aj = (t & 15) << 2;     // 0..60

    if (t < 64) { mrS[t] = m_row[bm + t]; isrS[t] = isr[bm + t]; }

    f32x4 acc[8] = {};
    float rs[4] = {0.f, 0.f, 0.f, 0.f};

    for (int jt = 0; jt < (N / KSPLIT) / 64; ++jt) {
        const int j0 = jbase + jt * 64;
        __syncthreads();   // protect previous iteration's LDS reads (+ mrS init)
        #pragma unroll
        for (int p = 0; p < 4; ++p) {
            int slot = t + p * 256;
            int d = slot >> 3, joff = (slot & 7) << 3;
            *(u16x8*)&BhS[d][joff] = *(const u16x8*)(Bh + (size_t)d * N + j0 + joff);
        }
        float4 mcv = *(const float4*)(mc + j0 + aj);
        float4 icv = *(const float4*)(ic + j0 + aj);
        #pragma unroll
        for (int s = 0; s < 4; ++s) {
            int row = arow + s * 16;
            f16x4 av = *(const f16x4*)(Am + (size_t)(bm + row) * N + j0 + aj);
            float mr = mrS[row], sr = isrS[row];
            float p0 = fexp2((float)av.x - 0.5f * (mr + mcv.x)) * (sr * icv.x);
            float p1 = fexp2((float)av.y - 0.5f * (mr + mcv.y)) * (sr * icv.y);
            float p2 = fexp2((float)av.z - 0.5f * (mr + mcv.z)) * (sr * icv.z);
            float p3 = fexp2((float)av.w - 0.5f * (mr + mcv.w)) * (sr * icv.w);
            rs[s] += p0 + p1 + p2 + p3;
            ushort4 hv, lv;
            split1_trunc(p0, hv.x, lv.x); split1_trunc(p1, hv.y, lv.y);
            split1_trunc(p2, hv.z, lv.z); split1_trunc(p3, hv.w, lv.w);
            *(ushort4*)&PhS[row][aj] = hv;
            *(ushort4*)&PlS[row][aj] = lv;
        }
        __syncthreads();
        #pragma unroll
        for (int ks = 0; ks < 2; ++ks) {
            const int kk = ks * 32 + quad * 8;
            bf16x8 ph = *(const bf16x8*)&PhS[w * 16 + l16][kk];
            bf16x8 pl = *(const bf16x8*)&PlS[w * 16 + l16][kk];
            #pragma unroll
            for (int ni = 0; ni < 8; ++ni) {
                bf16x8 bh = *(const bf16x8*)&BhS[ni * 16 + l16][kk];
                acc[ni] = MFMA(ph, bh, acc[ni]);
                acc[ni] = MFMA(pl, bh, acc[ni]);
            }
        }
    }
    #pragma unroll
    for (int ni = 0; ni < 8; ++ni)
        #pragma unroll
        for (int r = 0; r < 4; ++r) {
            int row = w * 16 + quad * 4 + r;
            int col = ni * 16 + l16;
            Cp[(size_t)(bm + row) * D + col] = acc[ni][r];
        }
    #pragma unroll
    for (int s = 0; s < 4; ++s) {
        float v = rs[s];
        v += __shfl_xor(v, 1); v += __shfl_xor(v, 2);
        v += __shfl_xor(v, 4); v += __shfl_xor(v, 8);
        if (l16 == 0) spn[bm + arow + s * 16] = v;   // unique writer per (y,row)
    }
}

// ---------------------------------------------------------------------------
// Sum split-K partials (fixed order), V = sn*u - sp*sn*w, per-block V^2
// partial into acc_part (no atomics — finalize does the deterministic sum).
// ---------------------------------------------------------------------------
__global__ __launch_bounds__(256) void final_reduce(const float* __restrict__ u_part,
    const float* __restrict__ w_part, const float* __restrict__ sp_part,
    const float* __restrict__ sn_part, double* __restrict__ acc_part)
{
    __shared__ float red[256];
    const int t = threadIdx.x;
    const int idx = blockIdx.x * 256 + t;
    float u = 0.f, w = 0.f;
    #pragma unroll
    for (int c = 0; c < KSPLIT; ++c) {
        u += u_part[(size_t)c * (N * D) + idx];
        w += w_part[(size_t)c * (N * D) + idx];
    }
    const int i = idx >> 7;
    float sp = 0.f, sn = 0.f;
    #pragma unroll
    for (int c = 0; c < KSPLIT; ++c) {
        sp += sp_part[(size_t)c * N + i];
        sn += sn_part[(size_t)c * N + i];
    }
    const float v = sn * u - sp * sn * w;
    red[t] = v * v; __syncthreads();
    for (int s = 128; s > 0; s >>= 1) { if (t < s) red[t] += red[t + s]; __syncthreads(); }
    if (!t) acc_part[blockIdx.x] = (double)red[0];
}

// ---------------------------------------------------------------------------
// Deterministic final sum: 2048 double partials, fixed-order + fixed tree.
// ---------------------------------------------------------------------------
__global__ __launch_bounds__(256) void finalize(const double* __restrict__ acc_part,
                                                float* __restrict__ out)
{
    __shared__ double red[256];
    const int t = threadIdx.x;
    double s = 0.0;
    #pragma unroll
    for (int i = 0; i < 8; ++i) s += acc_part[t + i * 256];
    red[t] = s; __syncthreads();
    for (int st = 128; st > 0; st >>= 1) {
        if (t < st) red[t] += red[t + st];
        __syncthreads();
    }
    if (!t) out[0] = (float)(red[0] * (1.0 / ((double)N * (double)D)));
}

// ---------------------------------------------------------------------------
extern "C" void kernel_launch(void* const* d_in, const int* in_sizes, int n_in,
                              void* d_out, int out_size, void* d_ws, size_t ws_size,
                              hipStream_t stream)
{
    const float* y_pos = (const float*)d_in[0];
    const float* eps   = (const float*)d_in[1];
    const float* W_in  = (const float*)d_in[2];
    const float* b_in  = (const float*)d_in[3];
    const float* W_blk = (const float*)d_in[4];
    const float* b_blk = (const float*)d_in[5];
    const float* W_out = (const float*)d_in[6];
    const float* b_out = (const float*)d_in[7];
    float* out = (float*)d_out;
    (void)in_sizes; (void)n_in; (void)out_size; (void)ws_size;

    char* p = (char*)d_ws;
    auto alloc = [&](size_t bytes) {
        char* r = p;
        p += (bytes + 255) & ~(size_t)255;
        return r;
    };
    // --- small arrays ---
    double* acc_part = (double*)alloc(2048 * 8);
    float* sp_part = (float*)alloc((size_t)KSPLIT * N * 4);
    float* sn_part = (float*)alloc((size_t)KSPLIT * N * 4);
    float* m_row  = (float*)alloc(N * 4);
    float* isr    = (float*)alloc(N * 4);
    float* m_col  = (float*)alloc(2 * N * 4);
    float* isc    = (float*)alloc(2 * N * 4);
    float* nx     = (float*)alloc(N * 4);
    float* ny     = (float*)alloc(N * 4);
    // --- xo fp32 + bf16 x/y arrays (hi only) ---
    float* xo  = (float*)alloc((size_t)N * D * 4);
    u16* xh    = (u16*)alloc((size_t)N * D * 2);
    u16* xth   = (u16*)alloc((size_t)N * D * 2);
    u16* yh    = (u16*)alloc((size_t)N * D * 2);
    u16* yth   = (u16*)alloc((size_t)N * D * 2);
    // --- shared region (16 MB): weights hi (2.3 MB, dead after gen_fused),
    //     then stats partials (6 MB), then u/w_part (16 MB) ---
    char* genreg = alloc((size_t)KSPLIT * N * D * 4 * 2);
    u16* wih = (u16*)genreg;
    u16* wbh = wih + (size_t)H * D;
    u16* woh = wbh + (size_t)4 * H * H;
    // aliases (disjoint lifetimes, stream-ordered):
    float* prm_p = (float*)genreg;                 // 32*N each = 0.5 MB
    float* prs_p = prm_p + 32 * N;
    float* prm_n = prs_p + 32 * N;
    float* prs_n = prm_n + 32 * N;
    float* pcm_p = prs_n + 32 * N;                 // 128*N = 2 MB each
    float* pcs_p = pcm_p + 128 * N;                // ends at 6 MB
    float* u_part = (float*)genreg;                // KSPLIT*N*D = 8 MB
    float* w_part = u_part + (size_t)KSPLIT * N * D;
    // --- the big ones (64 MB, fp16) ---
    f16* Apos = (f16*)alloc((size_t)N * N * 2);
    f16* Aneg = (f16*)alloc((size_t)N * N * 2);

    // --- RTN-convert y_pos + weights to bf16 hi ---
    SplitArgs sa;
    sa.d[0] = { y_pos, yh,  N * D };
    sa.d[1] = { W_in,  wih, H * D };
    sa.d[2] = { W_blk, wbh, 4 * H * H };
    sa.d[3] = { W_out, woh, D * H };
    split_multi<<<dim3(1024, 4), 256, 0, stream>>>(sa);

    // --- FUSED generator: whole 6-layer chain, x LDS-resident ---
    gen_fused<<<N / 16, 512, 0, stream>>>(eps, wih, wbh, woh,
                                          b_in, b_blk, b_out, xo, xh);

    // --- deterministic row norms (nx from xo, ny from y_pos) ---
    rownorm<<<dim3(N / 64, 2), 256, 0, stream>>>(xo, y_pos, nx, ny);

    // --- RTN transposes ---
    transpose_rtn<<<dim3(N / 32, D / 32, 2), 256, 0, stream>>>(
        xo, y_pos, xth, yth);

    // --- distance matrices (fp16 log2-domain, single-bf16 MFMA) + stats ---
    dist_fused<<<dim3(N / 128, N / 128, 2), 256, 0, stream>>>(
        xh, yh, nx, ny, Apos, Aneg,
        prm_p, prs_p, pcm_p, pcs_p, prm_n, prs_n);

    // --- combine partials into m_row/isr, m_col/isc (parallel) ---
    stats_combine<<<192, 256, 0, stream>>>(prm_p, prs_p, prm_n, prs_n,
                                           pcm_p, pcs_p,
                                           m_row, isr, m_col, isc);

    // --- P@V via MFMA (P built on the fly; sp/sn deterministic partials) ---
    pv_mfma<<<dim3(N / 64, KSPLIT, 2), 256, 0, stream>>>(Apos, Aneg,
        yth, xth, m_row, isr, m_col, isc, u_part, w_part, sp_part, sn_part);

    // --- combine partials, V^2 reduction (no atomics) ---
    final_reduce<<<(N * D) / 256, 256, 0, stream>>>(u_part, w_part,
                                                    sp_part, sn_part, acc_part);
    finalize<<<1, 256, 0, stream>>>(acc_part, out);
}

// Round 7
// 227.175 us; speedup vs baseline: 1.3790x; 1.0012x over previous
//
#include <hip/hip_runtime.h>
#include <math.h>

#define N 4096
#define D 128
#define H 512
#define KSPLIT 4
// 5 * log2(e): distances stored in log2 domain so all softmax exps are raw v_exp_f32
#define SC_LOG2 7.2134752044f

typedef short bf16x8 __attribute__((ext_vector_type(8)));
typedef float f32x4 __attribute__((ext_vector_type(4)));
typedef unsigned short u16x8 __attribute__((ext_vector_type(8)));
typedef unsigned short u16;
typedef _Float16 f16;
typedef _Float16 f16x4 __attribute__((ext_vector_type(4)));

#define MFMA(a, b, c) __builtin_amdgcn_mfma_f32_16x16x32_bf16((a), (b), (c), 0, 0, 0)
#define SCHED_FENCE() __builtin_amdgcn_sched_barrier(0)

__device__ __forceinline__ float fexp2(float x)
{
#if __has_builtin(__builtin_amdgcn_exp2f)
    return __builtin_amdgcn_exp2f(x);
#else
    return exp2f(x);
#endif
}

// Raw v_sqrt_f32 (~2 ULP) — downstream is f16-quantized anyway.
__device__ __forceinline__ float fsqrt(float x)
{
#if __has_builtin(__builtin_amdgcn_sqrtf)
    return __builtin_amdgcn_sqrtf(x);
#else
    return sqrtf(x);
#endif
}

__device__ __forceinline__ float bf2f(u16 h)
{
    return __uint_as_float(((unsigned)h) << 16);
}

// Round-to-nearest bf16 (unbiased) — for operands whose hi is used ALONE.
__device__ __forceinline__ u16 rtn_bf16(float v)
{
    unsigned u = __float_as_uint(v);
    return (u16)((u + 0x7FFFu + ((u >> 16) & 1u)) >> 16);
}

// RTN split (hi usable alone; lo compensates).
__device__ __forceinline__ void split1(float v, u16& h, u16& l)
{
    u16 hh = rtn_bf16(v);
    float r = v - bf2f(hh);
    h = hh;
    l = rtn_bf16(r);
}

// Cheap truncation split (3 ops); hi+lo pair accuracy identical.
__device__ __forceinline__ void split1_trunc(float v, u16& h, u16& l)
{
    unsigned bv = __float_as_uint(v);
    unsigned hb = bv & 0xFFFF0000u;
    float r = v - __uint_as_float(hb);
    h = (u16)(hb >> 16);
    l = (u16)(__float_as_uint(r) >> 16);
}

// DPP cross-lane move within 16-lane rows (pure VALU — no DS latency).
template <int CTRL>
__device__ __forceinline__ float dppf(float x)
{
    int r = __builtin_amdgcn_update_dpp(0, __float_as_int(x), CTRL, 0xF, 0xF, true);
    return __int_as_float(r);
}

// ---------------------------------------------------------------------------
// RTN-bf16 converter for 4 flat fp32 arrays (hi only).
// ---------------------------------------------------------------------------
struct SplitDesc { const float* src; u16* h; int n; };
struct SplitArgs { SplitDesc d[4]; };

__global__ __launch_bounds__(256) void split_multi(SplitArgs args)
{
    SplitDesc de = args.d[blockIdx.y];
    int idx = (blockIdx.x * 256 + threadIdx.x) * 4;
    if (idx >= de.n) return;
    float4 v = *(const float4*)(de.src + idx);
    ushort4 hv;
    hv.x = rtn_bf16(v.x); hv.y = rtn_bf16(v.y);
    hv.z = rtn_bf16(v.z); hv.w = rtn_bf16(v.w);
    *(ushort4*)(de.h + idx) = hv;
}

// ---------------------------------------------------------------------------
// One generator layer (output width 512 -> x LDS update). K compile-time,
// PF=4-deep W prefetch ring. R5/R6 both compiled to VGPR=44: the LLVM
// scheduler SANK the ring loads back to just-before-use (pressure
// heuristic), exposing ~4 serial L2 latencies per k-step -> 76 us.
// sched_barrier(0) after the issue batch and after the MFMA cluster pins
// placement: loads for kt+PF sit architecturally above kt's MFMAs, so
// ~16 loads stay in flight behind counted vmcnt. VGPR must jump to
// ~110-140 if this takes (the verification tell).
// ---------------------------------------------------------------------------
template <int K, bool RR>
__device__ __forceinline__ void gen_layer(
    u16 (&XhS)[16][520], u16 (&XlS)[16][520],
    const u16* __restrict__ W, const float* __restrict__ bias,
    int w, int quad, int l16)
{
    const int nb = w * 64;
    constexpr int NT = K >> 5;
    constexpr int PF = NT < 4 ? NT : 4;
    f32x4 acc[4] = {};
    const u16* wp[4];
    #pragma unroll
    for (int ni = 0; ni < 4; ++ni)
        wp[ni] = W + (size_t)(nb + ni * 16 + l16) * K + quad * 8;
    float bl4[4];
    #pragma unroll
    for (int ni = 0; ni < 4; ++ni) bl4[ni] = bias[nb + ni * 16 + l16];
    // prefetch ring — issue PF stages, then fence so they can't sink
    bf16x8 B[PF][4];
    #pragma unroll
    for (int s = 0; s < PF; ++s)
        #pragma unroll
        for (int ni = 0; ni < 4; ++ni)
            B[s][ni] = *(const bf16x8*)(wp[ni] + s * 32);
    SCHED_FENCE();
    #pragma unroll
    for (int kt = 0; kt < NT; ++kt) {
        const int kk = kt * 32 + quad * 8;
        bf16x8 bn[4];
        if (kt + PF < NT) {
            #pragma unroll
            for (int ni = 0; ni < 4; ++ni)
                bn[ni] = *(const bf16x8*)(wp[ni] + (kt + PF) * 32);
        }
        SCHED_FENCE();   // loads above stay above; MFMAs below stay below
        bf16x8 af  = *(const bf16x8*)&XhS[l16][kk];
        bf16x8 alf = *(const bf16x8*)&XlS[l16][kk];
        #pragma unroll
        for (int ni = 0; ni < 4; ++ni) {
            acc[ni] = MFMA(af,  B[kt % PF][ni], acc[ni]);
            acc[ni] = MFMA(alf, B[kt % PF][ni], acc[ni]);
        }
        if (kt + PF < NT) {
            #pragma unroll
            for (int ni = 0; ni < 4; ++ni)
                B[kt % PF][ni] = bn[ni];        // rename, free when unrolled
        }
        SCHED_FENCE();
    }
    __syncthreads();                            // all waves done reading x
    #pragma unroll
    for (int ni = 0; ni < 4; ++ni) {
        const int col = nb + ni * 16 + l16;
        #pragma unroll
        for (int r = 0; r < 4; ++r) {
            const int row = quad * 4 + r;
            float v = acc[ni][r] + bl4[ni];
            if (RR) {
                float prev = bf2f(XhS[row][col]) + bf2f(XlS[row][col]);
                v = prev + fmaxf(v, 0.0f);
            }
            u16 hh, ll;
            split1_trunc(v, hh, ll);
            XhS[row][col] = hh;
            XlS[row][col] = ll;
        }
    }
    __syncthreads();                            // x updated for next layer
}

// ---------------------------------------------------------------------------
// FUSED generator: each block owns 16 rows of x, runs ALL 6 layers with x
// resident in LDS (hi/lo bf16, 33 KB). W direct global->VGPR (L2-broadcast
// across the 256 blocks). 8 waves x 64-col chunks. Zero K-loop barriers.
// ---------------------------------------------------------------------------
__global__ __launch_bounds__(512, 2) void gen_fused(
    const float* __restrict__ eps,
    const u16* __restrict__ Win, const u16* __restrict__ Wblk,
    const u16* __restrict__ Wout,
    const float* __restrict__ b_in, const float* __restrict__ b_blk,
    const float* __restrict__ b_out,
    float* __restrict__ xo, u16* __restrict__ xh)
{
    __shared__ u16 XhS[16][520], XlS[16][520];
    const int t = threadIdx.x;
    const int w = t >> 6, lane = t & 63;
    const int quad = lane >> 4, l16 = lane & 15;
    const int bm = blockIdx.x * 16;

    // --- stage eps rows -> x LDS (split1 RTN) ---
    {
        int idx = t * 4;                       // 0..2047 over 16x128
        int row = idx >> 7, col = idx & 127;
        float4 v = *(const float4*)(eps + (size_t)(bm + row) * D + col);
        ushort4 hv, lv;
        split1(v.x, hv.x, lv.x); split1(v.y, hv.y, lv.y);
        split1(v.z, hv.z, lv.z); split1(v.w, hv.w, lv.w);
        *(ushort4*)&XhS[row][col] = hv;
        *(ushort4*)&XlS[row][col] = lv;
    }
    __syncthreads();

    gen_layer<D, false>(XhS, XlS, Win, b_in, w, quad, l16);
    for (int i = 0; i < 4; ++i)
        gen_layer<H, true>(XhS, XlS, Wblk + (size_t)i * H * H, b_blk + i * H,
                           w, quad, l16);

    // --- last layer: out width 128, fp32 xo + RTN xh to global ---
    {
        const int n0 = w * 16;                 // 8 waves x 16 cols
        constexpr int NT = H >> 5;
        constexpr int PF = 4;
        f32x4 acc5 = {};
        const u16* wp = Wout + (size_t)(n0 + l16) * H + quad * 8;
        const float bl = b_out[n0 + l16];
        bf16x8 B5[PF];
        #pragma unroll
        for (int s = 0; s < PF; ++s)
            B5[s] = *(const bf16x8*)(wp + s * 32);
        SCHED_FENCE();
        #pragma unroll
        for (int kt = 0; kt < NT; ++kt) {
            const int kk = kt * 32 + quad * 8;
            bf16x8 bn5;
            if (kt + PF < NT)
                bn5 = *(const bf16x8*)(wp + (kt + PF) * 32);
            SCHED_FENCE();
            bf16x8 af  = *(const bf16x8*)&XhS[l16][kk];
            bf16x8 alf = *(const bf16x8*)&XlS[l16][kk];
            acc5 = MFMA(af,  B5[kt % PF], acc5);
            acc5 = MFMA(alf, B5[kt % PF], acc5);
            if (kt + PF < NT) B5[kt % PF] = bn5;
            SCHED_FENCE();
        }
        const int col = n0 + l16;
        #pragma unroll
        for (int r = 0; r < 4; ++r) {
            const int gm = bm + quad * 4 + r;
            float v = acc5[r] + bl;
            xo[(size_t)gm * D + col] = v;
            xh[(size_t)gm * D + col] = rtn_bf16(v);
        }
    }
}

// ---------------------------------------------------------------------------
// Deterministic row-norms: nx from xo, ny from y_pos. 4 threads/row, fixed
// order + fixed 2-step shfl tree (replaces the fp-atomic path that tripped
// the bit-identical-replay check).
// ---------------------------------------------------------------------------
__global__ __launch_bounds__(256) void rownorm(
    const float* __restrict__ X, const float* __restrict__ Y,
    float* __restrict__ nx, float* __restrict__ ny)
{
    const float* src = blockIdx.y ? Y : X;
    float* dst = blockIdx.y ? ny : nx;
    const int t = threadIdx.x;
    const int row = blockIdx.x * 64 + (t >> 2);
    const int q = t & 3;
    const float* rp = src + (size_t)row * D + q * 32;
    float s = 0.f;
    #pragma unroll
    for (int i = 0; i < 8; ++i) {
        float4 v = *(const float4*)(rp + i * 4);
        s += v.x * v.x + v.y * v.y + v.z * v.z + v.w * v.w;
    }
    s += __shfl_xor(s, 1);
    s += __shfl_xor(s, 2);
    if (q == 0) dst[row] = s;
}

// ---------------------------------------------------------------------------
// Transpose + RTN-bf16 (pure — norms moved to rownorm).
// ---------------------------------------------------------------------------
__global__ __launch_bounds__(256) void transpose_rtn(
    const float* __restrict__ X, const float* __restrict__ Y,
    u16* __restrict__ Xth, u16* __restrict__ Yth)
{
    const float* src = blockIdx.z ? Y : X;
    u16* th = blockIdx.z ? Yth : Xth;
    __shared__ float tile[32][33];
    const int t = threadIdx.x;
    const int r0 = blockIdx.x * 32, c0 = blockIdx.y * 32;
    {
        int rit = t >> 3, coff = (t & 7) * 4;
        float4 v = *(const float4*)(src + (size_t)(r0 + rit) * D + c0 + coff);
        tile[rit][coff + 0] = v.x; tile[rit][coff + 1] = v.y;
        tile[rit][coff + 2] = v.z; tile[rit][coff + 3] = v.w;
    }
    __syncthreads();
    {
        int cit = t >> 3, roff = (t & 7) * 4;
        ushort4 hv;
        hv.x = rtn_bf16(tile[roff + 0][cit]);
        hv.y = rtn_bf16(tile[roff + 1][cit]);
        hv.z = rtn_bf16(tile[roff + 2][cit]);
        hv.w = rtn_bf16(tile[roff + 3][cit]);
        *(ushort4*)(th + (size_t)(c0 + cit) * N + r0 + roff) = hv;
    }
}

// ---------------------------------------------------------------------------
// Distance via SINGLE RTN-bf16 MFMA, fused stats, pos+neg merged. A fp16,
// stored in LOG2 domain. Epilogue in POSITIVE s-domain: raw v_sqrt_f32,
// SC^2 folded into norms, per-element diag cndmask.
// Tile 128(M)x128(N), 4 waves each owning 32 rows x full 128 cols.
// ---------------------------------------------------------------------------
__global__ __launch_bounds__(256) void dist_fused(
    const u16* __restrict__ Xh, const u16* __restrict__ Yh,
    const float* __restrict__ nx, const float* __restrict__ ny,
    f16* __restrict__ Apos, f16* __restrict__ Aneg,
    float* __restrict__ prm_p, float* __restrict__ prs_p,
    float* __restrict__ pcm_p, float* __restrict__ pcs_p,
    float* __restrict__ prm_n, float* __restrict__ prs_n)
{
    const int mat = blockIdx.z;                // 0: X vs Y ; 1: X vs X
    const u16* Bhp = mat ? Xh : Yh;
    const float* nb = mat ? nx : ny;
    f16* Out = mat ? Aneg : Apos;
    float* prm = mat ? prm_n : prm_p;
    float* prs = mat ? prs_n : prs_p;

    __shared__ u16 XhS[128][40], YhS[128][40];
    const int t = threadIdx.x;
    const int w = t >> 6, lane = t & 63;
    const int quad = lane >> 4, l16 = lane & 15;
    const int bm = blockIdx.y * 128, bn = blockIdx.x * 128;
    f32x4 acc[2][8] = {};

    for (int k0 = 0; k0 < D; k0 += 32) {
        __syncthreads();
        #pragma unroll
        for (int p = 0; p < 2; ++p) {
            int slot = t + p * 256;            // 512 slots = 128 rows x 4 octets
            int row = slot >> 2, koff = (slot & 3) << 3;
            *(u16x8*)&XhS[row][koff] =
                *(const u16x8*)(Xh + (size_t)(bm + row) * D + k0 + koff);
        }
        #pragma unroll
        for (int p = 0; p < 2; ++p) {
            int slot = t + p * 256;
            int row = slot >> 2, koff = (slot & 3) << 3;
            int pr = ((row & 3) << 4) | ((row & 63) >> 2) | (row & 64);
            int kf = koff ^ (((pr >> 4) & 3) << 3);
            *(u16x8*)&YhS[pr][kf] =
                *(const u16x8*)(Bhp + (size_t)(bn + row) * D + k0 + koff);
        }
        __syncthreads();
        bf16x8 af[2], bhf[8];
        #pragma unroll
        for (int mi = 0; mi < 2; ++mi)
            af[mi] = *(const bf16x8*)&XhS[w * 32 + mi * 16 + l16][quad * 8];
        #pragma unroll
        for (int ni = 0; ni < 8; ++ni) {
            int nn = ni & 3, hf = ni >> 2;
            bhf[ni] = *(const bf16x8*)
                &YhS[hf * 64 + nn * 16 + l16][(quad * 8) ^ (nn << 3)];
        }
        #pragma unroll
        for (int mi = 0; mi < 2; ++mi)
            #pragma unroll
            for (int ni = 0; ni < 8; ++ni)
                acc[mi][ni] = MFMA(af[mi], bhf[ni], acc[mi][ni]);
    }
    // lane's 8 j's: jb..jb+3 and jb+64..jb+67
    const int jb = bn + (l16 << 2);
    const float SC2 = SC_LOG2 * SC_LOG2;
    const float c2 = -2.0f * SC2;
    const float4 n0v = *(const float4*)(nb + jb);
    const float4 n1v = *(const float4*)(nb + jb + 64);
    const float nl[8] = {n0v.x * SC2, n0v.y * SC2, n0v.z * SC2, n0v.w * SC2,
                         n1v.x * SC2, n1v.y * SC2, n1v.z * SC2, n1v.w * SC2};
    // --- transform in place to s = dist*SC (positive domain) + f16 stores ---
    #pragma unroll
    for (int mi = 0; mi < 2; ++mi)
        #pragma unroll
        for (int r = 0; r < 4; ++r) {
            const int gm = bm + w * 32 + mi * 16 + quad * 4 + r;
            const float nxm = nx[gm] * SC2;
            f16x4 ov0, ov1;
            #pragma unroll
            for (int nn = 0; nn < 4; ++nn) {
                float s0 = fsqrt(fmaxf(
                    fmaf(acc[mi][nn][r], c2, nxm + nl[nn]), 0.f));
                float s1 = fsqrt(fmaxf(
                    fmaf(acc[mi][4 + nn][r], c2, nxm + nl[4 + nn]), 0.f));
                if (mat) {
                    if (gm == jb + nn) s0 = 5.0e6f;
                    if (gm == jb + 64 + nn) s1 = 5.0e6f;
                }
                acc[mi][nn][r] = s0;
                acc[mi][4 + nn][r] = s1;
                ov0[nn] = (f16)(-s0);
                ov1[nn] = (f16)(-s1);
            }
            *(f16x4*)(Out + (size_t)gm * N + jb) = ov0;
            *(f16x4*)(Out + (size_t)gm * N + jb + 64) = ov1;
        }
    // --- row mins of s (== -row max of a): in-lane over 8 ni, DPP over l16 ---
    float m[2][4];
    #pragma unroll
    for (int mi = 0; mi < 2; ++mi)
        #pragma unroll
        for (int r = 0; r < 4; ++r) {
            float v = fminf(fminf(fminf(acc[mi][0][r], acc[mi][1][r]),
                                  fminf(acc[mi][2][r], acc[mi][3][r])),
                            fminf(fminf(acc[mi][4][r], acc[mi][5][r]),
                                  fminf(acc[mi][6][r], acc[mi][7][r])));
            v = fminf(v, dppf<0xB1>(v));
            v = fminf(v, dppf<0x4E>(v));
            v = fminf(v, dppf<0x141>(v));
            v = fminf(v, dppf<0x140>(v));
            m[mi][r] = v;
        }
    // --- wave-shared shift mn (min s over the wave's 32 rows x 128 cols) ---
    float mn = fminf(fminf(fminf(m[0][0], m[0][1]), fminf(m[0][2], m[0][3])),
                     fminf(fminf(m[1][0], m[1][1]), fminf(m[1][2], m[1][3])));
    mn = fminf(mn, __shfl_xor(mn, 16));
    mn = fminf(mn, __shfl_xor(mn, 32));
    // --- single exp pass: e = 2^(mn - s) feeds row sums (sig) + col sums ---
    float sig[2][4] = {};
    float cs[8] = {};
    #pragma unroll
    for (int mi = 0; mi < 2; ++mi)
        #pragma unroll
        for (int ni = 0; ni < 8; ++ni) {
            float e0 = fexp2(mn - acc[mi][ni][0]);
            float e1 = fexp2(mn - acc[mi][ni][1]);
            float e2 = fexp2(mn - acc[mi][ni][2]);
            float e3 = fexp2(mn - acc[mi][ni][3]);
            sig[mi][0] += e0; sig[mi][1] += e1;
            sig[mi][2] += e2; sig[mi][3] += e3;
            cs[ni] += (e0 + e1) + (e2 + e3);
        }
    // --- row partials: DPP tree-sum sig, rescale to row max (a-domain) ---
    const int ct = blockIdx.x;
    #pragma unroll
    for (int mi = 0; mi < 2; ++mi)
        #pragma unroll
        for (int r = 0; r < 4; ++r) {
            float s = sig[mi][r];
            s += dppf<0xB1>(s);
            s += dppf<0x4E>(s);
            s += dppf<0x141>(s);
            s += dppf<0x140>(s);
            s *= fexp2(m[mi][r] - mn);
            if (l16 == 0) {
                int grow = bm + w * 32 + mi * 16 + quad * 4 + r;
                prm[(size_t)ct * N + grow] = -m[mi][r];
                prs[(size_t)ct * N + grow] = s;
            }
        }
    // --- col partials (pos only): quad-reduce cs, shift is -mn (uniform) ---
    if (mat == 0) {
        const int rt = blockIdx.y * 4 + w;      // 32-row tiles -> 128 planes
        #pragma unroll
        for (int ni = 0; ni < 8; ++ni) {
            cs[ni] += __shfl_xor(cs[ni], 16);
            cs[ni] += __shfl_xor(cs[ni], 32);
        }
        if (quad == 0) {
            float4 c0 = {cs[0], cs[1], cs[2], cs[3]};
            float4 c1 = {cs[4], cs[5], cs[6], cs[7]};
            float4 m4 = {-mn, -mn, -mn, -mn};
            *(float4*)(pcs_p + (size_t)rt * N + jb) = c0;
            *(float4*)(pcs_p + (size_t)rt * N + jb + 64) = c1;
            *(float4*)(pcm_p + (size_t)rt * N + jb) = m4;
            *(float4*)(pcm_p + (size_t)rt * N + jb + 64) = m4;
        }
    }
}

// ---------------------------------------------------------------------------
// Combine partials into row/col softmax stats — parallel (192 x 256).
// ---------------------------------------------------------------------------
__global__ __launch_bounds__(256) void stats_combine(
    const float* __restrict__ prm_p, const float* __restrict__ prs_p,
    const float* __restrict__ prm_n, const float* __restrict__ prs_n,
    const float* __restrict__ pcm_p, const float* __restrict__ pcs_p,
    float* __restrict__ m_row, float* __restrict__ isr,
    float* __restrict__ m_col, float* __restrict__ isc)
{
    __shared__ float Ms[4][64], Ss[4][64];
    const int t = threadIdx.x;
    const int g = t >> 6, l = t & 63;
    const int idx = blockIdx.x * 64 + l;

    float m = -3.0e38f, s = 0.f;
    if (idx < N) {
        const int i = idx;
        const int c0 = g * 8;
        #pragma unroll 4
        for (int c = c0; c < c0 + 8; ++c) {
            m = fmaxf(m, prm_p[(size_t)c * N + i]);
            m = fmaxf(m, prm_n[(size_t)c * N + i]);
        }
        #pragma unroll 4
        for (int c = c0; c < c0 + 8; ++c) {
            s += prs_p[(size_t)c * N + i] * fexp2(prm_p[(size_t)c * N + i] - m);
            s += prs_n[(size_t)c * N + i] * fexp2(prm_n[(size_t)c * N + i] - m);
        }
    } else {
        const int mat = (idx - N) >> 12;
        const int j = idx & (N - 1);
        const float* pm = mat ? prm_n : pcm_p;
        const float* ps = mat ? prs_n : pcs_p;
        const int cnt = mat ? 8 : 32;
        const int cb = g * cnt;
        #pragma unroll 4
        for (int c = cb; c < cb + cnt; ++c)
            m = fmaxf(m, pm[(size_t)c * N + j]);
        #pragma unroll 4
        for (int c = cb; c < cb + cnt; ++c)
            s += ps[(size_t)c * N + j] * fexp2(pm[(size_t)c * N + j] - m);
    }
    Ms[g][l] = m; Ss[g][l] = s;
    __syncthreads();
    if (g == 0) {
        float m0 = Ms[0][l], m1 = Ms[1][l], m2 = Ms[2][l], m3 = Ms[3][l];
        float mm = fmaxf(fmaxf(m0, m1), fmaxf(m2, m3));
        float ss = Ss[0][l] * fexp2(m0 - mm) + Ss[1][l] * fexp2(m1 - mm)
                 + Ss[2][l] * fexp2(m2 - mm) + Ss[3][l] * fexp2(m3 - mm);
        if (idx < N) {
            m_row[idx] = mm;
            isr[idx] = 1.0f / sqrtf(ss);
        } else {
            const int mat = (idx - N) >> 12;
            const int j = idx & (N - 1);
            m_col[mat * N + j] = mm;
            isc[mat * N + j] = 1.0f / sqrtf(ss);
        }
    }
}

// ---------------------------------------------------------------------------
// pv via MFMA: A fp16 tile (log2 domain) -> P (fp32 rowsums -> per-KSPLIT
// partial stores, deterministic), split P (trunc) to bf16 hi/lo in LDS,
// MFMA P @ B (B = RTN-bf16 transposed [d][j], hi only).
// ---------------------------------------------------------------------------
__global__ __launch_bounds__(256) void pv_mfma(
    const f16* __restrict__ Apos, const f16* __restrict__ Aneg,
    const u16* __restrict__ Yth, const u16* __restrict__ Xth,
    const float* __restrict__ m_row, const float* __restrict__ isr,
    const float* __restrict__ m_col, const float* __restrict__ isc,
    float* __restrict__ u_part, float* __restrict__ w_part,
    float* __restrict__ sp_part, float* __restrict__ sn_part)
{
    const int mat = blockIdx.z;
    const f16* Am = mat ? Aneg : Apos;
    const u16* Bh = mat ? Xth : Yth;
    const float* mc = m_col + mat * N;
    const float* ic = isc + mat * N;
    float* Cp = (mat ? w_part : u_part) + (size_t)blockIdx.y * (N * D);
    float* spn = (mat ? sn_part : sp_part) + (size_t)blockIdx.y * N;

    __shared__ u16 BhS[128][72];
    __shared__ u16 PhS[64][72], PlS[64][72];
    __shared__ float mrS[64], isrS[64];

    const int t = threadIdx.x;
    const int w = t >> 6, lane = t & 63;
    const int quad = lane >> 4, l16 = lane & 15;
    const int bm = blockIdx.x * 64;
    const int jbase = blockIdx.y * (N / KSPLIT);
    const int arow = t >> 4;          // 0..15
    const int aj = (t & 15) << 2;     // 0..60

    if (t < 64) { mrS[t] = m_row[bm + t]; isrS[t] = isr[bm + t]; }

    f32x4 acc[8] = {};
    float rs[4] = {0.f, 0.f, 0.f, 0.f};

    for (int jt = 0; jt < (N / KSPLIT) / 64; ++jt) {
        const int j0 = jbase + jt * 64;
        __syncthreads();   // protect previous iteration's LDS reads (+ mrS init)
        #pragma unroll
        for (int p = 0; p < 4; ++p) {
            int slot = t + p * 256;
            int d = slot >> 3, joff = (slot & 7) << 3;
            *(u16x8*)&BhS[d][joff] = *(const u16x8*)(Bh + (size_t)d * N + j0 + joff);
        }
        float4 mcv = *(const float4*)(mc + j0 + aj);
        float4 icv = *(const float4*)(ic + j0 + aj);
        #pragma unroll
        for (int s = 0; s < 4; ++s) {
            int row = arow + s * 16;
            f16x4 av = *(const f16x4*)(Am + (size_t)(bm + row) * N + j0 + aj);
            float mr = mrS[row], sr = isrS[row];
            float p0 = fexp2((float)av.x - 0.5f * (mr + mcv.x)) * (sr * icv.x);
            float p1 = fexp2((float)av.y - 0.5f * (mr + mcv.y)) * (sr * icv.y);
            float p2 = fexp2((float)av.z - 0.5f * (mr + mcv.z)) * (sr * icv.z);
            float p3 = fexp2((float)av.w - 0.5f * (mr + mcv.w)) * (sr * icv.w);
            rs[s] += p0 + p1 + p2 + p3;
            ushort4 hv, lv;
            split1_trunc(p0, hv.x, lv.x); split1_trunc(p1, hv.y, lv.y);
            split1_trunc(p2, hv.z, lv.z); split1_trunc(p3, hv.w, lv.w);
            *(ushort4*)&PhS[row][aj] = hv;
            *(ushort4*)&PlS[row][aj] = lv;
        }
        __syncthreads();
        #pragma unroll
        for (int ks = 0; ks < 2; ++ks) {
            const int kk = ks * 32 + quad * 8;
            bf16x8 ph = *(const bf16x8*)&PhS[w * 16 + l16][kk];
            bf16x8 pl = *(const bf16x8*)&PlS[w * 16 + l16][kk];
            #pragma unroll
            for (int ni = 0; ni < 8; ++ni) {
                bf16x8 bh = *(const bf16x8*)&BhS[ni * 16 + l16][kk];
                acc[ni] = MFMA(ph, bh, acc[ni]);
                acc[ni] = MFMA(pl, bh, acc[ni]);
            }
        }
    }
    #pragma unroll
    for (int ni = 0; ni < 8; ++ni)
        #pragma unroll
        for (int r = 0; r < 4; ++r) {
            int row = w * 16 + quad * 4 + r;
            int col = ni * 16 + l16;
            Cp[(size_t)(bm + row) * D + col] = acc[ni][r];
        }
    #pragma unroll
    for (int s = 0; s < 4; ++s) {
        float v = rs[s];
        v += __shfl_xor(v, 1); v += __shfl_xor(v, 2);
        v += __shfl_xor(v, 4); v += __shfl_xor(v, 8);
        if (l16 == 0) spn[bm + arow + s * 16] = v;   // unique writer per (y,row)
    }
}

// ---------------------------------------------------------------------------
// Sum split-K partials (fixed order), V = sn*u - sp*sn*w, per-block V^2
// partial into acc_part (no atomics — finalize does the deterministic sum).
// ---------------------------------------------------------------------------
__global__ __launch_bounds__(256) void final_reduce(const float* __restrict__ u_part,
    const float* __restrict__ w_part, const float* __restrict__ sp_part,
    const float* __restrict__ sn_part, double* __restrict__ acc_part)
{
    __shared__ float red[256];
    const int t = threadIdx.x;
    const int idx = blockIdx.x * 256 + t;
    float u = 0.f, w = 0.f;
    #pragma unroll
    for (int c = 0; c < KSPLIT; ++c) {
        u += u_part[(size_t)c * (N * D) + idx];
        w += w_part[(size_t)c * (N * D) + idx];
    }
    const int i = idx >> 7;
    float sp = 0.f, sn = 0.f;
    #pragma unroll
    for (int c = 0; c < KSPLIT; ++c) {
        sp += sp_part[(size_t)c * N + i];
        sn += sn_part[(size_t)c * N + i];
    }
    const float v = sn * u - sp * sn * w;
    red[t] = v * v; __syncthreads();
    for (int s = 128; s > 0; s >>= 1) { if (t < s) red[t] += red[t + s]; __syncthreads(); }
    if (!t) acc_part[blockIdx.x] = (double)red[0];
}

// ---------------------------------------------------------------------------
// Deterministic final sum: 2048 double partials, fixed-order + fixed tree.
// ---------------------------------------------------------------------------
__global__ __launch_bounds__(256) void finalize(const double* __restrict__ acc_part,
                                                float* __restrict__ out)
{
    __shared__ double red[256];
    const int t = threadIdx.x;
    double s = 0.0;
    #pragma unroll
    for (int i = 0; i < 8; ++i) s += acc_part[t + i * 256];
    red[t] = s; __syncthreads();
    for (int st = 128; st > 0; st >>= 1) {
        if (t < st) red[t] += red[t + st];
        __syncthreads();
    }
    if (!t) out[0] = (float)(red[0] * (1.0 / ((double)N * (double)D)));
}

// ---------------------------------------------------------------------------
extern "C" void kernel_launch(void* const* d_in, const int* in_sizes, int n_in,
                              void* d_out, int out_size, void* d_ws, size_t ws_size,
                              hipStream_t stream)
{
    const float* y_pos = (const float*)d_in[0];
    const float* eps   = (const float*)d_in[1];
    const float* W_in  = (const float*)d_in[2];
    const float* b_in  = (const float*)d_in[3];
    const float* W_blk = (const float*)d_in[4];
    const float* b_blk = (const float*)d_in[5];
    const float* W_out = (const float*)d_in[6];
    const float* b_out = (const float*)d_in[7];
    float* out = (float*)d_out;
    (void)in_sizes; (void)n_in; (void)out_size; (void)ws_size;

    char* p = (char*)d_ws;
    auto alloc = [&](size_t bytes) {
        char* r = p;
        p += (bytes + 255) & ~(size_t)255;
        return r;
    };
    // --- small arrays ---
    double* acc_part = (double*)alloc(2048 * 8);
    float* sp_part = (float*)alloc((size_t)KSPLIT * N * 4);
    float* sn_part = (float*)alloc((size_t)KSPLIT * N * 4);
    float* m_row  = (float*)alloc(N * 4);
    float* isr    = (float*)alloc(N * 4);
    float* m_col  = (float*)alloc(2 * N * 4);
    float* isc    = (float*)alloc(2 * N * 4);
    float* nx     = (float*)alloc(N * 4);
    float* ny     = (float*)alloc(N * 4);
    // --- xo fp32 + bf16 x/y arrays (hi only) ---
    float* xo  = (float*)alloc((size_t)N * D * 4);
    u16* xh    = (u16*)alloc((size_t)N * D * 2);
    u16* xth   = (u16*)alloc((size_t)N * D * 2);
    u16* yh    = (u16*)alloc((size_t)N * D * 2);
    u16* yth   = (u16*)alloc((size_t)N * D * 2);
    // --- shared region (16 MB): weights hi (2.3 MB, dead after gen_fused),
    //     then stats partials (6 MB), then u/w_part (16 MB) ---
    char* genreg = alloc((size_t)KSPLIT * N * D * 4 * 2);
    u16* wih = (u16*)genreg;
    u16* wbh = wih + (size_t)H * D;
    u16* woh = wbh + (size_t)4 * H * H;
    // aliases (disjoint lifetimes, stream-ordered):
    float* prm_p = (float*)genreg;                 // 32*N each = 0.5 MB
    float* prs_p = prm_p + 32 * N;
    float* prm_n = prs_p + 32 * N;
    float* prs_n = prm_n + 32 * N;
    float* pcm_p = prs_n + 32 * N;                 // 128*N = 2 MB each
    float* pcs_p = pcm_p + 128 * N;                // ends at 6 MB
    float* u_part = (float*)genreg;                // KSPLIT*N*D = 8 MB
    float* w_part = u_part + (size_t)KSPLIT * N * D;
    // --- the big ones (64 MB, fp16) ---
    f16* Apos = (f16*)alloc((size_t)N * N * 2);
    f16* Aneg = (f16*)alloc((size_t)N * N * 2);

    // --- RTN-convert y_pos + weights to bf16 hi ---
    SplitArgs sa;
    sa.d[0] = { y_pos, yh,  N * D };
    sa.d[1] = { W_in,  wih, H * D };
    sa.d[2] = { W_blk, wbh, 4 * H * H };
    sa.d[3] = { W_out, woh, D * H };
    split_multi<<<dim3(1024, 4), 256, 0, stream>>>(sa);

    // --- FUSED generator: whole 6-layer chain, x LDS-resident ---
    gen_fused<<<N / 16, 512, 0, stream>>>(eps, wih, wbh, woh,
                                          b_in, b_blk, b_out, xo, xh);

    // --- deterministic row norms (nx from xo, ny from y_pos) ---
    rownorm<<<dim3(N / 64, 2), 256, 0, stream>>>(xo, y_pos, nx, ny);

    // --- RTN transposes ---
    transpose_rtn<<<dim3(N / 32, D / 32, 2), 256, 0, stream>>>(
        xo, y_pos, xth, yth);

    // --- distance matrices (fp16 log2-domain, single-bf16 MFMA) + stats ---
    dist_fused<<<dim3(N / 128, N / 128, 2), 256, 0, stream>>>(
        xh, yh, nx, ny, Apos, Aneg,
        prm_p, prs_p, pcm_p, pcs_p, prm_n, prs_n);

    // --- combine partials into m_row/isr, m_col/isc (parallel) ---
    stats_combine<<<192, 256, 0, stream>>>(prm_p, prs_p, prm_n, prs_n,
                                           pcm_p, pcs_p,
                                           m_row, isr, m_col, isc);

    // --- P@V via MFMA (P built on the fly; sp/sn deterministic partials) ---
    pv_mfma<<<dim3(N / 64, KSPLIT, 2), 256, 0, stream>>>(Apos, Aneg,
        yth, xth, m_row, isr, m_col, isc, u_part, w_part, sp_part, sn_part);

    // --- combine partials, V^2 reduction (no atomics) ---
    final_reduce<<<(N * D) / 256, 256, 0, stream>>>(u_part, w_part,
                                                    sp_part, sn_part, acc_part);
    finalize<<<1, 256, 0, stream>>>(acc_part, out);
}